// Round 1
// baseline (1616.734 us; speedup 1.0000x reference)
//
#include <hip/hip_runtime.h>
#include <math.h>

#define M_TOK 100352   // 8*112*112 tokens
#define NHEAD 6

// ---------------------------------------------------------------------------
// Fold upsample+conv3x3 weights into 4 parity-dependent 2x2 kernels.
// For output (oh,ow) on the 2x-nearest-upsampled grid, the 3x3 taps hit only
// x rows {(oh-1)>>1, (oh-1)>>1+1} (and same for cols), with weights summed by
// parity class. W4g layout: [(c2*4+p)*192 + ci]*4 + (ri*2+cj), p = po*2+pw.
// ---------------------------------------------------------------------------
__global__ __launch_bounds__(256) void fold_kernel(const float* __restrict__ up_w,
                                                   float* __restrict__ W4g) {
    int idx = blockIdx.x * 256 + threadIdx.x;
    if (idx >= 96 * 4 * 192) return;
    int c2 = idx / 768;
    int rem = idx - c2 * 768;
    int p = rem / 192;
    int ci = rem - p * 192;
    int po = p >> 1, pw = p & 1;
    const float* w = up_w + (c2 * 192 + ci) * 9;
    float w9[9];
#pragma unroll
    for (int k = 0; k < 9; k++) w9[k] = w[k];
    float r0[3], r1[3];
#pragma unroll
    for (int kw = 0; kw < 3; kw++) {
        if (po == 0) { r0[kw] = w9[kw];          r1[kw] = w9[3 + kw] + w9[6 + kw]; }
        else         { r0[kw] = w9[kw] + w9[3 + kw]; r1[kw] = w9[6 + kw]; }
    }
    float o00, o01, o10, o11;
    if (pw == 0) { o00 = r0[0];        o01 = r0[1] + r0[2]; o10 = r1[0];        o11 = r1[1] + r1[2]; }
    else         { o00 = r0[0] + r0[1]; o01 = r0[2];        o10 = r1[0] + r1[1]; o11 = r1[2]; }
    *(float4*)&W4g[(size_t)idx * 4] = make_float4(o00, o01, o10, o11);
}

// ---------------------------------------------------------------------------
// Fused upsample-conv3x3 + BN(eval) + ReLU.
// Grid: (49 pixel tiles 16x16, 6 c2-groups of 16, 8 batches). Block 256.
// Thread: 2x2 same-parity output pixels x 4 channels (64 FMA / 13 LDS reads).
// Output written token-major: T[(b*12544 + oh*112 + ow)*96 + c2].
// ---------------------------------------------------------------------------
__global__ __launch_bounds__(256) void conv_kernel(const float* __restrict__ x,
        const float* __restrict__ W4g, const float* __restrict__ up_b,
        const float* __restrict__ bn_g, const float* __restrict__ bn_b,
        const float* __restrict__ bn_m, const float* __restrict__ bn_v,
        float* __restrict__ T) {
    __shared__ float xs[32 * 100];        // [ci][10][10] x tile (zero-padded borders)
    __shared__ float ws[16 * 4 * 132];    // [c2l][p][128 +pad4] folded weights

    int tile = blockIdx.x, c2blk = blockIdx.y, b = blockIdx.z;
    int oh0 = (tile / 7) * 16, ow0 = (tile % 7) * 16;
    int xr0 = (oh0 >> 1) - 1, xc0 = (ow0 >> 1) - 1;
    int tid = threadIdx.x;
    int c2t = tid >> 6;                 // wave id -> 4 channels
    int l = tid & 63;
    int pt = l >> 4;                    // parity 0..3
    int po = pt >> 1, pw = pt & 1;
    int qt = l & 15;
    int qr = qt >> 2, qc = qt & 3;      // 2x2-quad coords in 8x8 parity grid
    int xrow = qr * 2 + po, xcol = qc * 2 + pw;

    float acc[2][2][4];
#pragma unroll
    for (int i = 0; i < 2; i++)
#pragma unroll
        for (int j = 0; j < 2; j++)
#pragma unroll
            for (int cc = 0; cc < 4; cc++) acc[i][j][cc] = 0.f;

    for (int ci0 = 0; ci0 < 192; ci0 += 32) {
        __syncthreads();
        // stage x tile (zero-fill outside [0,56))
        for (int i = tid; i < 3200; i += 256) {
            int cil = i / 100; int rem = i - cil * 100;
            int r = rem / 10, c = rem - r * 10;
            int gr = xr0 + r, gc = xc0 + c;
            float v = 0.f;
            if ((unsigned)gr < 56u && (unsigned)gc < 56u)
                v = x[(size_t)(b * 192 + ci0 + cil) * 3136 + gr * 56 + gc];
            xs[i] = v;
        }
        // stage folded weights for this chunk
        for (int i = tid; i < 8192; i += 256) {
            int c2l = i >> 9; int rem = i & 511;
            int pp = rem >> 7; int j = rem & 127;
            ws[(c2l * 4 + pp) * 132 + j] =
                W4g[(size_t)((c2blk * 16 + c2l) * 4 + pp) * 768 + ci0 * 4 + j];
        }
        __syncthreads();

        for (int ci = 0; ci < 32; ci++) {
            float xv[3][3];
#pragma unroll
            for (int rr = 0; rr < 3; rr++)
#pragma unroll
                for (int cc = 0; cc < 3; cc++)
                    xv[rr][cc] = xs[ci * 100 + (xrow + rr) * 10 + xcol + cc];
#pragma unroll
            for (int cc = 0; cc < 4; cc++) {
                float4 wv = *(const float4*)&ws[((c2t * 4 + cc) * 4 + pt) * 132 + ci * 4];
#pragma unroll
                for (int i = 0; i < 2; i++)
#pragma unroll
                    for (int j = 0; j < 2; j++) {
                        float a = acc[i][j][cc];
                        a = fmaf(wv.x, xv[i][j], a);
                        a = fmaf(wv.y, xv[i][j + 1], a);
                        a = fmaf(wv.z, xv[i + 1][j], a);
                        a = fmaf(wv.w, xv[i + 1][j + 1], a);
                        acc[i][j][cc] = a;
                    }
            }
        }
    }

    // BN + ReLU epilogue
    float sc[4], sh[4];
#pragma unroll
    for (int cc = 0; cc < 4; cc++) {
        int c2 = c2blk * 16 + c2t * 4 + cc;
        float s = bn_g[c2] * rsqrtf(bn_v[c2] + 1e-5f);
        sc[cc] = s;
        sh[cc] = (up_b[c2] - bn_m[c2]) * s + bn_b[c2];
    }
#pragma unroll
    for (int i = 0; i < 2; i++)
#pragma unroll
        for (int j = 0; j < 2; j++) {
            int oh = oh0 + qr * 4 + i * 2 + po;
            int ow = ow0 + qc * 4 + j * 2 + pw;
            size_t tok = (size_t)b * 12544 + oh * 112 + ow;
            float4 v;
            v.x = fmaxf(acc[i][j][0] * sc[0] + sh[0], 0.f);
            v.y = fmaxf(acc[i][j][1] * sc[1] + sh[1], 0.f);
            v.z = fmaxf(acc[i][j][2] * sc[2] + sh[2], 0.f);
            v.w = fmaxf(acc[i][j][3] * sc[3] + sh[3], 0.f);
            *(float4*)&T[tok * 96 + c2blk * 16 + c2t * 4] = v;
        }
}

// ---------------------------------------------------------------------------
// LayerNorm over C=96. One wave per token (lane handles elem lane and 64+lane).
// ---------------------------------------------------------------------------
__global__ __launch_bounds__(256) void ln_kernel(const float* __restrict__ X,
        const float* __restrict__ g, const float* __restrict__ bta,
        float* __restrict__ Y) {
    int tok = blockIdx.x * 4 + (threadIdx.x >> 6);
    int lane = threadIdx.x & 63;
    const float* row = X + (size_t)tok * 96;
    float x1 = row[lane];
    float x2 = (lane < 32) ? row[64 + lane] : 0.f;
    float s = x1 + x2, q = x1 * x1 + x2 * x2;
#pragma unroll
    for (int off = 32; off; off >>= 1) {
        s += __shfl_xor(s, off, 64);
        q += __shfl_xor(q, off, 64);
    }
    float mean = s * (1.f / 96.f);
    float var = q * (1.f / 96.f) - mean * mean;
    float rstd = rsqrtf(var + 1e-5f);
    float* outp = Y + (size_t)tok * 96;
    outp[lane] = (x1 - mean) * rstd * g[lane] + bta[lane];
    if (lane < 32) outp[64 + lane] = (x2 - mean) * rstd * g[64 + lane] + bta[64 + lane];
}

// ---------------------------------------------------------------------------
// f32 GEMM: C(MxN) = A(MxK) @ W(NxK)^T + bias, fused epilogue.
// EPI 0: bias; 1: bias + exact GELU; 2: bias + residual add (res ptr).
// BM=128, BN=64, BK=32; 256 threads, 8x4 per thread.
// ---------------------------------------------------------------------------
template <int EPI>
__global__ __launch_bounds__(256) void gemm_kernel(const float* __restrict__ A,
        const float* __restrict__ W, const float* __restrict__ bias,
        float* __restrict__ C, const float* __restrict__ res, int N, int K) {
    __shared__ float As[32][132];  // [k][m]
    __shared__ float Bs[32][68];   // [k][n]
    int tid = threadIdx.x;
    int tx = tid & 15, ty = tid >> 4;
    int n0 = blockIdx.x * 64;
    int m0 = blockIdx.y * 128;

    float acc[8][4];
#pragma unroll
    for (int i = 0; i < 8; i++)
#pragma unroll
        for (int j = 0; j < 4; j++) acc[i][j] = 0.f;

    for (int k0 = 0; k0 < K; k0 += 32) {
        __syncthreads();
        {   // A tile: 128 rows x 32 k, transposed into LDS
            int r = tid >> 3, c = (tid & 7) << 2;
            const float* ap = A + (size_t)(m0 + r) * K + k0 + c;
#pragma unroll
            for (int rr = 0; rr < 4; rr++) {
                float4 v = *(const float4*)(ap + (size_t)rr * 32 * K);
                As[c + 0][r + rr * 32] = v.x;
                As[c + 1][r + rr * 32] = v.y;
                As[c + 2][r + rr * 32] = v.z;
                As[c + 3][r + rr * 32] = v.w;
            }
        }
        {   // B tile: 64 n-rows x 32 k, transposed; zero-fill n >= N
            int n = tid >> 2, c = (tid & 3) << 3;
            int gn = n0 + n;
            float4 v0 = make_float4(0.f, 0.f, 0.f, 0.f), v1 = v0;
            if (gn < N) {
                const float* wp = W + (size_t)gn * K + k0 + c;
                v0 = *(const float4*)wp;
                v1 = *(const float4*)(wp + 4);
            }
            Bs[c + 0][n] = v0.x; Bs[c + 1][n] = v0.y; Bs[c + 2][n] = v0.z; Bs[c + 3][n] = v0.w;
            Bs[c + 4][n] = v1.x; Bs[c + 5][n] = v1.y; Bs[c + 6][n] = v1.z; Bs[c + 7][n] = v1.w;
        }
        __syncthreads();
#pragma unroll
        for (int kk = 0; kk < 32; kk++) {
            float4 a0 = *(const float4*)&As[kk][ty * 4];
            float4 a1 = *(const float4*)&As[kk][64 + ty * 4];
            float4 b4 = *(const float4*)&Bs[kk][tx * 4];
            float av[8] = {a0.x, a0.y, a0.z, a0.w, a1.x, a1.y, a1.z, a1.w};
            float bv[4] = {b4.x, b4.y, b4.z, b4.w};
#pragma unroll
            for (int i = 0; i < 8; i++)
#pragma unroll
                for (int j = 0; j < 4; j++) acc[i][j] = fmaf(av[i], bv[j], acc[i][j]);
        }
    }

    int gn0 = n0 + tx * 4;
    if (gn0 >= N) return;
    float4 b4 = *(const float4*)&bias[gn0];
#pragma unroll
    for (int i = 0; i < 8; i++) {
        int row = m0 + (i < 4 ? ty * 4 + i : 64 + ty * 4 + i - 4);
        float4 v = make_float4(acc[i][0] + b4.x, acc[i][1] + b4.y,
                               acc[i][2] + b4.z, acc[i][3] + b4.w);
        if (EPI == 1) {
            v.x = 0.5f * v.x * (1.f + erff(v.x * 0.70710678118654752f));
            v.y = 0.5f * v.y * (1.f + erff(v.y * 0.70710678118654752f));
            v.z = 0.5f * v.z * (1.f + erff(v.z * 0.70710678118654752f));
            v.w = 0.5f * v.w * (1.f + erff(v.w * 0.70710678118654752f));
        }
        if (EPI == 2) {
            float4 r4 = *(const float4*)&res[(size_t)row * N + gn0];
            v.x += r4.x; v.y += r4.y; v.z += r4.z; v.w += r4.w;
        }
        *(float4*)&C[(size_t)row * N + gn0] = v;
    }
}

// ---------------------------------------------------------------------------
// Window attention: one block per window (49 tokens), loop over 6 heads.
// Gathers qkv rows via token map (handles shift-roll), computes scores +
// rel-pos bias + shift mask, softmax, PV, scatters output to token order.
// ---------------------------------------------------------------------------
__global__ __launch_bounds__(256) void attn_kernel(const float* __restrict__ qkv,
        const float* __restrict__ rel, float* __restrict__ ao, int shift) {
    __shared__ float qs[49 * 16];     // [a][d], pre-scaled by 0.25
    __shared__ float kts[16 * 52];    // [d][m] transposed, cols 49..51 zero
    __shared__ float vs[49 * 16];     // [m][d]
    __shared__ float ps[49 * 52];     // [a][m] scores -> exp
    __shared__ float rinv[49];
    __shared__ int toks[49];
    __shared__ int lab[49];
    __shared__ float rels[169 * 6];

    int tid = threadIdx.x;
    int Wd = blockIdx.x;
    int bb = Wd >> 8, wl = Wd & 255, wh = wl >> 4, ww = wl & 15;

    if (tid < 49) {
        int r = tid / 7, c = tid - r * 7;
        int h = wh * 7 + r, w = ww * 7 + c;   // window-grid (label) position
        int hs = h, wsx = w;
        if (shift > 0) {
            hs = h + 3; if (hs >= 112) hs -= 112;
            wsx = w + 3; if (wsx >= 112) wsx -= 112;
        }
        toks[tid] = bb * 12544 + hs * 112 + wsx;
        int lh = (h < 105) ? 0 : (h < 109 ? 1 : 2);
        int lw = (w < 105) ? 0 : (w < 109 ? 1 : 2);
        lab[tid] = lh * 3 + lw;
    }
    for (int i = tid; i < 1014; i += 256) rels[i] = rel[i];
    if (tid < 48) {   // zero kts pad columns 49..51 (16 d * 3)
        int d = tid / 3, j = tid - (tid / 3) * 3;
        kts[d * 52 + 49 + j] = 0.f;
    }
    __syncthreads();

    for (int head = 0; head < NHEAD; head++) {
        for (int i = tid; i < 784; i += 256) {
            int a = i >> 4, d = i & 15;
            const float* rowp = qkv + (size_t)toks[a] * 288 + head * 16 + d;
            qs[i] = rowp[0] * 0.25f;      // hd^-0.5 = 1/4
            kts[d * 52 + a] = rowp[96];
            vs[i] = rowp[192];
        }
        __syncthreads();
        // scores: 49 rows x 13 groups of 4 keys
        for (int e = tid; e < 637; e += 256) {
            int a = e / 13, m4 = e - a * 13;
            int m0 = m4 * 4;
            float4 s = make_float4(0.f, 0.f, 0.f, 0.f);
#pragma unroll
            for (int d = 0; d < 16; d++) {
                float qv = qs[a * 16 + d];
                float4 kv = *(const float4*)&kts[d * 52 + m0];
                s.x = fmaf(qv, kv.x, s.x);
                s.y = fmaf(qv, kv.y, s.y);
                s.z = fmaf(qv, kv.z, s.z);
                s.w = fmaf(qv, kv.w, s.w);
            }
            int ah = a / 7, aw = a - (a / 7) * 7;
            float sj[4] = {s.x, s.y, s.z, s.w};
#pragma unroll
            for (int j = 0; j < 4; j++) {
                int m = m0 + j;
                if (m < 49) {
                    int mh = m / 7, mw = m - (m / 7) * 7;
                    float val = sj[j] + rels[((ah - mh + 6) * 13 + (aw - mw + 6)) * 6 + head];
                    if (shift > 0 && lab[a] != lab[m]) val -= 100.f;
                    ps[a * 52 + m] = val;
                }
            }
        }
        __syncthreads();
        if (tid < 49) {   // softmax row
            float mx = -1e30f;
            for (int m = 0; m < 49; m++) mx = fmaxf(mx, ps[tid * 52 + m]);
            float sum = 0.f;
            for (int m = 0; m < 49; m++) {
                float e2 = __expf(ps[tid * 52 + m] - mx);
                ps[tid * 52 + m] = e2;
                sum += e2;
            }
            rinv[tid] = 1.0f / sum;
        }
        __syncthreads();
        if (tid < 196) {   // PV: (a, 4 d's) per thread
            int a = tid >> 2, d0 = (tid & 3) * 4;
            float4 o = make_float4(0.f, 0.f, 0.f, 0.f);
            for (int m = 0; m < 49; m++) {
                float pv = ps[a * 52 + m];
                float4 vv = *(const float4*)&vs[m * 16 + d0];
                o.x = fmaf(pv, vv.x, o.x);
                o.y = fmaf(pv, vv.y, o.y);
                o.z = fmaf(pv, vv.z, o.z);
                o.w = fmaf(pv, vv.w, o.w);
            }
            float ri = rinv[a];
            o.x *= ri; o.y *= ri; o.z *= ri; o.w *= ri;
            *(float4*)&ao[(size_t)toks[a] * 96 + head * 16 + d0] = o;
        }
        __syncthreads();
    }
}

// ---------------------------------------------------------------------------
// Final 1x1 conv (96->48) + ReLU. Block: 64 tokens, wave w handles co = w,w+4,...
// ---------------------------------------------------------------------------
__global__ __launch_bounds__(256) void outconv_kernel(const float* __restrict__ T,
        const float* __restrict__ ow, const float* __restrict__ ob,
        float* __restrict__ out) {
    __shared__ float ts[64 * 100];
    __shared__ float wsh[48 * 96];
    int tid = threadIdx.x;
    size_t tok0 = (size_t)blockIdx.x * 64;
    for (int i = tid; i < 6144; i += 256) {
        int tk = i / 96, c = i - tk * 96;
        ts[tk * 100 + c] = T[(tok0 + tk) * 96 + c];
    }
    for (int i = tid; i < 4608; i += 256) wsh[i] = ow[i];
    __syncthreads();
    int lane = tid & 63, wv = tid >> 6;
    float4 xr[24];
#pragma unroll
    for (int c4 = 0; c4 < 24; c4++) xr[c4] = *(const float4*)&ts[lane * 100 + c4 * 4];
    int tok = (int)tok0 + lane;
    int bb = tok / 12544, pp = tok - bb * 12544;
    for (int co = wv; co < 48; co += 4) {
        float a = 0.f;
#pragma unroll
        for (int c4 = 0; c4 < 24; c4++) {
            float4 w4 = *(const float4*)&wsh[co * 96 + c4 * 4];
            a = fmaf(xr[c4].x, w4.x, a);
            a = fmaf(xr[c4].y, w4.y, a);
            a = fmaf(xr[c4].z, w4.z, a);
            a = fmaf(xr[c4].w, w4.w, a);
        }
        a += ob[co];
        out[((size_t)bb * 48 + co) * 12544 + pp] = fmaxf(a, 0.f);
    }
}

// ---------------------------------------------------------------------------
extern "C" void kernel_launch(void* const* d_in, const int* in_sizes, int n_in,
                              void* d_out, int out_size, void* d_ws, size_t ws_size,
                              hipStream_t stream) {
    const float* x     = (const float*)d_in[0];
    const float* up_w  = (const float*)d_in[1];
    const float* up_b  = (const float*)d_in[2];
    const float* bn_g  = (const float*)d_in[3];
    const float* bn_b  = (const float*)d_in[4];
    const float* bn_m  = (const float*)d_in[5];
    const float* bn_v  = (const float*)d_in[6];
    const float* n1g   = (const float*)d_in[7];
    const float* n1b   = (const float*)d_in[8];
    const float* qkvw  = (const float*)d_in[9];
    const float* qkvb  = (const float*)d_in[10];
    const float* projw = (const float*)d_in[11];
    const float* projb = (const float*)d_in[12];
    const float* rel   = (const float*)d_in[13];
    const float* n2g   = (const float*)d_in[14];
    const float* n2b   = (const float*)d_in[15];
    const float* f1w   = (const float*)d_in[16];
    const float* f1b   = (const float*)d_in[17];
    const float* f2w   = (const float*)d_in[18];
    const float* f2b   = (const float*)d_in[19];
    const float* outw  = (const float*)d_in[20];
    const float* outb  = (const float*)d_in[21];
    float* out = (float*)d_out;

    // workspace layout (floats): T | XB (xn / attn-out) | BIG (qkv / mlp-hidden) | W4g
    float* T   = (float*)d_ws;
    float* XB  = T + (size_t)M_TOK * 96;
    float* BIG = XB + (size_t)M_TOK * 96;
    float* W4g = BIG + (size_t)M_TOK * 384;   // total ~232 MB

    fold_kernel<<<288, 256, 0, stream>>>(up_w, W4g);
    conv_kernel<<<dim3(49, 6, 8), 256, 0, stream>>>(x, W4g, up_b, bn_g, bn_b, bn_m, bn_v, T);

    for (int blk = 0; blk < 2; blk++) {
        int shift = (blk == 0) ? 0 : 3;
        ln_kernel<<<M_TOK / 4, 256, 0, stream>>>(T, n1g + blk * 96, n1b + blk * 96, XB);
        gemm_kernel<0><<<dim3(5, M_TOK / 128), 256, 0, stream>>>(
            XB, qkvw + blk * 27648, qkvb + blk * 288, BIG, nullptr, 288, 96);
        attn_kernel<<<2048, 256, 0, stream>>>(BIG, rel + blk * 1014, XB, shift);
        gemm_kernel<2><<<dim3(2, M_TOK / 128), 256, 0, stream>>>(
            XB, projw + blk * 9216, projb + blk * 96, T, T, 96, 96);
        ln_kernel<<<M_TOK / 4, 256, 0, stream>>>(T, n2g + blk * 96, n2b + blk * 96, XB);
        gemm_kernel<1><<<dim3(6, M_TOK / 128), 256, 0, stream>>>(
            XB, f1w + blk * 36864, f1b + blk * 384, BIG, nullptr, 384, 96);
        gemm_kernel<2><<<dim3(2, M_TOK / 128), 256, 0, stream>>>(
            BIG, f2w + blk * 36864, f2b + blk * 96, T, T, 96, 384);
    }

    outconv_kernel<<<M_TOK / 64, 256, 0, stream>>>(T, outw, outb, out);
}

// Round 2
// 915.815 us; speedup vs baseline: 1.7654x; 1.7654x over previous
//
#include <hip/hip_runtime.h>
#include <math.h>

#define M_TOK 100352   // 8*112*112 tokens
#define NHEAD 6

typedef unsigned short u16;
typedef __attribute__((ext_vector_type(8))) short bf16x8;
typedef __attribute__((ext_vector_type(4))) float f32x4;
typedef __attribute__((ext_vector_type(4))) unsigned int u32x4;

__device__ inline float bf2f(u16 u) {
    union { float f; unsigned int i; } v; v.i = ((unsigned int)u) << 16; return v.f;
}
__device__ inline u16 f2bf(float f) {
    union { float f; unsigned int i; } v; v.f = f;
    unsigned int r = v.i + 0x7fffu + ((v.i >> 16) & 1u);
    return (u16)(r >> 16);
}

// ---------------------------------------------------------------------------
// Cast all GEMM weights f32 -> bf16 into Wh.
// Layout: qkv (2*288*96) | proj (2*96*96) | f1 (2*384*96) | f2 (2*96*384)
// ---------------------------------------------------------------------------
__global__ __launch_bounds__(256) void cast_w_kernel(const float* __restrict__ qkvw,
        const float* __restrict__ projw, const float* __restrict__ f1w,
        const float* __restrict__ f2w, u16* __restrict__ Wh) {
    int i = blockIdx.x * 256 + threadIdx.x;
    if (i < 55296) Wh[i] = f2bf(qkvw[i]);
    else if (i < 73728) Wh[i] = f2bf(projw[i - 55296]);
    else if (i < 147456) Wh[i] = f2bf(f1w[i - 73728]);
    else if (i < 221184) Wh[i] = f2bf(f2w[i - 147456]);
}

// ---------------------------------------------------------------------------
// Fold upsample+conv3x3 into 4 parity x 4 tap 2x2 kernels (verified in R1),
// output bf16: Wc[((p*4+tap)*96 + c2)*192 + ci], tap = di*2+dj.
// ---------------------------------------------------------------------------
__global__ __launch_bounds__(256) void fold_kernel(const float* __restrict__ up_w,
                                                   u16* __restrict__ Wc) {
    int idx = blockIdx.x * 256 + threadIdx.x;
    if (idx >= 96 * 4 * 192) return;
    int c2 = idx / 768;
    int rem = idx - c2 * 768;
    int p = rem / 192;
    int ci = rem - p * 192;
    int po = p >> 1, pw = p & 1;
    const float* w = up_w + (c2 * 192 + ci) * 9;
    float w9[9];
#pragma unroll
    for (int k = 0; k < 9; k++) w9[k] = w[k];
    float r0[3], r1[3];
#pragma unroll
    for (int kw = 0; kw < 3; kw++) {
        if (po == 0) { r0[kw] = w9[kw];              r1[kw] = w9[3 + kw] + w9[6 + kw]; }
        else         { r0[kw] = w9[kw] + w9[3 + kw]; r1[kw] = w9[6 + kw]; }
    }
    float o00, o01, o10, o11;
    if (pw == 0) { o00 = r0[0];         o01 = r0[1] + r0[2]; o10 = r1[0];         o11 = r1[1] + r1[2]; }
    else         { o00 = r0[0] + r0[1]; o01 = r0[2];         o10 = r1[0] + r1[1]; o11 = r1[2]; }
    size_t base = ((size_t)p * 4 * 96 + c2) * 192 + ci;
    Wc[base + 0 * 96 * 192] = f2bf(o00);
    Wc[base + 1 * 96 * 192] = f2bf(o01);
    Wc[base + 2 * 96 * 192] = f2bf(o10);
    Wc[base + 3 * 96 * 192] = f2bf(o11);
}

// ---------------------------------------------------------------------------
// x [b][192][56][56] f32 -> xT [b][3136][192] bf16, XOR-swizzled LDS (both
// phases conflict-free at dword granularity).
// ---------------------------------------------------------------------------
__global__ __launch_bounds__(256) void transpose_kernel(const float* __restrict__ x,
                                                        u16* __restrict__ xT) {
    __shared__ unsigned int ts[64 * 96];
    int b = blockIdx.y;
    int pix0 = blockIdx.x * 64;
    int tid = threadIdx.x;
    int p = tid & 63, dg = tid >> 6;
    const float* xb = x + (size_t)b * 192 * 3136 + pix0 + p;
    for (int d = dg; d < 96; d += 4) {
        float v0 = xb[(size_t)(2 * d) * 3136];
        float v1 = xb[(size_t)(2 * d + 1) * 3136];
        unsigned int pk = ((unsigned int)f2bf(v1) << 16) | (unsigned int)f2bf(v0);
        ts[p * 96 + ((d & ~31) | ((d & 31) ^ (p & 31)))] = pk;
    }
    __syncthreads();
    for (int i = tid; i < 1536; i += 256) {
        int pp = i / 24, c = i - pp * 24;
        unsigned int r[4];
#pragma unroll
        for (int j = 0; j < 4; j++) {
            int d = c * 4 + j;
            r[j] = ts[pp * 96 + ((d & ~31) | ((d & 31) ^ (pp & 31)))];
        }
        u32x4 v = {r[0], r[1], r[2], r[3]};
        *(u32x4*)&xT[((size_t)b * 3136 + pix0 + pp) * 192 + c * 8] = v;
    }
}

// ---------------------------------------------------------------------------
// Implicit-GEMM conv via MFMA. Block: 64 output pixels (8x8 tile of one
// parity class) x 96 channels. Input region 9x9x192 bf16 in LDS; 4 tap-GEMMs
// (K=192 each, staged in 2 chunks of 96). Epilogue: BN + ReLU -> T f32.
// ---------------------------------------------------------------------------
__global__ __launch_bounds__(256) void conv_mfma(const u16* __restrict__ xT,
        const u16* __restrict__ Wc, const float* __restrict__ up_b,
        const float* __restrict__ bn_g, const float* __restrict__ bn_b,
        const float* __restrict__ bn_m, const float* __restrict__ bn_v,
        float* __restrict__ T) {
    __shared__ u16 xs[81 * 200];   // [pix(9x9)][ci 192 +pad8]
    __shared__ u16 ws[96 * 104];   // [c2][k-chunk 96 +pad8]
    int tile = blockIdx.x, p = blockIdx.y, b = blockIdx.z;
    int po = p >> 1, pw = p & 1;
    int a0 = (tile / 7) * 8, b0 = (tile % 7) * 8;
    int rro = a0 - 1 + po, cco = b0 - 1 + pw;
    int tid = threadIdx.x;
    int w = tid >> 6, lane = tid & 63, quad = lane >> 4, l16 = lane & 15;
    int mbase = (w & 1) * 32;
    int nt0 = (w >> 1) * 3;

    // stage 9x9x192 input region (zero-padded at borders)
    for (int i = tid; i < 1944; i += 256) {
        int pix = i / 24, c = i - pix * 24;
        int rr = pix / 9, cc = pix - rr * 9;
        int gr = rro + rr, gc = cco + cc;
        u32x4 v = {0u, 0u, 0u, 0u};
        if ((unsigned)gr < 56u && (unsigned)gc < 56u)
            v = *(const u32x4*)&xT[((size_t)b * 3136 + gr * 56 + gc) * 192 + c * 8];
        *(u32x4*)&xs[pix * 200 + c * 8] = v;
    }

    f32x4 zero = {0.f, 0.f, 0.f, 0.f};
    f32x4 acc[2][3];
#pragma unroll
    for (int mi = 0; mi < 2; mi++)
#pragma unroll
        for (int ni = 0; ni < 3; ni++) acc[mi][ni] = zero;

    int aoffp[2];
#pragma unroll
    for (int mi = 0; mi < 2; mi++) {
        int pixel = mbase + mi * 16 + l16;
        aoffp[mi] = ((pixel >> 3) * 9 + (pixel & 7)) * 200;   // tap offset added later
    }

    for (int tap = 0; tap < 4; tap++) {
        int di = tap >> 1, dj = tap & 1;
        int tsh = (di * 9 + dj) * 200;
        for (int kc = 0; kc < 2; kc++) {
            __syncthreads();
            for (int i = tid; i < 1152; i += 256) {
                int r = i / 12, c = i - r * 12;
                *(u32x4*)&ws[r * 104 + c * 8] =
                    *(const u32x4*)&Wc[(((size_t)p * 4 + tap) * 96 + r) * 192 + kc * 96 + c * 8];
            }
            __syncthreads();
#pragma unroll
            for (int kk = 0; kk < 3; kk++) {
                bf16x8 af[2], bfr[3];
#pragma unroll
                for (int mi = 0; mi < 2; mi++)
                    af[mi] = *(const bf16x8*)&xs[aoffp[mi] + tsh + kc * 96 + kk * 32 + quad * 8];
#pragma unroll
                for (int ni = 0; ni < 3; ni++)
                    bfr[ni] = *(const bf16x8*)&ws[((nt0 + ni) * 16 + l16) * 104 + kk * 32 + quad * 8];
#pragma unroll
                for (int mi = 0; mi < 2; mi++)
#pragma unroll
                    for (int ni = 0; ni < 3; ni++)
                        acc[mi][ni] = __builtin_amdgcn_mfma_f32_16x16x32_bf16(
                            af[mi], bfr[ni], acc[mi][ni], 0, 0, 0);
            }
        }
    }

    // BN + ReLU epilogue, scatter to token-major T
#pragma unroll
    for (int ni = 0; ni < 3; ni++) {
        int c2 = (nt0 + ni) * 16 + l16;
        float sc = bn_g[c2] * rsqrtf(bn_v[c2] + 1e-5f);
        float sh = (up_b[c2] - bn_m[c2]) * sc + bn_b[c2];
#pragma unroll
        for (int mi = 0; mi < 2; mi++) {
#pragma unroll
            for (int reg = 0; reg < 4; reg++) {
                int pixel = mbase + mi * 16 + quad * 4 + reg;
                int pr = pixel >> 3, pc = pixel & 7;
                int oh = 2 * (a0 + pr) + po, ow = 2 * (b0 + pc) + pw;
                size_t tok = (size_t)b * 12544 + oh * 112 + ow;
                T[tok * 96 + c2] = fmaxf(acc[mi][ni][reg] * sc + sh, 0.f);
            }
        }
    }
}

// ---------------------------------------------------------------------------
// LayerNorm over C=96, f32 in -> bf16 out. One wave per token.
// ---------------------------------------------------------------------------
__global__ __launch_bounds__(256) void ln_kernel(const float* __restrict__ X,
        const float* __restrict__ g, const float* __restrict__ bta,
        u16* __restrict__ Y) {
    int tok = blockIdx.x * 4 + (threadIdx.x >> 6);
    int lane = threadIdx.x & 63;
    const float* row = X + (size_t)tok * 96;
    float x1 = row[lane];
    float x2 = (lane < 32) ? row[64 + lane] : 0.f;
    float s = x1 + x2, q = x1 * x1 + x2 * x2;
#pragma unroll
    for (int off = 32; off; off >>= 1) {
        s += __shfl_xor(s, off, 64);
        q += __shfl_xor(q, off, 64);
    }
    float mean = s * (1.f / 96.f);
    float var = q * (1.f / 96.f) - mean * mean;
    float rstd = rsqrtf(var + 1e-5f);
    u16* outp = Y + (size_t)tok * 96;
    outp[lane] = f2bf((x1 - mean) * rstd * g[lane] + bta[lane]);
    if (lane < 32) outp[64 + lane] = f2bf((x2 - mean) * rstd * g[64 + lane] + bta[64 + lane]);
}

// ---------------------------------------------------------------------------
// bf16 MFMA GEMM: C(MxN) = A(MxK) @ W(NxK)^T + bias.
// EPI 0: bias -> bf16 out; 1: bias+GELU -> bf16 out; 2: bias+residual -> f32.
// BM=128, BN=96, BK=96. 4 waves: each 4 m-tiles x 3 n-tiles of 16x16.
// ---------------------------------------------------------------------------
template <int EPI>
__global__ __launch_bounds__(256) void gemm_mfma(const u16* __restrict__ A,
        const u16* __restrict__ W, const float* __restrict__ bias,
        void* Cout, const float* res, int N, int K) {
    __shared__ u16 As[128 * 104];
    __shared__ u16 Bs[96 * 104];
    int tid = threadIdx.x;
    int w = tid >> 6, lane = tid & 63, quad = lane >> 4, l16 = lane & 15;
    int n0 = blockIdx.x * 96;
    size_t m0 = (size_t)blockIdx.y * 128;
    int mbase = (w & 1) * 64;
    int nt0 = (w >> 1) * 3;

    f32x4 zero = {0.f, 0.f, 0.f, 0.f};
    f32x4 acc[4][3];
#pragma unroll
    for (int mi = 0; mi < 4; mi++)
#pragma unroll
        for (int ni = 0; ni < 3; ni++) acc[mi][ni] = zero;

    for (int k0 = 0; k0 < K; k0 += 96) {
        __syncthreads();
        for (int i = tid; i < 1536; i += 256) {
            int r = i / 12, c = i - r * 12;
            *(u32x4*)&As[r * 104 + c * 8] = *(const u32x4*)&A[(m0 + r) * K + k0 + c * 8];
        }
        for (int i = tid; i < 1152; i += 256) {
            int r = i / 12, c = i - r * 12;
            *(u32x4*)&Bs[r * 104 + c * 8] = *(const u32x4*)&W[(size_t)(n0 + r) * K + k0 + c * 8];
        }
        __syncthreads();
#pragma unroll
        for (int kk = 0; kk < 3; kk++) {
            bf16x8 af[4], bfr[3];
#pragma unroll
            for (int mi = 0; mi < 4; mi++)
                af[mi] = *(const bf16x8*)&As[(mbase + mi * 16 + l16) * 104 + kk * 32 + quad * 8];
#pragma unroll
            for (int ni = 0; ni < 3; ni++)
                bfr[ni] = *(const bf16x8*)&Bs[((nt0 + ni) * 16 + l16) * 104 + kk * 32 + quad * 8];
#pragma unroll
            for (int mi = 0; mi < 4; mi++)
#pragma unroll
                for (int ni = 0; ni < 3; ni++)
                    acc[mi][ni] = __builtin_amdgcn_mfma_f32_16x16x32_bf16(
                        af[mi], bfr[ni], acc[mi][ni], 0, 0, 0);
        }
    }

#pragma unroll
    for (int ni = 0; ni < 3; ni++) {
        int col = n0 + (nt0 + ni) * 16 + l16;
        float bv = bias[col];
#pragma unroll
        for (int mi = 0; mi < 4; mi++) {
            size_t rowb = m0 + mbase + mi * 16 + quad * 4;
#pragma unroll
            for (int reg = 0; reg < 4; reg++) {
                size_t row = rowb + reg;
                float v = acc[mi][ni][reg] + bv;
                if (EPI == 1) v = 0.5f * v * (1.f + erff(v * 0.70710678118654752f));
                if (EPI == 2) {
                    v += res[row * N + col];
                    ((float*)Cout)[row * N + col] = v;
                } else {
                    ((u16*)Cout)[row * N + col] = f2bf(v);
                }
            }
        }
    }
}

// ---------------------------------------------------------------------------
// Window attention (bf16 I/O, f32 compute). One block per window, 6 heads.
// ---------------------------------------------------------------------------
__global__ __launch_bounds__(256) void attn_kernel(const u16* __restrict__ qkv,
        const float* __restrict__ rel, u16* __restrict__ ao, int shift) {
    __shared__ float qs[49 * 16];
    __shared__ float kts[16 * 52];
    __shared__ float vs[49 * 16];
    __shared__ float ps[49 * 52];
    __shared__ float rinv[49];
    __shared__ int toks[49];
    __shared__ int lab[49];
    __shared__ float rels[169 * 6];

    int tid = threadIdx.x;
    int Wd = blockIdx.x;
    int bb = Wd >> 8, wl = Wd & 255, wh = wl >> 4, ww = wl & 15;

    if (tid < 49) {
        int r = tid / 7, c = tid - r * 7;
        int h = wh * 7 + r, w = ww * 7 + c;
        int hs = h, wsx = w;
        if (shift > 0) {
            hs = h + 3; if (hs >= 112) hs -= 112;
            wsx = w + 3; if (wsx >= 112) wsx -= 112;
        }
        toks[tid] = bb * 12544 + hs * 112 + wsx;
        int lh = (h < 105) ? 0 : (h < 109 ? 1 : 2);
        int lw = (w < 105) ? 0 : (w < 109 ? 1 : 2);
        lab[tid] = lh * 3 + lw;
    }
    for (int i = tid; i < 1014; i += 256) rels[i] = rel[i];
    if (tid < 48) {
        int d = tid / 3, j = tid - (tid / 3) * 3;
        kts[d * 52 + 49 + j] = 0.f;
    }
    __syncthreads();

    for (int head = 0; head < NHEAD; head++) {
        for (int i = tid; i < 784; i += 256) {
            int a = i >> 4, d = i & 15;
            const u16* rowp = qkv + (size_t)toks[a] * 288 + head * 16 + d;
            qs[i] = bf2f(rowp[0]) * 0.25f;
            kts[d * 52 + a] = bf2f(rowp[96]);
            vs[i] = bf2f(rowp[192]);
        }
        __syncthreads();
        for (int e = tid; e < 637; e += 256) {
            int a = e / 13, m4 = e - a * 13;
            int m0 = m4 * 4;
            float4 s = make_float4(0.f, 0.f, 0.f, 0.f);
#pragma unroll
            for (int d = 0; d < 16; d++) {
                float qv = qs[a * 16 + d];
                float4 kv = *(const float4*)&kts[d * 52 + m0];
                s.x = fmaf(qv, kv.x, s.x);
                s.y = fmaf(qv, kv.y, s.y);
                s.z = fmaf(qv, kv.z, s.z);
                s.w = fmaf(qv, kv.w, s.w);
            }
            int ah = a / 7, aw = a - (a / 7) * 7;
            float sj[4] = {s.x, s.y, s.z, s.w};
#pragma unroll
            for (int j = 0; j < 4; j++) {
                int m = m0 + j;
                if (m < 49) {
                    int mh = m / 7, mw = m - (m / 7) * 7;
                    float val = sj[j] + rels[((ah - mh + 6) * 13 + (aw - mw + 6)) * 6 + head];
                    if (shift > 0 && lab[a] != lab[m]) val -= 100.f;
                    ps[a * 52 + m] = val;
                }
            }
        }
        __syncthreads();
        if (tid < 49) {
            float mx = -1e30f;
            for (int m = 0; m < 49; m++) mx = fmaxf(mx, ps[tid * 52 + m]);
            float sum = 0.f;
            for (int m = 0; m < 49; m++) {
                float e2 = __expf(ps[tid * 52 + m] - mx);
                ps[tid * 52 + m] = e2;
                sum += e2;
            }
            rinv[tid] = 1.0f / sum;
        }
        __syncthreads();
        if (tid < 196) {
            int a = tid >> 2, d0 = (tid & 3) * 4;
            float4 o = make_float4(0.f, 0.f, 0.f, 0.f);
            for (int m = 0; m < 49; m++) {
                float pv = ps[a * 52 + m];
                float4 vv = *(const float4*)&vs[m * 16 + d0];
                o.x = fmaf(pv, vv.x, o.x);
                o.y = fmaf(pv, vv.y, o.y);
                o.z = fmaf(pv, vv.z, o.z);
                o.w = fmaf(pv, vv.w, o.w);
            }
            float ri = rinv[a];
            unsigned int lo = ((unsigned int)f2bf(o.y * ri) << 16) | (unsigned int)f2bf(o.x * ri);
            unsigned int hi = ((unsigned int)f2bf(o.w * ri) << 16) | (unsigned int)f2bf(o.z * ri);
            *(uint2*)&ao[(size_t)toks[a] * 96 + head * 16 + d0] = make_uint2(lo, hi);
        }
        __syncthreads();
    }
}

// ---------------------------------------------------------------------------
// Final 1x1 conv (96->48) + ReLU, reads T f32.
// ---------------------------------------------------------------------------
__global__ __launch_bounds__(256) void outconv_kernel(const float* __restrict__ T,
        const float* __restrict__ ow, const float* __restrict__ ob,
        float* __restrict__ out) {
    __shared__ float ts[64 * 100];
    __shared__ float wsh[48 * 96];
    int tid = threadIdx.x;
    size_t tok0 = (size_t)blockIdx.x * 64;
    for (int i = tid; i < 6144; i += 256) {
        int tk = i / 96, c = i - tk * 96;
        ts[tk * 100 + c] = T[(tok0 + tk) * 96 + c];
    }
    for (int i = tid; i < 4608; i += 256) wsh[i] = ow[i];
    __syncthreads();
    int lane = tid & 63, wv = tid >> 6;
    float4 xr[24];
#pragma unroll
    for (int c4 = 0; c4 < 24; c4++) xr[c4] = *(const float4*)&ts[lane * 100 + c4 * 4];
    int tok = (int)tok0 + lane;
    int bb = tok / 12544, pp = tok - bb * 12544;
    for (int co = wv; co < 48; co += 4) {
        float a = 0.f;
#pragma unroll
        for (int c4 = 0; c4 < 24; c4++) {
            float4 w4 = *(const float4*)&wsh[co * 96 + c4 * 4];
            a = fmaf(xr[c4].x, w4.x, a);
            a = fmaf(xr[c4].y, w4.y, a);
            a = fmaf(xr[c4].z, w4.z, a);
            a = fmaf(xr[c4].w, w4.w, a);
        }
        a += ob[co];
        out[((size_t)bb * 48 + co) * 12544 + pp] = fmaxf(a, 0.f);
    }
}

// ---------------------------------------------------------------------------
extern "C" void kernel_launch(void* const* d_in, const int* in_sizes, int n_in,
                              void* d_out, int out_size, void* d_ws, size_t ws_size,
                              hipStream_t stream) {
    const float* x     = (const float*)d_in[0];
    const float* up_w  = (const float*)d_in[1];
    const float* up_b  = (const float*)d_in[2];
    const float* bn_g  = (const float*)d_in[3];
    const float* bn_b  = (const float*)d_in[4];
    const float* bn_m  = (const float*)d_in[5];
    const float* bn_v  = (const float*)d_in[6];
    const float* n1g   = (const float*)d_in[7];
    const float* n1b   = (const float*)d_in[8];
    const float* qkvw  = (const float*)d_in[9];
    const float* qkvb  = (const float*)d_in[10];
    const float* projw = (const float*)d_in[11];
    const float* projb = (const float*)d_in[12];
    const float* rel   = (const float*)d_in[13];
    const float* n2g   = (const float*)d_in[14];
    const float* n2b   = (const float*)d_in[15];
    const float* f1w   = (const float*)d_in[16];
    const float* f1b   = (const float*)d_in[17];
    const float* f2w   = (const float*)d_in[18];
    const float* f2b   = (const float*)d_in[19];
    const float* outw  = (const float*)d_in[20];
    const float* outb  = (const float*)d_in[21];
    float* out = (float*)d_out;

    // workspace (bytes): T f32 | XBh bf16 | BIGh bf16 | xT bf16 | Wc bf16 | Wh bf16
    char* base = (char*)d_ws;
    float* T  = (float*)base;                       base += (size_t)M_TOK * 96 * 4;
    u16* XBh  = (u16*)base;                         base += (size_t)M_TOK * 96 * 2;
    u16* BIGh = (u16*)base;                         base += (size_t)M_TOK * 384 * 2;
    u16* xT   = (u16*)base;                         base += (size_t)8 * 3136 * 192 * 2;
    u16* Wc   = (u16*)base;                         base += (size_t)16 * 96 * 192 * 2;
    u16* Wh   = (u16*)base;
    u16* qkvwh = Wh;
    u16* projwh = Wh + 55296;
    u16* f1wh = Wh + 73728;
    u16* f2wh = Wh + 147456;

    cast_w_kernel<<<864, 256, 0, stream>>>(qkvw, projw, f1w, f2w, Wh);
    fold_kernel<<<288, 256, 0, stream>>>(up_w, Wc);
    transpose_kernel<<<dim3(49, 8), 256, 0, stream>>>(x, xT);
    conv_mfma<<<dim3(49, 4, 8), 256, 0, stream>>>(xT, Wc, up_b, bn_g, bn_b, bn_m, bn_v, T);

    for (int blk = 0; blk < 2; blk++) {
        int shift = (blk == 0) ? 0 : 3;
        ln_kernel<<<M_TOK / 4, 256, 0, stream>>>(T, n1g + blk * 96, n1b + blk * 96, XBh);
        gemm_mfma<0><<<dim3(3, M_TOK / 128), 256, 0, stream>>>(
            XBh, qkvwh + blk * 27648, qkvb + blk * 288, BIGh, nullptr, 288, 96);
        attn_kernel<<<2048, 256, 0, stream>>>(BIGh, rel + blk * 1014, XBh, shift);
        gemm_mfma<2><<<dim3(1, M_TOK / 128), 256, 0, stream>>>(
            XBh, projwh + blk * 9216, projb + blk * 96, T, T, 96, 96);
        ln_kernel<<<M_TOK / 4, 256, 0, stream>>>(T, n2g + blk * 96, n2b + blk * 96, XBh);
        gemm_mfma<1><<<dim3(4, M_TOK / 128), 256, 0, stream>>>(
            XBh, f1wh + blk * 36864, f1b + blk * 384, BIGh, nullptr, 384, 96);
        gemm_mfma<2><<<dim3(1, M_TOK / 128), 256, 0, stream>>>(
            BIGh, f2wh + blk * 36864, f2b + blk * 96, T, T, 96, 384);
    }

    outconv_kernel<<<M_TOK / 64, 256, 0, stream>>>(T, outw, outb, out);
}

// Round 3
// 781.189 us; speedup vs baseline: 2.0696x; 1.1723x over previous
//
#include <hip/hip_runtime.h>
#include <math.h>

#define M_TOK 100352   // 8*112*112 tokens
#define NHEAD 6

typedef unsigned short u16;
typedef __attribute__((ext_vector_type(8))) short bf16x8;
typedef __attribute__((ext_vector_type(4))) float f32x4;
typedef __attribute__((ext_vector_type(4))) unsigned int u32x4;

__device__ inline float bf2f(u16 u) {
    union { float f; unsigned int i; } v; v.i = ((unsigned int)u) << 16; return v.f;
}
__device__ inline u16 f2bf(float f) {
    union { float f; unsigned int i; } v; v.f = f;
    unsigned int r = v.i + 0x7fffu + ((v.i >> 16) & 1u);
    return (u16)(r >> 16);
}

// ---------------------------------------------------------------------------
// Cast all GEMM weights f32 -> bf16 into Wh.
// ---------------------------------------------------------------------------
__global__ __launch_bounds__(256) void cast_w_kernel(const float* __restrict__ qkvw,
        const float* __restrict__ projw, const float* __restrict__ f1w,
        const float* __restrict__ f2w, u16* __restrict__ Wh) {
    int i = blockIdx.x * 256 + threadIdx.x;
    if (i < 55296) Wh[i] = f2bf(qkvw[i]);
    else if (i < 73728) Wh[i] = f2bf(projw[i - 55296]);
    else if (i < 147456) Wh[i] = f2bf(f1w[i - 73728]);
    else if (i < 221184) Wh[i] = f2bf(f2w[i - 147456]);
}

// ---------------------------------------------------------------------------
// Fold upsample+conv3x3 into 4 parity x 4 tap 2x2 kernels (verified).
// ---------------------------------------------------------------------------
__global__ __launch_bounds__(256) void fold_kernel(const float* __restrict__ up_w,
                                                   u16* __restrict__ Wc) {
    int idx = blockIdx.x * 256 + threadIdx.x;
    if (idx >= 96 * 4 * 192) return;
    int c2 = idx / 768;
    int rem = idx - c2 * 768;
    int p = rem / 192;
    int ci = rem - p * 192;
    int po = p >> 1, pw = p & 1;
    const float* w = up_w + (c2 * 192 + ci) * 9;
    float w9[9];
#pragma unroll
    for (int k = 0; k < 9; k++) w9[k] = w[k];
    float r0[3], r1[3];
#pragma unroll
    for (int kw = 0; kw < 3; kw++) {
        if (po == 0) { r0[kw] = w9[kw];              r1[kw] = w9[3 + kw] + w9[6 + kw]; }
        else         { r0[kw] = w9[kw] + w9[3 + kw]; r1[kw] = w9[6 + kw]; }
    }
    float o00, o01, o10, o11;
    if (pw == 0) { o00 = r0[0];         o01 = r0[1] + r0[2]; o10 = r1[0];         o11 = r1[1] + r1[2]; }
    else         { o00 = r0[0] + r0[1]; o01 = r0[2];         o10 = r1[0] + r1[1]; o11 = r1[2]; }
    size_t base = ((size_t)p * 4 * 96 + c2) * 192 + ci;
    Wc[base + 0 * 96 * 192] = f2bf(o00);
    Wc[base + 1 * 96 * 192] = f2bf(o01);
    Wc[base + 2 * 96 * 192] = f2bf(o10);
    Wc[base + 3 * 96 * 192] = f2bf(o11);
}

// ---------------------------------------------------------------------------
// x [b][192][56][56] f32 -> xT [b][3136][192] bf16 (XOR-swizzled LDS).
// ---------------------------------------------------------------------------
__global__ __launch_bounds__(256) void transpose_kernel(const float* __restrict__ x,
                                                        u16* __restrict__ xT) {
    __shared__ unsigned int ts[64 * 96];
    int b = blockIdx.y;
    int pix0 = blockIdx.x * 64;
    int tid = threadIdx.x;
    int p = tid & 63, dg = tid >> 6;
    const float* xb = x + (size_t)b * 192 * 3136 + pix0 + p;
    for (int d = dg; d < 96; d += 4) {
        float v0 = xb[(size_t)(2 * d) * 3136];
        float v1 = xb[(size_t)(2 * d + 1) * 3136];
        unsigned int pk = ((unsigned int)f2bf(v1) << 16) | (unsigned int)f2bf(v0);
        ts[p * 96 + ((d & ~31) | ((d & 31) ^ (p & 31)))] = pk;
    }
    __syncthreads();
    for (int i = tid; i < 1536; i += 256) {
        int pp = i / 24, c = i - pp * 24;
        unsigned int r[4];
#pragma unroll
        for (int j = 0; j < 4; j++) {
            int d = c * 4 + j;
            r[j] = ts[pp * 96 + ((d & ~31) | ((d & 31) ^ (pp & 31)))];
        }
        u32x4 v = {r[0], r[1], r[2], r[3]};
        *(u32x4*)&xT[((size_t)b * 3136 + pix0 + pp) * 192 + c * 8] = v;
    }
}

// ---------------------------------------------------------------------------
// Implicit-GEMM conv via MFMA (unchanged from passing R2).
// ---------------------------------------------------------------------------
__global__ __launch_bounds__(256) void conv_mfma(const u16* __restrict__ xT,
        const u16* __restrict__ Wc, const float* __restrict__ up_b,
        const float* __restrict__ bn_g, const float* __restrict__ bn_b,
        const float* __restrict__ bn_m, const float* __restrict__ bn_v,
        float* __restrict__ T) {
    __shared__ u16 xs[81 * 200];
    __shared__ u16 ws[96 * 104];
    int tile = blockIdx.x, p = blockIdx.y, b = blockIdx.z;
    int po = p >> 1, pw = p & 1;
    int a0 = (tile / 7) * 8, b0 = (tile % 7) * 8;
    int rro = a0 - 1 + po, cco = b0 - 1 + pw;
    int tid = threadIdx.x;
    int w = tid >> 6, lane = tid & 63, quad = lane >> 4, l16 = lane & 15;
    int mbase = (w & 1) * 32;
    int nt0 = (w >> 1) * 3;

    for (int i = tid; i < 1944; i += 256) {
        int pix = i / 24, c = i - pix * 24;
        int rr = pix / 9, cc = pix - rr * 9;
        int gr = rro + rr, gc = cco + cc;
        u32x4 v = {0u, 0u, 0u, 0u};
        if ((unsigned)gr < 56u && (unsigned)gc < 56u)
            v = *(const u32x4*)&xT[((size_t)b * 3136 + gr * 56 + gc) * 192 + c * 8];
        *(u32x4*)&xs[pix * 200 + c * 8] = v;
    }

    f32x4 zero = {0.f, 0.f, 0.f, 0.f};
    f32x4 acc[2][3];
#pragma unroll
    for (int mi = 0; mi < 2; mi++)
#pragma unroll
        for (int ni = 0; ni < 3; ni++) acc[mi][ni] = zero;

    int aoffp[2];
#pragma unroll
    for (int mi = 0; mi < 2; mi++) {
        int pixel = mbase + mi * 16 + l16;
        aoffp[mi] = ((pixel >> 3) * 9 + (pixel & 7)) * 200;
    }

    for (int tap = 0; tap < 4; tap++) {
        int di = tap >> 1, dj = tap & 1;
        int tsh = (di * 9 + dj) * 200;
        for (int kc = 0; kc < 2; kc++) {
            __syncthreads();
            for (int i = tid; i < 1152; i += 256) {
                int r = i / 12, c = i - r * 12;
                *(u32x4*)&ws[r * 104 + c * 8] =
                    *(const u32x4*)&Wc[(((size_t)p * 4 + tap) * 96 + r) * 192 + kc * 96 + c * 8];
            }
            __syncthreads();
#pragma unroll
            for (int kk = 0; kk < 3; kk++) {
                bf16x8 af[2], bfr[3];
#pragma unroll
                for (int mi = 0; mi < 2; mi++)
                    af[mi] = *(const bf16x8*)&xs[aoffp[mi] + tsh + kc * 96 + kk * 32 + quad * 8];
#pragma unroll
                for (int ni = 0; ni < 3; ni++)
                    bfr[ni] = *(const bf16x8*)&ws[((nt0 + ni) * 16 + l16) * 104 + kk * 32 + quad * 8];
#pragma unroll
                for (int mi = 0; mi < 2; mi++)
#pragma unroll
                    for (int ni = 0; ni < 3; ni++)
                        acc[mi][ni] = __builtin_amdgcn_mfma_f32_16x16x32_bf16(
                            af[mi], bfr[ni], acc[mi][ni], 0, 0, 0);
            }
        }
    }

#pragma unroll
    for (int ni = 0; ni < 3; ni++) {
        int c2 = (nt0 + ni) * 16 + l16;
        float sc = bn_g[c2] * rsqrtf(bn_v[c2] + 1e-5f);
        float sh = (up_b[c2] - bn_m[c2]) * sc + bn_b[c2];
#pragma unroll
        for (int mi = 0; mi < 2; mi++) {
#pragma unroll
            for (int reg = 0; reg < 4; reg++) {
                int pixel = mbase + mi * 16 + quad * 4 + reg;
                int pr = pixel >> 3, pc = pixel & 7;
                int oh = 2 * (a0 + pr) + po, ow = 2 * (b0 + pc) + pw;
                size_t tok = (size_t)b * 12544 + oh * 112 + ow;
                T[tok * 96 + c2] = fmaxf(acc[mi][ni][reg] * sc + sh, 0.f);
            }
        }
    }
}

// ---------------------------------------------------------------------------
// LayerNorm over C=96, f32 in -> bf16 out.
// ---------------------------------------------------------------------------
__global__ __launch_bounds__(256) void ln_kernel(const float* __restrict__ X,
        const float* __restrict__ g, const float* __restrict__ bta,
        u16* __restrict__ Y) {
    int tok = blockIdx.x * 4 + (threadIdx.x >> 6);
    int lane = threadIdx.x & 63;
    const float* row = X + (size_t)tok * 96;
    float x1 = row[lane];
    float x2 = (lane < 32) ? row[64 + lane] : 0.f;
    float s = x1 + x2, q = x1 * x1 + x2 * x2;
#pragma unroll
    for (int off = 32; off; off >>= 1) {
        s += __shfl_xor(s, off, 64);
        q += __shfl_xor(q, off, 64);
    }
    float mean = s * (1.f / 96.f);
    float var = q * (1.f / 96.f) - mean * mean;
    float rstd = rsqrtf(var + 1e-5f);
    u16* outp = Y + (size_t)tok * 96;
    outp[lane] = f2bf((x1 - mean) * rstd * g[lane] + bta[lane]);
    if (lane < 32) outp[64 + lane] = f2bf((x2 - mean) * rstd * g[64 + lane] + bta[64 + lane]);
}

// ---------------------------------------------------------------------------
// bf16 MFMA GEMM (unchanged from passing R2).
// ---------------------------------------------------------------------------
template <int EPI>
__global__ __launch_bounds__(256) void gemm_mfma(const u16* __restrict__ A,
        const u16* __restrict__ W, const float* __restrict__ bias,
        void* Cout, const float* res, int N, int K) {
    __shared__ u16 As[128 * 104];
    __shared__ u16 Bs[96 * 104];
    int tid = threadIdx.x;
    int w = tid >> 6, lane = tid & 63, quad = lane >> 4, l16 = lane & 15;
    int n0 = blockIdx.x * 96;
    size_t m0 = (size_t)blockIdx.y * 128;
    int mbase = (w & 1) * 64;
    int nt0 = (w >> 1) * 3;

    f32x4 zero = {0.f, 0.f, 0.f, 0.f};
    f32x4 acc[4][3];
#pragma unroll
    for (int mi = 0; mi < 4; mi++)
#pragma unroll
        for (int ni = 0; ni < 3; ni++) acc[mi][ni] = zero;

    for (int k0 = 0; k0 < K; k0 += 96) {
        __syncthreads();
        for (int i = tid; i < 1536; i += 256) {
            int r = i / 12, c = i - r * 12;
            *(u32x4*)&As[r * 104 + c * 8] = *(const u32x4*)&A[(m0 + r) * K + k0 + c * 8];
        }
        for (int i = tid; i < 1152; i += 256) {
            int r = i / 12, c = i - r * 12;
            *(u32x4*)&Bs[r * 104 + c * 8] = *(const u32x4*)&W[(size_t)(n0 + r) * K + k0 + c * 8];
        }
        __syncthreads();
#pragma unroll
        for (int kk = 0; kk < 3; kk++) {
            bf16x8 af[4], bfr[3];
#pragma unroll
            for (int mi = 0; mi < 4; mi++)
                af[mi] = *(const bf16x8*)&As[(mbase + mi * 16 + l16) * 104 + kk * 32 + quad * 8];
#pragma unroll
            for (int ni = 0; ni < 3; ni++)
                bfr[ni] = *(const bf16x8*)&Bs[((nt0 + ni) * 16 + l16) * 104 + kk * 32 + quad * 8];
#pragma unroll
            for (int mi = 0; mi < 4; mi++)
#pragma unroll
                for (int ni = 0; ni < 3; ni++)
                    acc[mi][ni] = __builtin_amdgcn_mfma_f32_16x16x32_bf16(
                        af[mi], bfr[ni], acc[mi][ni], 0, 0, 0);
        }
    }

#pragma unroll
    for (int ni = 0; ni < 3; ni++) {
        int col = n0 + (nt0 + ni) * 16 + l16;
        float bv = bias[col];
#pragma unroll
        for (int mi = 0; mi < 4; mi++) {
            size_t rowb = m0 + mbase + mi * 16 + quad * 4;
#pragma unroll
            for (int reg = 0; reg < 4; reg++) {
                size_t row = rowb + reg;
                float v = acc[mi][ni][reg] + bv;
                if (EPI == 1) v = 0.5f * v * (1.f + erff(v * 0.70710678118654752f));
                if (EPI == 2) {
                    v += res[row * N + col];
                    ((float*)Cout)[row * N + col] = v;
                } else {
                    ((u16*)Cout)[row * N + col] = f2bf(v);
                }
            }
        }
    }
}

// ---------------------------------------------------------------------------
// MFMA window attention. Block = 192 threads (3 waves), one window/block;
// wave w handles heads 2w, 2w+1. Per wave-head: QK^T (16 MFMAs, d padded to
// K=32), register softmax (C-layout, shfl row-reduce, 0.25 scale fused into
// bias FMA, 1/sum deferred), P -> LDS bf16 (aliases q/k), PV (8 MFMAs vs V^T).
// ---------------------------------------------------------------------------
__global__ __launch_bounds__(192) void attn_mfma(const u16* __restrict__ qkv,
        const float* __restrict__ rel, u16* __restrict__ ao, int shift) {
    __shared__ u16 qk[3][5120];     // per wave: qs [64][40] @0, ks [64][40] @2560; P [64][72] aliases
    __shared__ u16 vt[3][1152];     // per wave: vT [16 d][72 keys]
    __shared__ float rels[1014];
    __shared__ int toks[49];
    __shared__ int lab[49];

    int tid = threadIdx.x;
    int w = tid >> 6, lane = tid & 63, quad = lane >> 4, l16 = lane & 15;
    int Wd = blockIdx.x;
    int bb = Wd >> 8, wl = Wd & 255, wh = wl >> 4, ww = wl & 15;

    if (tid < 49) {
        int r = tid / 7, c = tid - r * 7;
        int h = wh * 7 + r, wq = ww * 7 + c;
        int hs = h, wsx = wq;
        if (shift > 0) {
            hs = h + 3; if (hs >= 112) hs -= 112;
            wsx = wq + 3; if (wsx >= 112) wsx -= 112;
        }
        toks[tid] = bb * 12544 + hs * 112 + wsx;
        int lh = (h < 105) ? 0 : (h < 109 ? 1 : 2);
        int lw = (wq < 105) ? 0 : (wq < 109 ? 1 : 2);
        lab[tid] = lh * 3 + lw;
    }
    for (int i = tid; i < 1014; i += 192) rels[i] = rel[i];
    __syncthreads();

    u16* qs  = qk[w];
    u16* ks  = qk[w] + 2560;
    u16* Ps  = qk[w];          // stride 72, aliases qs/ks after QK
    u16* vts = vt[w];

    for (int hh = 0; hh < 2; hh++) {
        int head = w * 2 + hh;
        __syncthreads();   // prior-iter P/vT reads done before restaging

        // ---- stage: zero pads ----
        u32x4 z4 = {0u, 0u, 0u, 0u};
        for (int i = lane; i < 256; i += 64) {      // q/k cols 16..31, all rows
            int row = i >> 2; int mat = (i >> 1) & 1; int ch = i & 1;
            *(u32x4*)&((mat ? ks : qs)[row * 40 + 16 + ch * 8]) = z4;
        }
        if (lane < 60) {                            // q/k rows 49..63, cols 0..15
            int row = 49 + (lane >> 2); int mat = (lane >> 1) & 1; int ch = lane & 1;
            *(u32x4*)&((mat ? ks : qs)[row * 40 + ch * 8]) = z4;
        }
        for (int i = lane; i < 240; i += 64) {      // vT keys 49..63
            int row = i / 15, key = 49 + (i - row * 15);
            vts[row * 72 + key] = 0;
        }
        // ---- stage: gather q,k rows; v transposed ----
        if (lane < 49) {
            const u16* base = qkv + (size_t)toks[lane] * 288 + head * 16;
            *(u32x4*)&qs[lane * 40]     = *(const u32x4*)(base);
            *(u32x4*)&qs[lane * 40 + 8] = *(const u32x4*)(base + 8);
            *(u32x4*)&ks[lane * 40]     = *(const u32x4*)(base + 96);
            *(u32x4*)&ks[lane * 40 + 8] = *(const u32x4*)(base + 96 + 8);
            union { u32x4 v; unsigned int u[4]; } v0, v1;
            v0.v = *(const u32x4*)(base + 192);
            v1.v = *(const u32x4*)(base + 192 + 8);
#pragma unroll
            for (int j = 0; j < 4; j++) {
                vts[(2 * j)     * 72 + lane] = (u16)(v0.u[j] & 0xffffu);
                vts[(2 * j + 1) * 72 + lane] = (u16)(v0.u[j] >> 16);
                vts[(8 + 2 * j)     * 72 + lane] = (u16)(v1.u[j] & 0xffffu);
                vts[(8 + 2 * j + 1) * 72 + lane] = (u16)(v1.u[j] >> 16);
            }
        }
        __syncthreads();

        // ---- QK^T: S[64][64] in C-layout registers ----
        f32x4 S[4][4];
        {
            bf16x8 af[4], bf[4];
#pragma unroll
            for (int mi = 0; mi < 4; mi++)
                af[mi] = *(const bf16x8*)&qs[(mi * 16 + l16) * 40 + quad * 8];
#pragma unroll
            for (int ni = 0; ni < 4; ni++)
                bf[ni] = *(const bf16x8*)&ks[(ni * 16 + l16) * 40 + quad * 8];
#pragma unroll
            for (int mi = 0; mi < 4; mi++)
#pragma unroll
                for (int ni = 0; ni < 4; ni++)
                    S[mi][ni] = __builtin_amdgcn_mfma_f32_16x16x32_bf16(
                        af[mi], bf[ni], f32x4{0.f, 0.f, 0.f, 0.f}, 0, 0, 0);
        }

        // ---- bias + scale + mask (rows m = mi*16+quad*4+reg, cols n = ni*16+l16) ----
        int ai6[16], la[16];
#pragma unroll
        for (int mi = 0; mi < 4; mi++)
#pragma unroll
            for (int reg = 0; reg < 4; reg++) {
                int i = mi * 4 + reg;
                int a = mi * 16 + quad * 4 + reg;
                int ah = (a * 37) >> 8; int aw = a - ah * 7;
                ai6[i] = (ah * 13 + aw) * 6 + 504 + head;   // 504 = 6*6*13 + 6*6
                la[i] = lab[a < 49 ? a : 48];
            }
        int k6[4], lk[4], kv[4];
#pragma unroll
        for (int ni = 0; ni < 4; ni++) {
            int kk = ni * 16 + l16;
            int kh = (kk * 37) >> 8; int kw = kk - kh * 7;
            k6[ni] = (kh * 13 + kw) * 6;
            lk[ni] = lab[kk < 49 ? kk : 48];
            kv[ni] = (kk < 49);
        }
#pragma unroll
        for (int mi = 0; mi < 4; mi++)
#pragma unroll
            for (int ni = 0; ni < 4; ni++)
#pragma unroll
                for (int reg = 0; reg < 4; reg++) {
                    int i = mi * 4 + reg;
                    int a = mi * 16 + quad * 4 + reg;
                    float s = S[mi][ni][reg];
                    float val;
                    if (!kv[ni]) val = -1e30f;
                    else if (a < 49) {
                        val = fmaf(s, 0.25f, rels[ai6[i] - k6[ni]]);
                        if (shift > 0 && la[i] != lk[ni]) val -= 100.f;
                    } else val = s * 0.25f;
                    S[mi][ni][reg] = val;
                }

        // ---- softmax in registers ----
        float rinv[16];
#pragma unroll
        for (int mi = 0; mi < 4; mi++)
#pragma unroll
            for (int reg = 0; reg < 4; reg++) {
                float mx = fmaxf(fmaxf(S[mi][0][reg], S[mi][1][reg]),
                                 fmaxf(S[mi][2][reg], S[mi][3][reg]));
#pragma unroll
                for (int d = 1; d < 16; d <<= 1) mx = fmaxf(mx, __shfl_xor(mx, d, 64));
                float sm = 0.f;
#pragma unroll
                for (int ni = 0; ni < 4; ni++) {
                    float e = __expf(S[mi][ni][reg] - mx);
                    S[mi][ni][reg] = e;
                    sm += e;
                }
#pragma unroll
                for (int d = 1; d < 16; d <<= 1) sm += __shfl_xor(sm, d, 64);
                rinv[mi * 4 + reg] = 1.0f / sm;
            }
        __syncthreads();   // all QK frag reads done before P overwrites qs/ks

        // ---- write P (bf16) to LDS, stride 72 ----
#pragma unroll
        for (int mi = 0; mi < 4; mi++)
#pragma unroll
            for (int ni = 0; ni < 4; ni++)
#pragma unroll
                for (int reg = 0; reg < 4; reg++)
                    Ps[(mi * 16 + quad * 4 + reg) * 72 + ni * 16 + l16] = f2bf(S[mi][ni][reg]);
        __syncthreads();

        // ---- PV: O[64][16] ----
        f32x4 O[4];
#pragma unroll
        for (int mi = 0; mi < 4; mi++) O[mi] = f32x4{0.f, 0.f, 0.f, 0.f};
        {
            bf16x8 vf[2];
#pragma unroll
            for (int ksp = 0; ksp < 2; ksp++)
                vf[ksp] = *(const bf16x8*)&vts[l16 * 72 + ksp * 32 + quad * 8];
#pragma unroll
            for (int mi = 0; mi < 4; mi++)
#pragma unroll
                for (int ksp = 0; ksp < 2; ksp++) {
                    bf16x8 pf = *(const bf16x8*)&Ps[(mi * 16 + l16) * 72 + ksp * 32 + quad * 8];
                    O[mi] = __builtin_amdgcn_mfma_f32_16x16x32_bf16(pf, vf[ksp], O[mi], 0, 0, 0);
                }
        }

        // ---- store (deferred 1/sum) ----
#pragma unroll
        for (int mi = 0; mi < 4; mi++)
#pragma unroll
            for (int reg = 0; reg < 4; reg++) {
                int a = mi * 16 + quad * 4 + reg;
                if (a < 49)
                    ao[(size_t)toks[a] * 96 + head * 16 + l16] =
                        f2bf(O[mi][reg] * rinv[mi * 4 + reg]);
            }
    }
}

// ---------------------------------------------------------------------------
// Final 1x1 conv (96->48) + ReLU.
// ---------------------------------------------------------------------------
__global__ __launch_bounds__(256) void outconv_kernel(const float* __restrict__ T,
        const float* __restrict__ ow, const float* __restrict__ ob,
        float* __restrict__ out) {
    __shared__ float ts[64 * 100];
    __shared__ float wsh[48 * 96];
    int tid = threadIdx.x;
    size_t tok0 = (size_t)blockIdx.x * 64;
    for (int i = tid; i < 6144; i += 256) {
        int tk = i / 96, c = i - tk * 96;
        ts[tk * 100 + c] = T[(tok0 + tk) * 96 + c];
    }
    for (int i = tid; i < 4608; i += 256) wsh[i] = ow[i];
    __syncthreads();
    int lane = tid & 63, wv = tid >> 6;
    float4 xr[24];
#pragma unroll
    for (int c4 = 0; c4 < 24; c4++) xr[c4] = *(const float4*)&ts[lane * 100 + c4 * 4];
    int tok = (int)tok0 + lane;
    int bb = tok / 12544, pp = tok - bb * 12544;
    for (int co = wv; co < 48; co += 4) {
        float a = 0.f;
#pragma unroll
        for (int c4 = 0; c4 < 24; c4++) {
            float4 w4 = *(const float4*)&wsh[co * 96 + c4 * 4];
            a = fmaf(xr[c4].x, w4.x, a);
            a = fmaf(xr[c4].y, w4.y, a);
            a = fmaf(xr[c4].z, w4.z, a);
            a = fmaf(xr[c4].w, w4.w, a);
        }
        a += ob[co];
        out[((size_t)bb * 48 + co) * 12544 + pp] = fmaxf(a, 0.f);
    }
}

// ---------------------------------------------------------------------------
extern "C" void kernel_launch(void* const* d_in, const int* in_sizes, int n_in,
                              void* d_out, int out_size, void* d_ws, size_t ws_size,
                              hipStream_t stream) {
    const float* x     = (const float*)d_in[0];
    const float* up_w  = (const float*)d_in[1];
    const float* up_b  = (const float*)d_in[2];
    const float* bn_g  = (const float*)d_in[3];
    const float* bn_b  = (const float*)d_in[4];
    const float* bn_m  = (const float*)d_in[5];
    const float* bn_v  = (const float*)d_in[6];
    const float* n1g   = (const float*)d_in[7];
    const float* n1b   = (const float*)d_in[8];
    const float* qkvw  = (const float*)d_in[9];
    const float* qkvb  = (const float*)d_in[10];
    const float* projw = (const float*)d_in[11];
    const float* projb = (const float*)d_in[12];
    const float* rel   = (const float*)d_in[13];
    const float* n2g   = (const float*)d_in[14];
    const float* n2b   = (const float*)d_in[15];
    const float* f1w   = (const float*)d_in[16];
    const float* f1b   = (const float*)d_in[17];
    const float* f2w   = (const float*)d_in[18];
    const float* f2b   = (const float*)d_in[19];
    const float* outw  = (const float*)d_in[20];
    const float* outb  = (const float*)d_in[21];
    float* out = (float*)d_out;

    char* base = (char*)d_ws;
    float* T  = (float*)base;                       base += (size_t)M_TOK * 96 * 4;
    u16* XBh  = (u16*)base;                         base += (size_t)M_TOK * 96 * 2;
    u16* BIGh = (u16*)base;                         base += (size_t)M_TOK * 384 * 2;
    u16* xT   = (u16*)base;                         base += (size_t)8 * 3136 * 192 * 2;
    u16* Wc   = (u16*)base;                         base += (size_t)16 * 96 * 192 * 2;
    u16* Wh   = (u16*)base;
    u16* qkvwh = Wh;
    u16* projwh = Wh + 55296;
    u16* f1wh = Wh + 73728;
    u16* f2wh = Wh + 147456;

    cast_w_kernel<<<864, 256, 0, stream>>>(qkvw, projw, f1w, f2w, Wh);
    fold_kernel<<<288, 256, 0, stream>>>(up_w, Wc);
    transpose_kernel<<<dim3(49, 8), 256, 0, stream>>>(x, xT);
    conv_mfma<<<dim3(49, 4, 8), 256, 0, stream>>>(xT, Wc, up_b, bn_g, bn_b, bn_m, bn_v, T);

    for (int blk = 0; blk < 2; blk++) {
        int shift = (blk == 0) ? 0 : 3;
        ln_kernel<<<M_TOK / 4, 256, 0, stream>>>(T, n1g + blk * 96, n1b + blk * 96, XBh);
        gemm_mfma<0><<<dim3(3, M_TOK / 128), 256, 0, stream>>>(
            XBh, qkvwh + blk * 27648, qkvb + blk * 288, BIGh, nullptr, 288, 96);
        attn_mfma<<<2048, 192, 0, stream>>>(BIGh, rel + blk * 1014, XBh, shift);
        gemm_mfma<2><<<dim3(1, M_TOK / 128), 256, 0, stream>>>(
            XBh, projwh + blk * 9216, projb + blk * 96, T, T, 96, 96);
        ln_kernel<<<M_TOK / 4, 256, 0, stream>>>(T, n2g + blk * 96, n2b + blk * 96, XBh);
        gemm_mfma<1><<<dim3(4, M_TOK / 128), 256, 0, stream>>>(
            XBh, f1wh + blk * 36864, f1b + blk * 384, BIGh, nullptr, 384, 96);
        gemm_mfma<2><<<dim3(1, M_TOK / 128), 256, 0, stream>>>(
            BIGh, f2wh + blk * 36864, f2b + blk * 96, T, T, 96, 384);
    }

    outconv_kernel<<<M_TOK / 64, 256, 0, stream>>>(T, outw, outb, out);
}

// Round 4
// 734.953 us; speedup vs baseline: 2.1998x; 1.0629x over previous
//
#include <hip/hip_runtime.h>
#include <math.h>

#define M_TOK 100352   // 8*112*112 tokens
#define NHEAD 6

typedef unsigned short u16;
typedef __attribute__((ext_vector_type(8))) short bf16x8;
typedef __attribute__((ext_vector_type(4))) float f32x4;
typedef __attribute__((ext_vector_type(4))) unsigned int u32x4;

__device__ inline float bf2f(u16 u) {
    union { float f; unsigned int i; } v; v.i = ((unsigned int)u) << 16; return v.f;
}
__device__ inline u16 f2bf(float f) {
    union { float f; unsigned int i; } v; v.f = f;
    unsigned int r = v.i + 0x7fffu + ((v.i >> 16) & 1u);
    return (u16)(r >> 16);
}

// ---------------------------------------------------------------------------
// Cast all GEMM weights f32 -> bf16 into Wh.
// ---------------------------------------------------------------------------
__global__ __launch_bounds__(256) void cast_w_kernel(const float* __restrict__ qkvw,
        const float* __restrict__ projw, const float* __restrict__ f1w,
        const float* __restrict__ f2w, u16* __restrict__ Wh) {
    int i = blockIdx.x * 256 + threadIdx.x;
    if (i < 55296) Wh[i] = f2bf(qkvw[i]);
    else if (i < 73728) Wh[i] = f2bf(projw[i - 55296]);
    else if (i < 147456) Wh[i] = f2bf(f1w[i - 73728]);
    else if (i < 221184) Wh[i] = f2bf(f2w[i - 147456]);
}

// ---------------------------------------------------------------------------
// Fold upsample+conv3x3 into 4 parity x 4 tap 2x2 kernels (verified).
// ---------------------------------------------------------------------------
__global__ __launch_bounds__(256) void fold_kernel(const float* __restrict__ up_w,
                                                   u16* __restrict__ Wc) {
    int idx = blockIdx.x * 256 + threadIdx.x;
    if (idx >= 96 * 4 * 192) return;
    int c2 = idx / 768;
    int rem = idx - c2 * 768;
    int p = rem / 192;
    int ci = rem - p * 192;
    int po = p >> 1, pw = p & 1;
    const float* w = up_w + (c2 * 192 + ci) * 9;
    float w9[9];
#pragma unroll
    for (int k = 0; k < 9; k++) w9[k] = w[k];
    float r0[3], r1[3];
#pragma unroll
    for (int kw = 0; kw < 3; kw++) {
        if (po == 0) { r0[kw] = w9[kw];              r1[kw] = w9[3 + kw] + w9[6 + kw]; }
        else         { r0[kw] = w9[kw] + w9[3 + kw]; r1[kw] = w9[6 + kw]; }
    }
    float o00, o01, o10, o11;
    if (pw == 0) { o00 = r0[0];         o01 = r0[1] + r0[2]; o10 = r1[0];         o11 = r1[1] + r1[2]; }
    else         { o00 = r0[0] + r0[1]; o01 = r0[2];         o10 = r1[0] + r1[1]; o11 = r1[2]; }
    size_t base = ((size_t)p * 4 * 96 + c2) * 192 + ci;
    Wc[base + 0 * 96 * 192] = f2bf(o00);
    Wc[base + 1 * 96 * 192] = f2bf(o01);
    Wc[base + 2 * 96 * 192] = f2bf(o10);
    Wc[base + 3 * 96 * 192] = f2bf(o11);
}

// ---------------------------------------------------------------------------
// Precompute attention bias tables: BT[blk][type][head][64][64] f32.
// type = (wh==15)*2 + (ww==15). Includes rel-pos bias + shift mask (blk 1),
// -1e30 for pad keys (k>=49), 0 for pad queries.
// ---------------------------------------------------------------------------
__global__ __launch_bounds__(256) void bias_gen(const float* __restrict__ rel,
                                                float* __restrict__ BT) {
    int blkid = blockIdx.x;                // blk*24 + type*6 + head
    int blk = blkid / 24;
    int rem = blkid - blk * 24;
    int type = rem / 6, head = rem - (rem / 6) * 6;
    const float* relp = rel + blk * 1014;
    bool shift = (blk == 1);
    for (int i = threadIdx.x; i < 4096; i += 256) {
        int a = i >> 6, k = i & 63;
        float v;
        if (k >= 49) v = -1e30f;
        else if (a >= 49) v = 0.f;
        else {
            int ah = (a * 37) >> 8, aw = a - ah * 7;
            int kh = (k * 37) >> 8, kw = k - kh * 7;
            v = relp[((ah - kh + 6) * 13 + (aw - kw + 6)) * 6 + head];
            if (shift) {
                int lha = (type & 2) ? (ah < 4 ? 1 : 2) : 0;
                int lwa = (type & 1) ? (aw < 4 ? 1 : 2) : 0;
                int lhk = (type & 2) ? (kh < 4 ? 1 : 2) : 0;
                int lwk = (type & 1) ? (kw < 4 ? 1 : 2) : 0;
                if (lha != lhk || lwa != lwk) v -= 100.f;
            }
        }
        BT[(size_t)blkid * 4096 + i] = v;
    }
}

// ---------------------------------------------------------------------------
// x [b][192][56][56] f32 -> xT [b][3136][192] bf16 (XOR-swizzled LDS).
// ---------------------------------------------------------------------------
__global__ __launch_bounds__(256) void transpose_kernel(const float* __restrict__ x,
                                                        u16* __restrict__ xT) {
    __shared__ unsigned int ts[64 * 96];
    int b = blockIdx.y;
    int pix0 = blockIdx.x * 64;
    int tid = threadIdx.x;
    int p = tid & 63, dg = tid >> 6;
    const float* xb = x + (size_t)b * 192 * 3136 + pix0 + p;
    for (int d = dg; d < 96; d += 4) {
        float v0 = xb[(size_t)(2 * d) * 3136];
        float v1 = xb[(size_t)(2 * d + 1) * 3136];
        unsigned int pk = ((unsigned int)f2bf(v1) << 16) | (unsigned int)f2bf(v0);
        ts[p * 96 + ((d & ~31) | ((d & 31) ^ (p & 31)))] = pk;
    }
    __syncthreads();
    for (int i = tid; i < 1536; i += 256) {
        int pp = i / 24, c = i - pp * 24;
        unsigned int r[4];
#pragma unroll
        for (int j = 0; j < 4; j++) {
            int d = c * 4 + j;
            r[j] = ts[pp * 96 + ((d & ~31) | ((d & 31) ^ (pp & 31)))];
        }
        u32x4 v = {r[0], r[1], r[2], r[3]};
        *(u32x4*)&xT[((size_t)b * 3136 + pix0 + pp) * 192 + c * 8] = v;
    }
}

// ---------------------------------------------------------------------------
// Implicit-GEMM conv via MFMA (unchanged from passing R2/R3).
// ---------------------------------------------------------------------------
__global__ __launch_bounds__(256) void conv_mfma(const u16* __restrict__ xT,
        const u16* __restrict__ Wc, const float* __restrict__ up_b,
        const float* __restrict__ bn_g, const float* __restrict__ bn_b,
        const float* __restrict__ bn_m, const float* __restrict__ bn_v,
        float* __restrict__ T) {
    __shared__ u16 xs[81 * 200];
    __shared__ u16 ws[96 * 104];
    int tile = blockIdx.x, p = blockIdx.y, b = blockIdx.z;
    int po = p >> 1, pw = p & 1;
    int a0 = (tile / 7) * 8, b0 = (tile % 7) * 8;
    int rro = a0 - 1 + po, cco = b0 - 1 + pw;
    int tid = threadIdx.x;
    int w = tid >> 6, lane = tid & 63, quad = lane >> 4, l16 = lane & 15;
    int mbase = (w & 1) * 32;
    int nt0 = (w >> 1) * 3;

    for (int i = tid; i < 1944; i += 256) {
        int pix = i / 24, c = i - pix * 24;
        int rr = pix / 9, cc = pix - rr * 9;
        int gr = rro + rr, gc = cco + cc;
        u32x4 v = {0u, 0u, 0u, 0u};
        if ((unsigned)gr < 56u && (unsigned)gc < 56u)
            v = *(const u32x4*)&xT[((size_t)b * 3136 + gr * 56 + gc) * 192 + c * 8];
        *(u32x4*)&xs[pix * 200 + c * 8] = v;
    }

    f32x4 zero = {0.f, 0.f, 0.f, 0.f};
    f32x4 acc[2][3];
#pragma unroll
    for (int mi = 0; mi < 2; mi++)
#pragma unroll
        for (int ni = 0; ni < 3; ni++) acc[mi][ni] = zero;

    int aoffp[2];
#pragma unroll
    for (int mi = 0; mi < 2; mi++) {
        int pixel = mbase + mi * 16 + l16;
        aoffp[mi] = ((pixel >> 3) * 9 + (pixel & 7)) * 200;
    }

    for (int tap = 0; tap < 4; tap++) {
        int di = tap >> 1, dj = tap & 1;
        int tsh = (di * 9 + dj) * 200;
        for (int kc = 0; kc < 2; kc++) {
            __syncthreads();
            for (int i = tid; i < 1152; i += 256) {
                int r = i / 12, c = i - r * 12;
                *(u32x4*)&ws[r * 104 + c * 8] =
                    *(const u32x4*)&Wc[(((size_t)p * 4 + tap) * 96 + r) * 192 + kc * 96 + c * 8];
            }
            __syncthreads();
#pragma unroll
            for (int kk = 0; kk < 3; kk++) {
                bf16x8 af[2], bfr[3];
#pragma unroll
                for (int mi = 0; mi < 2; mi++)
                    af[mi] = *(const bf16x8*)&xs[aoffp[mi] + tsh + kc * 96 + kk * 32 + quad * 8];
#pragma unroll
                for (int ni = 0; ni < 3; ni++)
                    bfr[ni] = *(const bf16x8*)&ws[((nt0 + ni) * 16 + l16) * 104 + kk * 32 + quad * 8];
#pragma unroll
                for (int mi = 0; mi < 2; mi++)
#pragma unroll
                    for (int ni = 0; ni < 3; ni++)
                        acc[mi][ni] = __builtin_amdgcn_mfma_f32_16x16x32_bf16(
                            af[mi], bfr[ni], acc[mi][ni], 0, 0, 0);
            }
        }
    }

#pragma unroll
    for (int ni = 0; ni < 3; ni++) {
        int c2 = (nt0 + ni) * 16 + l16;
        float sc = bn_g[c2] * rsqrtf(bn_v[c2] + 1e-5f);
        float sh = (up_b[c2] - bn_m[c2]) * sc + bn_b[c2];
#pragma unroll
        for (int mi = 0; mi < 2; mi++) {
#pragma unroll
            for (int reg = 0; reg < 4; reg++) {
                int pixel = mbase + mi * 16 + quad * 4 + reg;
                int pr = pixel >> 3, pc = pixel & 7;
                int oh = 2 * (a0 + pr) + po, ow = 2 * (b0 + pc) + pw;
                size_t tok = (size_t)b * 12544 + oh * 112 + ow;
                T[tok * 96 + c2] = fmaxf(acc[mi][ni][reg] * sc + sh, 0.f);
            }
        }
    }
}

// ---------------------------------------------------------------------------
// LayerNorm over C=96, f32 in -> bf16 out.
// ---------------------------------------------------------------------------
__global__ __launch_bounds__(256) void ln_kernel(const float* __restrict__ X,
        const float* __restrict__ g, const float* __restrict__ bta,
        u16* __restrict__ Y) {
    int tok = blockIdx.x * 4 + (threadIdx.x >> 6);
    int lane = threadIdx.x & 63;
    const float* row = X + (size_t)tok * 96;
    float x1 = row[lane];
    float x2 = (lane < 32) ? row[64 + lane] : 0.f;
    float s = x1 + x2, q = x1 * x1 + x2 * x2;
#pragma unroll
    for (int off = 32; off; off >>= 1) {
        s += __shfl_xor(s, off, 64);
        q += __shfl_xor(q, off, 64);
    }
    float mean = s * (1.f / 96.f);
    float var = q * (1.f / 96.f) - mean * mean;
    float rstd = rsqrtf(var + 1e-5f);
    u16* outp = Y + (size_t)tok * 96;
    outp[lane] = f2bf((x1 - mean) * rstd * g[lane] + bta[lane]);
    if (lane < 32) outp[64 + lane] = f2bf((x2 - mean) * rstd * g[64 + lane] + bta[64 + lane]);
}

// ---------------------------------------------------------------------------
// bf16 MFMA GEMM (unchanged from passing R2/R3).
// ---------------------------------------------------------------------------
template <int EPI>
__global__ __launch_bounds__(256) void gemm_mfma(const u16* __restrict__ A,
        const u16* __restrict__ W, const float* __restrict__ bias,
        void* Cout, const float* res, int N, int K) {
    __shared__ u16 As[128 * 104];
    __shared__ u16 Bs[96 * 104];
    int tid = threadIdx.x;
    int w = tid >> 6, lane = tid & 63, quad = lane >> 4, l16 = lane & 15;
    int n0 = blockIdx.x * 96;
    size_t m0 = (size_t)blockIdx.y * 128;
    int mbase = (w & 1) * 64;
    int nt0 = (w >> 1) * 3;

    f32x4 zero = {0.f, 0.f, 0.f, 0.f};
    f32x4 acc[4][3];
#pragma unroll
    for (int mi = 0; mi < 4; mi++)
#pragma unroll
        for (int ni = 0; ni < 3; ni++) acc[mi][ni] = zero;

    for (int k0 = 0; k0 < K; k0 += 96) {
        __syncthreads();
        for (int i = tid; i < 1536; i += 256) {
            int r = i / 12, c = i - r * 12;
            *(u32x4*)&As[r * 104 + c * 8] = *(const u32x4*)&A[(m0 + r) * K + k0 + c * 8];
        }
        for (int i = tid; i < 1152; i += 256) {
            int r = i / 12, c = i - r * 12;
            *(u32x4*)&Bs[r * 104 + c * 8] = *(const u32x4*)&W[(size_t)(n0 + r) * K + k0 + c * 8];
        }
        __syncthreads();
#pragma unroll
        for (int kk = 0; kk < 3; kk++) {
            bf16x8 af[4], bfr[3];
#pragma unroll
            for (int mi = 0; mi < 4; mi++)
                af[mi] = *(const bf16x8*)&As[(mbase + mi * 16 + l16) * 104 + kk * 32 + quad * 8];
#pragma unroll
            for (int ni = 0; ni < 3; ni++)
                bfr[ni] = *(const bf16x8*)&Bs[((nt0 + ni) * 16 + l16) * 104 + kk * 32 + quad * 8];
#pragma unroll
            for (int mi = 0; mi < 4; mi++)
#pragma unroll
                for (int ni = 0; ni < 3; ni++)
                    acc[mi][ni] = __builtin_amdgcn_mfma_f32_16x16x32_bf16(
                        af[mi], bfr[ni], acc[mi][ni], 0, 0, 0);
        }
    }

#pragma unroll
    for (int ni = 0; ni < 3; ni++) {
        int col = n0 + (nt0 + ni) * 16 + l16;
        float bv = bias[col];
#pragma unroll
        for (int mi = 0; mi < 4; mi++) {
            size_t rowb = m0 + mbase + mi * 16 + quad * 4;
#pragma unroll
            for (int reg = 0; reg < 4; reg++) {
                size_t row = rowb + reg;
                float v = acc[mi][ni][reg] + bv;
                if (EPI == 1) v = 0.5f * v * (1.f + erff(v * 0.70710678118654752f));
                if (EPI == 2) {
                    v += res[row * N + col];
                    ((float*)Cout)[row * N + col] = v;
                } else {
                    ((u16*)Cout)[row * N + col] = f2bf(v);
                }
            }
        }
    }
}

// ---------------------------------------------------------------------------
// MFMA window attention v2: S^T formulation, barrier-free.
// Block = 192 threads (3 waves); wave w -> heads {2w, 2w+1}.
// - Q/K fragments loaded directly from global (no LDS staging).
// - Bias+mask from precomputed BT table (16 dwordx4 loads + 64 FMA).
// - Softmax in-lane over (kt,reg); 2 shfl per query-tile; rinv per-lane.
// - P: 16 ds_write_b64 -> wave-private LDS -> 8 ds_read_b128 B-frags.
// - PV computes O^T (A=V^T from LDS, B=P rows) -> 4 dwordx2 stores.
// ---------------------------------------------------------------------------
__global__ __launch_bounds__(192, 3) void attn_mfma(const u16* __restrict__ qkv,
        const float* __restrict__ BT, u16* __restrict__ ao, int shift) {
    __shared__ u16 Pl[3][64 * 72];
    __shared__ u16 vts[3][16 * 72];

    int tid = threadIdx.x;
    int w = tid >> 6, lane = tid & 63, quad = lane >> 4, l16 = lane & 15;
    int Wd = blockIdx.x;
    int bb = Wd >> 8, wl = Wd & 255, wh = wl >> 4, ww = wl & 15;
    int type = ((wh == 15) ? 2 : 0) + ((ww == 15) ? 1 : 0);

    // per-lane token indices (a = t*16 + l16, clamped; plus a = lane for V)
    int toks4[4], tokV;
#pragma unroll
    for (int t = 0; t < 4; t++) {
        int a = t * 16 + l16; if (a > 48) a = 48;
        int r = (a * 37) >> 8, c = a - r * 7;
        int h = wh * 7 + r, wq = ww * 7 + c;
        if (shift) { h += 3; if (h >= 112) h -= 112; wq += 3; if (wq >= 112) wq -= 112; }
        toks4[t] = bb * 12544 + h * 112 + wq;
    }
    {
        int a = lane > 48 ? 48 : lane;
        int r = (a * 37) >> 8, c = a - r * 7;
        int h = wh * 7 + r, wq = ww * 7 + c;
        if (shift) { h += 3; if (h >= 112) h -= 112; wq += 3; if (wq >= 112) wq -= 112; }
        tokV = bb * 12544 + h * 112 + wq;
    }

    u16* Pw = Pl[w];
    u16* vw = vts[w];

    // zero pad keys 49..63 in vT (persist across both heads)
    for (int i = lane; i < 240; i += 64) {
        int rrow = i / 15, key = 49 + (i - rrow * 15);
        vw[rrow * 72 + key] = 0;
    }

    for (int hh = 0; hh < 2; hh++) {
        int head = w * 2 + hh;

        // ---- Q/K fragments: direct global loads (quads 0,1 real; 2,3 zero) ----
        union { u32x4 u; bf16x8 h; } qf[4], kf[4];
#pragma unroll
        for (int t = 0; t < 4; t++) {
            u32x4 zq = {0u, 0u, 0u, 0u}, zk = {0u, 0u, 0u, 0u};
            if (quad < 2) {
                const u16* rb = qkv + (size_t)toks4[t] * 288 + head * 16 + quad * 8;
                zq = *(const u32x4*)(rb);
                zk = *(const u32x4*)(rb + 96);
            }
            qf[t].u = zq; kf[t].u = zk;
        }

        // ---- stage V rows transposed into wave-private LDS ----
        if (lane < 49) {
            const u16* vb = qkv + (size_t)tokV * 288 + head * 16 + 192;
            union { u32x4 v; unsigned int u[4]; } v0, v1;
            v0.v = *(const u32x4*)(vb);
            v1.v = *(const u32x4*)(vb + 8);
#pragma unroll
            for (int j = 0; j < 4; j++) {
                vw[(2 * j) * 72 + lane]         = (u16)(v0.u[j] & 0xffffu);
                vw[(2 * j + 1) * 72 + lane]     = (u16)(v0.u[j] >> 16);
                vw[(8 + 2 * j) * 72 + lane]     = (u16)(v1.u[j] & 0xffffu);
                vw[(8 + 2 * j + 1) * 72 + lane] = (u16)(v1.u[j] >> 16);
            }
        }

        // ---- S^T[key][query]: A = K rows, B = Q rows ----
        f32x4 S[4][4];   // [kt][qt]
#pragma unroll
        for (int kt = 0; kt < 4; kt++)
#pragma unroll
            for (int qt = 0; qt < 4; qt++)
                S[kt][qt] = __builtin_amdgcn_mfma_f32_16x16x32_bf16(
                    kf[kt].h, qf[qt].h, f32x4{0.f, 0.f, 0.f, 0.f}, 0, 0, 0);

        // ---- bias + scale + softmax (per query-tile) ----
        const float* bbase = BT + (size_t)(type * 6 + head) * 4096;
        float rinv[4];
#pragma unroll
        for (int qt = 0; qt < 4; qt++) {
            f32x4 bv[4];
#pragma unroll
            for (int kt = 0; kt < 4; kt++)
                bv[kt] = *(const f32x4*)&bbase[(size_t)(qt * 16 + l16) * 64 + kt * 16 + quad * 4];
            float mx = -3e38f;
#pragma unroll
            for (int kt = 0; kt < 4; kt++)
#pragma unroll
                for (int r = 0; r < 4; r++) {
                    float v = fmaf(S[kt][qt][r], 0.25f, bv[kt][r]);
                    S[kt][qt][r] = v;
                    mx = fmaxf(mx, v);
                }
            mx = fmaxf(mx, __shfl_xor(mx, 16, 64));
            mx = fmaxf(mx, __shfl_xor(mx, 32, 64));
            float sm = 0.f;
#pragma unroll
            for (int kt = 0; kt < 4; kt++)
#pragma unroll
                for (int r = 0; r < 4; r++) {
                    float e = __expf(S[kt][qt][r] - mx);
                    S[kt][qt][r] = e;
                    sm += e;
                }
            sm += __shfl_xor(sm, 16, 64);
            sm += __shfl_xor(sm, 32, 64);
            rinv[qt] = 1.0f / sm;
        }

        // ---- P -> wave-private LDS ([query][key], stride 72), b64 writes ----
#pragma unroll
        for (int qt = 0; qt < 4; qt++)
#pragma unroll
            for (int kt = 0; kt < 4; kt++) {
                unsigned int d0 = ((unsigned int)f2bf(S[kt][qt][1]) << 16) | f2bf(S[kt][qt][0]);
                unsigned int d1 = ((unsigned int)f2bf(S[kt][qt][3]) << 16) | f2bf(S[kt][qt][2]);
                *(uint2*)&Pw[(qt * 16 + l16) * 72 + kt * 16 + quad * 4] = make_uint2(d0, d1);
            }

        // ---- PV: O^T[dim][query] = V^T · P^T ----
        bf16x8 vf[2];
#pragma unroll
        for (int ksp = 0; ksp < 2; ksp++)
            vf[ksp] = *(const bf16x8*)&vw[l16 * 72 + ksp * 32 + quad * 8];
#pragma unroll
        for (int qt = 0; qt < 4; qt++) {
            f32x4 O = {0.f, 0.f, 0.f, 0.f};
#pragma unroll
            for (int ksp = 0; ksp < 2; ksp++) {
                bf16x8 pf = *(const bf16x8*)&Pw[(qt * 16 + l16) * 72 + ksp * 32 + quad * 8];
                O = __builtin_amdgcn_mfma_f32_16x16x32_bf16(vf[ksp], pf, O, 0, 0, 0);
            }
            int a = qt * 16 + l16;
            if (a < 49) {
                float ri = rinv[qt];
                unsigned int d0 = ((unsigned int)f2bf(O[1] * ri) << 16) | f2bf(O[0] * ri);
                unsigned int d1 = ((unsigned int)f2bf(O[3] * ri) << 16) | f2bf(O[2] * ri);
                *(uint2*)&ao[(size_t)toks4[qt] * 96 + head * 16 + quad * 4] = make_uint2(d0, d1);
            }
        }
    }
}

// ---------------------------------------------------------------------------
// Final 1x1 conv (96->48) + ReLU.
// ---------------------------------------------------------------------------
__global__ __launch_bounds__(256) void outconv_kernel(const float* __restrict__ T,
        const float* __restrict__ ow, const float* __restrict__ ob,
        float* __restrict__ out) {
    __shared__ float ts[64 * 100];
    __shared__ float wsh[48 * 96];
    int tid = threadIdx.x;
    size_t tok0 = (size_t)blockIdx.x * 64;
    for (int i = tid; i < 6144; i += 256) {
        int tk = i / 96, c = i - tk * 96;
        ts[tk * 100 + c] = T[(tok0 + tk) * 96 + c];
    }
    for (int i = tid; i < 4608; i += 256) wsh[i] = ow[i];
    __syncthreads();
    int lane = tid & 63, wv = tid >> 6;
    float4 xr[24];
#pragma unroll
    for (int c4 = 0; c4 < 24; c4++) xr[c4] = *(const float4*)&ts[lane * 100 + c4 * 4];
    int tok = (int)tok0 + lane;
    int bb = tok / 12544, pp = tok - bb * 12544;
    for (int co = wv; co < 48; co += 4) {
        float a = 0.f;
#pragma unroll
        for (int c4 = 0; c4 < 24; c4++) {
            float4 w4 = *(const float4*)&wsh[co * 96 + c4 * 4];
            a = fmaf(xr[c4].x, w4.x, a);
            a = fmaf(xr[c4].y, w4.y, a);
            a = fmaf(xr[c4].z, w4.z, a);
            a = fmaf(xr[c4].w, w4.w, a);
        }
        a += ob[co];
        out[((size_t)bb * 48 + co) * 12544 + pp] = fmaxf(a, 0.f);
    }
}

// ---------------------------------------------------------------------------
extern "C" void kernel_launch(void* const* d_in, const int* in_sizes, int n_in,
                              void* d_out, int out_size, void* d_ws, size_t ws_size,
                              hipStream_t stream) {
    const float* x     = (const float*)d_in[0];
    const float* up_w  = (const float*)d_in[1];
    const float* up_b  = (const float*)d_in[2];
    const float* bn_g  = (const float*)d_in[3];
    const float* bn_b  = (const float*)d_in[4];
    const float* bn_m  = (const float*)d_in[5];
    const float* bn_v  = (const float*)d_in[6];
    const float* n1g   = (const float*)d_in[7];
    const float* n1b   = (const float*)d_in[8];
    const float* qkvw  = (const float*)d_in[9];
    const float* qkvb  = (const float*)d_in[10];
    const float* projw = (const float*)d_in[11];
    const float* projb = (const float*)d_in[12];
    const float* rel   = (const float*)d_in[13];
    const float* n2g   = (const float*)d_in[14];
    const float* n2b   = (const float*)d_in[15];
    const float* f1w   = (const float*)d_in[16];
    const float* f1b   = (const float*)d_in[17];
    const float* f2w   = (const float*)d_in[18];
    const float* f2b   = (const float*)d_in[19];
    const float* outw  = (const float*)d_in[20];
    const float* outb  = (const float*)d_in[21];
    float* out = (float*)d_out;

    char* base = (char*)d_ws;
    float* T  = (float*)base;                       base += (size_t)M_TOK * 96 * 4;
    u16* XBh  = (u16*)base;                         base += (size_t)M_TOK * 96 * 2;
    u16* BIGh = (u16*)base;                         base += (size_t)M_TOK * 384 * 2;
    u16* xT   = (u16*)base;                         base += (size_t)8 * 3136 * 192 * 2;
    u16* Wc   = (u16*)base;                         base += (size_t)16 * 96 * 192 * 2;
    u16* Wh   = (u16*)base;                         base += (size_t)221184 * 2;
    float* BT = (float*)base;                       // 2*4*6*4096 f32 = 786 KB
    u16* qkvwh = Wh;
    u16* projwh = Wh + 55296;
    u16* f1wh = Wh + 73728;
    u16* f2wh = Wh + 147456;

    cast_w_kernel<<<864, 256, 0, stream>>>(qkvw, projw, f1w, f2w, Wh);
    fold_kernel<<<288, 256, 0, stream>>>(up_w, Wc);
    bias_gen<<<48, 256, 0, stream>>>(rel, BT);
    transpose_kernel<<<dim3(49, 8), 256, 0, stream>>>(x, xT);
    conv_mfma<<<dim3(49, 4, 8), 256, 0, stream>>>(xT, Wc, up_b, bn_g, bn_b, bn_m, bn_v, T);

    for (int blk = 0; blk < 2; blk++) {
        int shift = (blk == 0) ? 0 : 3;
        ln_kernel<<<M_TOK / 4, 256, 0, stream>>>(T, n1g + blk * 96, n1b + blk * 96, XBh);
        gemm_mfma<0><<<dim3(3, M_TOK / 128), 256, 0, stream>>>(
            XBh, qkvwh + blk * 27648, qkvb + blk * 288, BIGh, nullptr, 288, 96);
        attn_mfma<<<2048, 192, 0, stream>>>(BIGh, BT + (size_t)blk * 98304, XBh, shift);
        gemm_mfma<2><<<dim3(1, M_TOK / 128), 256, 0, stream>>>(
            XBh, projwh + blk * 9216, projb + blk * 96, T, T, 96, 96);
        ln_kernel<<<M_TOK / 4, 256, 0, stream>>>(T, n2g + blk * 96, n2b + blk * 96, XBh);
        gemm_mfma<1><<<dim3(4, M_TOK / 128), 256, 0, stream>>>(
            XBh, f1wh + blk * 36864, f1b + blk * 384, BIGh, nullptr, 384, 96);
        gemm_mfma<2><<<dim3(1, M_TOK / 128), 256, 0, stream>>>(
            BIGh, f2wh + blk * 36864, f2b + blk * 96, T, T, 96, 384);
    }

    outconv_kernel<<<M_TOK / 64, 256, 0, stream>>>(T, outw, outb, out);
}

// Round 5
// 636.121 us; speedup vs baseline: 2.5416x; 1.1554x over previous
//
#include <hip/hip_runtime.h>
#include <math.h>

#define M_TOK 100352   // 8*112*112 tokens
#define NHEAD 6

typedef unsigned short u16;
typedef __attribute__((ext_vector_type(8))) short bf16x8;
typedef __attribute__((ext_vector_type(4))) float f32x4;
typedef __attribute__((ext_vector_type(4))) unsigned int u32x4;

__device__ inline float bf2f(u16 u) {
    union { float f; unsigned int i; } v; v.i = ((unsigned int)u) << 16; return v.f;
}
__device__ inline u16 f2bf(float f) {
    union { float f; unsigned int i; } v; v.f = f;
    unsigned int r = v.i + 0x7fffu + ((v.i >> 16) & 1u);
    return (u16)(r >> 16);
}

// ---------------------------------------------------------------------------
// Cast all GEMM weights f32 -> bf16 into Wh (now incl. out_w 48x96).
// ---------------------------------------------------------------------------
__global__ __launch_bounds__(256) void cast_w_kernel(const float* __restrict__ qkvw,
        const float* __restrict__ projw, const float* __restrict__ f1w,
        const float* __restrict__ f2w, const float* __restrict__ outw,
        u16* __restrict__ Wh) {
    int i = blockIdx.x * 256 + threadIdx.x;
    if (i < 55296) Wh[i] = f2bf(qkvw[i]);
    else if (i < 73728) Wh[i] = f2bf(projw[i - 55296]);
    else if (i < 147456) Wh[i] = f2bf(f1w[i - 73728]);
    else if (i < 221184) Wh[i] = f2bf(f2w[i - 147456]);
    else if (i < 225792) Wh[i] = f2bf(outw[i - 221184]);
}

// ---------------------------------------------------------------------------
// Fold upsample+conv3x3 into 4 parity x 4 tap 2x2 kernels (verified).
// ---------------------------------------------------------------------------
__global__ __launch_bounds__(256) void fold_kernel(const float* __restrict__ up_w,
                                                   u16* __restrict__ Wc) {
    int idx = blockIdx.x * 256 + threadIdx.x;
    if (idx >= 96 * 4 * 192) return;
    int c2 = idx / 768;
    int rem = idx - c2 * 768;
    int p = rem / 192;
    int ci = rem - p * 192;
    int po = p >> 1, pw = p & 1;
    const float* w = up_w + (c2 * 192 + ci) * 9;
    float w9[9];
#pragma unroll
    for (int k = 0; k < 9; k++) w9[k] = w[k];
    float r0[3], r1[3];
#pragma unroll
    for (int kw = 0; kw < 3; kw++) {
        if (po == 0) { r0[kw] = w9[kw];              r1[kw] = w9[3 + kw] + w9[6 + kw]; }
        else         { r0[kw] = w9[kw] + w9[3 + kw]; r1[kw] = w9[6 + kw]; }
    }
    float o00, o01, o10, o11;
    if (pw == 0) { o00 = r0[0];         o01 = r0[1] + r0[2]; o10 = r1[0];         o11 = r1[1] + r1[2]; }
    else         { o00 = r0[0] + r0[1]; o01 = r0[2];         o10 = r1[0] + r1[1]; o11 = r1[2]; }
    size_t base = ((size_t)p * 4 * 96 + c2) * 192 + ci;
    Wc[base + 0 * 96 * 192] = f2bf(o00);
    Wc[base + 1 * 96 * 192] = f2bf(o01);
    Wc[base + 2 * 96 * 192] = f2bf(o10);
    Wc[base + 3 * 96 * 192] = f2bf(o11);
}

// ---------------------------------------------------------------------------
// Precompute attention bias tables: BT[blk][type][head][64][64] f32.
// ---------------------------------------------------------------------------
__global__ __launch_bounds__(256) void bias_gen(const float* __restrict__ rel,
                                                float* __restrict__ BT) {
    int blkid = blockIdx.x;                // blk*24 + type*6 + head
    int blk = blkid / 24;
    int rem = blkid - blk * 24;
    int type = rem / 6, head = rem - (rem / 6) * 6;
    const float* relp = rel + blk * 1014;
    bool shift = (blk == 1);
    for (int i = threadIdx.x; i < 4096; i += 256) {
        int a = i >> 6, k = i & 63;
        float v;
        if (k >= 49) v = -1e30f;
        else if (a >= 49) v = 0.f;
        else {
            int ah = (a * 37) >> 8, aw = a - ah * 7;
            int kh = (k * 37) >> 8, kw = k - kh * 7;
            v = relp[((ah - kh + 6) * 13 + (aw - kw + 6)) * 6 + head];
            if (shift) {
                int lha = (type & 2) ? (ah < 4 ? 1 : 2) : 0;
                int lwa = (type & 1) ? (aw < 4 ? 1 : 2) : 0;
                int lhk = (type & 2) ? (kh < 4 ? 1 : 2) : 0;
                int lwk = (type & 1) ? (kw < 4 ? 1 : 2) : 0;
                if (lha != lhk || lwa != lwk) v -= 100.f;
            }
        }
        BT[(size_t)blkid * 4096 + i] = v;
    }
}

// ---------------------------------------------------------------------------
// x [b][192][56][56] f32 -> xT [b][3136][192] bf16 (XOR-swizzled LDS).
// ---------------------------------------------------------------------------
__global__ __launch_bounds__(256) void transpose_kernel(const float* __restrict__ x,
                                                        u16* __restrict__ xT) {
    __shared__ unsigned int ts[64 * 96];
    int b = blockIdx.y;
    int pix0 = blockIdx.x * 64;
    int tid = threadIdx.x;
    int p = tid & 63, dg = tid >> 6;
    const float* xb = x + (size_t)b * 192 * 3136 + pix0 + p;
    for (int d = dg; d < 96; d += 4) {
        float v0 = xb[(size_t)(2 * d) * 3136];
        float v1 = xb[(size_t)(2 * d + 1) * 3136];
        unsigned int pk = ((unsigned int)f2bf(v1) << 16) | (unsigned int)f2bf(v0);
        ts[p * 96 + ((d & ~31) | ((d & 31) ^ (p & 31)))] = pk;
    }
    __syncthreads();
    for (int i = tid; i < 1536; i += 256) {
        int pp = i / 24, c = i - pp * 24;
        unsigned int r[4];
#pragma unroll
        for (int j = 0; j < 4; j++) {
            int d = c * 4 + j;
            r[j] = ts[pp * 96 + ((d & ~31) | ((d & 31) ^ (pp & 31)))];
        }
        u32x4 v = {r[0], r[1], r[2], r[3]};
        *(u32x4*)&xT[((size_t)b * 3136 + pix0 + pp) * 192 + c * 8] = v;
    }
}

// ---------------------------------------------------------------------------
// Implicit-GEMM conv via MFMA (unchanged from passing R2-R4).
// ---------------------------------------------------------------------------
__global__ __launch_bounds__(256) void conv_mfma(const u16* __restrict__ xT,
        const u16* __restrict__ Wc, const float* __restrict__ up_b,
        const float* __restrict__ bn_g, const float* __restrict__ bn_b,
        const float* __restrict__ bn_m, const float* __restrict__ bn_v,
        float* __restrict__ T) {
    __shared__ u16 xs[81 * 200];
    __shared__ u16 ws[96 * 104];
    int tile = blockIdx.x, p = blockIdx.y, b = blockIdx.z;
    int po = p >> 1, pw = p & 1;
    int a0 = (tile / 7) * 8, b0 = (tile % 7) * 8;
    int rro = a0 - 1 + po, cco = b0 - 1 + pw;
    int tid = threadIdx.x;
    int w = tid >> 6, lane = tid & 63, quad = lane >> 4, l16 = lane & 15;
    int mbase = (w & 1) * 32;
    int nt0 = (w >> 1) * 3;

    for (int i = tid; i < 1944; i += 256) {
        int pix = i / 24, c = i - pix * 24;
        int rr = pix / 9, cc = pix - rr * 9;
        int gr = rro + rr, gc = cco + cc;
        u32x4 v = {0u, 0u, 0u, 0u};
        if ((unsigned)gr < 56u && (unsigned)gc < 56u)
            v = *(const u32x4*)&xT[((size_t)b * 3136 + gr * 56 + gc) * 192 + c * 8];
        *(u32x4*)&xs[pix * 200 + c * 8] = v;
    }

    f32x4 zero = {0.f, 0.f, 0.f, 0.f};
    f32x4 acc[2][3];
#pragma unroll
    for (int mi = 0; mi < 2; mi++)
#pragma unroll
        for (int ni = 0; ni < 3; ni++) acc[mi][ni] = zero;

    int aoffp[2];
#pragma unroll
    for (int mi = 0; mi < 2; mi++) {
        int pixel = mbase + mi * 16 + l16;
        aoffp[mi] = ((pixel >> 3) * 9 + (pixel & 7)) * 200;
    }

    for (int tap = 0; tap < 4; tap++) {
        int di = tap >> 1, dj = tap & 1;
        int tsh = (di * 9 + dj) * 200;
        for (int kc = 0; kc < 2; kc++) {
            __syncthreads();
            for (int i = tid; i < 1152; i += 256) {
                int r = i / 12, c = i - r * 12;
                *(u32x4*)&ws[r * 104 + c * 8] =
                    *(const u32x4*)&Wc[(((size_t)p * 4 + tap) * 96 + r) * 192 + kc * 96 + c * 8];
            }
            __syncthreads();
#pragma unroll
            for (int kk = 0; kk < 3; kk++) {
                bf16x8 af[2], bfr[3];
#pragma unroll
                for (int mi = 0; mi < 2; mi++)
                    af[mi] = *(const bf16x8*)&xs[aoffp[mi] + tsh + kc * 96 + kk * 32 + quad * 8];
#pragma unroll
                for (int ni = 0; ni < 3; ni++)
                    bfr[ni] = *(const bf16x8*)&ws[((nt0 + ni) * 16 + l16) * 104 + kk * 32 + quad * 8];
#pragma unroll
                for (int mi = 0; mi < 2; mi++)
#pragma unroll
                    for (int ni = 0; ni < 3; ni++)
                        acc[mi][ni] = __builtin_amdgcn_mfma_f32_16x16x32_bf16(
                            af[mi], bfr[ni], acc[mi][ni], 0, 0, 0);
            }
        }
    }

#pragma unroll
    for (int ni = 0; ni < 3; ni++) {
        int c2 = (nt0 + ni) * 16 + l16;
        float sc = bn_g[c2] * rsqrtf(bn_v[c2] + 1e-5f);
        float sh = (up_b[c2] - bn_m[c2]) * sc + bn_b[c2];
#pragma unroll
        for (int mi = 0; mi < 2; mi++) {
#pragma unroll
            for (int reg = 0; reg < 4; reg++) {
                int pixel = mbase + mi * 16 + quad * 4 + reg;
                int pr = pixel >> 3, pc = pixel & 7;
                int oh = 2 * (a0 + pr) + po, ow = 2 * (b0 + pc) + pw;
                size_t tok = (size_t)b * 12544 + oh * 112 + ow;
                T[tok * 96 + c2] = fmaxf(acc[mi][ni][reg] * sc + sh, 0.f);
            }
        }
    }
}

// ---------------------------------------------------------------------------
// Fused LN + GEMM, transposed-C epilogue. Y = LN(T) @ W^T + bias [,GELU].
// A-operand = W rows (output cols), B-operand = LN'd T rows (output rows).
// BM=128, BN=96, K=96 (single tile = exact LN). EPI 0: bias; 1: bias+GELU.
// Output bf16, vectorized dwordx2 stores (lane holds 4 consecutive cols).
// ---------------------------------------------------------------------------
template <int EPI>
__global__ __launch_bounds__(256) void gemm_ln(const float* __restrict__ Tin,
        const u16* __restrict__ W, const float* __restrict__ g,
        const float* __restrict__ bt, const float* __restrict__ bias,
        u16* __restrict__ Cout, int N) {
    __shared__ u16 Xs[128 * 104];
    __shared__ u16 Ws[96 * 104];
    __shared__ __align__(16) float gb[192];
    int tid = threadIdx.x;
    int w = tid >> 6, lane = tid & 63, quad = lane >> 4, l16 = lane & 15;
    int mh = w & 1, nh = w >> 1;
    int n0 = blockIdx.x * 96;
    size_t m0 = (size_t)blockIdx.y * 128;

    if (tid < 192) gb[tid] = (tid < 96) ? g[tid] : bt[tid - 96];
    for (int i = tid; i < 1152; i += 256) {
        int r = i / 12, c = i - r * 12;
        *(u32x4*)&Ws[r * 104 + c * 8] = *(const u32x4*)&W[(size_t)(n0 + r) * 96 + c * 8];
    }
    __syncthreads();   // gb ready

    {   // stage LN(T) rows -> Xs bf16; thread-pair per row
        int r = tid >> 1, h = tid & 1;
        const float* rowp = Tin + (m0 + r) * 96 + h * 48;
        float4 v[12];
        float s = 0.f, q = 0.f;
#pragma unroll
        for (int j = 0; j < 12; j++) {
            v[j] = *(const float4*)&rowp[j * 4];
            s += v[j].x + v[j].y + v[j].z + v[j].w;
            q += v[j].x * v[j].x + v[j].y * v[j].y + v[j].z * v[j].z + v[j].w * v[j].w;
        }
        s += __shfl_xor(s, 1, 64);
        q += __shfl_xor(q, 1, 64);
        float mean = s * (1.f / 96.f);
        float var = q * (1.f / 96.f) - mean * mean;
        float rstd = rsqrtf(var + 1e-5f);
#pragma unroll
        for (int j = 0; j < 12; j += 2) {
            float4 g0 = *(const float4*)&gb[h * 48 + j * 4];
            float4 g1 = *(const float4*)&gb[h * 48 + j * 4 + 4];
            float4 b0 = *(const float4*)&gb[96 + h * 48 + j * 4];
            float4 b1 = *(const float4*)&gb[96 + h * 48 + j * 4 + 4];
            float y0 = (v[j].x - mean) * rstd * g0.x + b0.x;
            float y1 = (v[j].y - mean) * rstd * g0.y + b0.y;
            float y2 = (v[j].z - mean) * rstd * g0.z + b0.z;
            float y3 = (v[j].w - mean) * rstd * g0.w + b0.w;
            float y4 = (v[j + 1].x - mean) * rstd * g1.x + b1.x;
            float y5 = (v[j + 1].y - mean) * rstd * g1.y + b1.y;
            float y6 = (v[j + 1].z - mean) * rstd * g1.z + b1.z;
            float y7 = (v[j + 1].w - mean) * rstd * g1.w + b1.w;
            u32x4 pk = {((unsigned int)f2bf(y1) << 16) | f2bf(y0),
                        ((unsigned int)f2bf(y3) << 16) | f2bf(y2),
                        ((unsigned int)f2bf(y5) << 16) | f2bf(y4),
                        ((unsigned int)f2bf(y7) << 16) | f2bf(y6)};
            *(u32x4*)&Xs[r * 104 + h * 48 + j * 4] = pk;
        }
    }
    __syncthreads();

    f32x4 acc[3][4];
#pragma unroll
    for (int ni = 0; ni < 3; ni++)
#pragma unroll
        for (int mi = 0; mi < 4; mi++) acc[ni][mi] = f32x4{0.f, 0.f, 0.f, 0.f};
#pragma unroll
    for (int kk = 0; kk < 3; kk++) {
        bf16x8 af[3], bf[4];
#pragma unroll
        for (int ni = 0; ni < 3; ni++)
            af[ni] = *(const bf16x8*)&Ws[(nh * 48 + ni * 16 + l16) * 104 + kk * 32 + quad * 8];
#pragma unroll
        for (int mi = 0; mi < 4; mi++)
            bf[mi] = *(const bf16x8*)&Xs[(mh * 64 + mi * 16 + l16) * 104 + kk * 32 + quad * 8];
#pragma unroll
        for (int ni = 0; ni < 3; ni++)
#pragma unroll
            for (int mi = 0; mi < 4; mi++)
                acc[ni][mi] = __builtin_amdgcn_mfma_f32_16x16x32_bf16(
                    af[ni], bf[mi], acc[ni][mi], 0, 0, 0);
    }

#pragma unroll
    for (int ni = 0; ni < 3; ni++) {
        int colb = n0 + nh * 48 + ni * 16 + quad * 4;
        float4 bv = *(const float4*)&bias[colb];
#pragma unroll
        for (int mi = 0; mi < 4; mi++) {
            size_t row = m0 + mh * 64 + mi * 16 + l16;
            float v0 = acc[ni][mi][0] + bv.x, v1 = acc[ni][mi][1] + bv.y;
            float v2 = acc[ni][mi][2] + bv.z, v3 = acc[ni][mi][3] + bv.w;
            if (EPI == 1) {
                v0 = 0.5f * v0 * (1.f + erff(v0 * 0.70710678118654752f));
                v1 = 0.5f * v1 * (1.f + erff(v1 * 0.70710678118654752f));
                v2 = 0.5f * v2 * (1.f + erff(v2 * 0.70710678118654752f));
                v3 = 0.5f * v3 * (1.f + erff(v3 * 0.70710678118654752f));
            }
            unsigned int d0 = ((unsigned int)f2bf(v1) << 16) | f2bf(v0);
            unsigned int d1 = ((unsigned int)f2bf(v3) << 16) | f2bf(v2);
            *(uint2*)&Cout[row * N + colb] = make_uint2(d0, d1);
        }
    }
}

// ---------------------------------------------------------------------------
// GEMM + bias + residual, transposed-C epilogue. Yf32 = Xh @ W^T + bias + res.
// N=96 fixed, K in {96, 384}. Vectorized dwordx4 res-load/store.
// ---------------------------------------------------------------------------
__global__ __launch_bounds__(256) void gemm_res(const u16* __restrict__ Xh,
        const u16* __restrict__ W, const float* __restrict__ bias,
        const float* __restrict__ res, float* __restrict__ Cout, int K) {
    __shared__ u16 Xs[128 * 104];
    __shared__ u16 Ws[96 * 104];
    int tid = threadIdx.x;
    int w = tid >> 6, lane = tid & 63, quad = lane >> 4, l16 = lane & 15;
    int mh = w & 1, nh = w >> 1;
    size_t m0 = (size_t)blockIdx.x * 128;

    f32x4 acc[3][4];
#pragma unroll
    for (int ni = 0; ni < 3; ni++)
#pragma unroll
        for (int mi = 0; mi < 4; mi++) acc[ni][mi] = f32x4{0.f, 0.f, 0.f, 0.f};

    for (int k0 = 0; k0 < K; k0 += 96) {
        __syncthreads();
        for (int i = tid; i < 1536; i += 256) {
            int r = i / 12, c = i - r * 12;
            *(u32x4*)&Xs[r * 104 + c * 8] = *(const u32x4*)&Xh[(m0 + r) * K + k0 + c * 8];
        }
        for (int i = tid; i < 1152; i += 256) {
            int r = i / 12, c = i - r * 12;
            *(u32x4*)&Ws[r * 104 + c * 8] = *(const u32x4*)&W[(size_t)r * K + k0 + c * 8];
        }
        __syncthreads();
#pragma unroll
        for (int kk = 0; kk < 3; kk++) {
            bf16x8 af[3], bf[4];
#pragma unroll
            for (int ni = 0; ni < 3; ni++)
                af[ni] = *(const bf16x8*)&Ws[(nh * 48 + ni * 16 + l16) * 104 + kk * 32 + quad * 8];
#pragma unroll
            for (int mi = 0; mi < 4; mi++)
                bf[mi] = *(const bf16x8*)&Xs[(mh * 64 + mi * 16 + l16) * 104 + kk * 32 + quad * 8];
#pragma unroll
            for (int ni = 0; ni < 3; ni++)
#pragma unroll
                for (int mi = 0; mi < 4; mi++)
                    acc[ni][mi] = __builtin_amdgcn_mfma_f32_16x16x32_bf16(
                        af[ni], bf[mi], acc[ni][mi], 0, 0, 0);
        }
    }

#pragma unroll
    for (int ni = 0; ni < 3; ni++) {
        int colb = nh * 48 + ni * 16 + quad * 4;
        float4 bv = *(const float4*)&bias[colb];
#pragma unroll
        for (int mi = 0; mi < 4; mi++) {
            size_t row = m0 + mh * 64 + mi * 16 + l16;
            float4 rv = *(const float4*)&res[row * 96 + colb];
            f32x4 o = {acc[ni][mi][0] + bv.x + rv.x, acc[ni][mi][1] + bv.y + rv.y,
                       acc[ni][mi][2] + bv.z + rv.z, acc[ni][mi][3] + bv.w + rv.w};
            *(f32x4*)&Cout[row * 96 + colb] = o;
        }
    }
}

// ---------------------------------------------------------------------------
// MFMA window attention v2 (unchanged from passing R4).
// ---------------------------------------------------------------------------
__global__ __launch_bounds__(192, 3) void attn_mfma(const u16* __restrict__ qkv,
        const float* __restrict__ BT, u16* __restrict__ ao, int shift) {
    __shared__ u16 Pl[3][64 * 72];
    __shared__ u16 vts[3][16 * 72];

    int tid = threadIdx.x;
    int w = tid >> 6, lane = tid & 63, quad = lane >> 4, l16 = lane & 15;
    int Wd = blockIdx.x;
    int bb = Wd >> 8, wl = Wd & 255, wh = wl >> 4, ww = wl & 15;
    int type = ((wh == 15) ? 2 : 0) + ((ww == 15) ? 1 : 0);

    int toks4[4], tokV;
#pragma unroll
    for (int t = 0; t < 4; t++) {
        int a = t * 16 + l16; if (a > 48) a = 48;
        int r = (a * 37) >> 8, c = a - r * 7;
        int h = wh * 7 + r, wq = ww * 7 + c;
        if (shift) { h += 3; if (h >= 112) h -= 112; wq += 3; if (wq >= 112) wq -= 112; }
        toks4[t] = bb * 12544 + h * 112 + wq;
    }
    {
        int a = lane > 48 ? 48 : lane;
        int r = (a * 37) >> 8, c = a - r * 7;
        int h = wh * 7 + r, wq = ww * 7 + c;
        if (shift) { h += 3; if (h >= 112) h -= 112; wq += 3; if (wq >= 112) wq -= 112; }
        tokV = bb * 12544 + h * 112 + wq;
    }

    u16* Pw = Pl[w];
    u16* vw = vts[w];

    for (int i = lane; i < 240; i += 64) {
        int rrow = i / 15, key = 49 + (i - rrow * 15);
        vw[rrow * 72 + key] = 0;
    }

    for (int hh = 0; hh < 2; hh++) {
        int head = w * 2 + hh;

        union { u32x4 u; bf16x8 h; } qf[4], kf[4];
#pragma unroll
        for (int t = 0; t < 4; t++) {
            u32x4 zq = {0u, 0u, 0u, 0u}, zk = {0u, 0u, 0u, 0u};
            if (quad < 2) {
                const u16* rb = qkv + (size_t)toks4[t] * 288 + head * 16 + quad * 8;
                zq = *(const u32x4*)(rb);
                zk = *(const u32x4*)(rb + 96);
            }
            qf[t].u = zq; kf[t].u = zk;
        }

        if (lane < 49) {
            const u16* vb = qkv + (size_t)tokV * 288 + head * 16 + 192;
            union { u32x4 v; unsigned int u[4]; } v0, v1;
            v0.v = *(const u32x4*)(vb);
            v1.v = *(const u32x4*)(vb + 8);
#pragma unroll
            for (int j = 0; j < 4; j++) {
                vw[(2 * j) * 72 + lane]         = (u16)(v0.u[j] & 0xffffu);
                vw[(2 * j + 1) * 72 + lane]     = (u16)(v0.u[j] >> 16);
                vw[(8 + 2 * j) * 72 + lane]     = (u16)(v1.u[j] & 0xffffu);
                vw[(8 + 2 * j + 1) * 72 + lane] = (u16)(v1.u[j] >> 16);
            }
        }

        f32x4 S[4][4];
#pragma unroll
        for (int kt = 0; kt < 4; kt++)
#pragma unroll
            for (int qt = 0; qt < 4; qt++)
                S[kt][qt] = __builtin_amdgcn_mfma_f32_16x16x32_bf16(
                    kf[kt].h, qf[qt].h, f32x4{0.f, 0.f, 0.f, 0.f}, 0, 0, 0);

        const float* bbase = BT + (size_t)(type * 6 + head) * 4096;
        float rinv[4];
#pragma unroll
        for (int qt = 0; qt < 4; qt++) {
            f32x4 bv[4];
#pragma unroll
            for (int kt = 0; kt < 4; kt++)
                bv[kt] = *(const f32x4*)&bbase[(size_t)(qt * 16 + l16) * 64 + kt * 16 + quad * 4];
            float mx = -3e38f;
#pragma unroll
            for (int kt = 0; kt < 4; kt++)
#pragma unroll
                for (int r = 0; r < 4; r++) {
                    float v = fmaf(S[kt][qt][r], 0.25f, bv[kt][r]);
                    S[kt][qt][r] = v;
                    mx = fmaxf(mx, v);
                }
            mx = fmaxf(mx, __shfl_xor(mx, 16, 64));
            mx = fmaxf(mx, __shfl_xor(mx, 32, 64));
            float sm = 0.f;
#pragma unroll
            for (int kt = 0; kt < 4; kt++)
#pragma unroll
                for (int r = 0; r < 4; r++) {
                    float e = __expf(S[kt][qt][r] - mx);
                    S[kt][qt][r] = e;
                    sm += e;
                }
            sm += __shfl_xor(sm, 16, 64);
            sm += __shfl_xor(sm, 32, 64);
            rinv[qt] = 1.0f / sm;
        }

#pragma unroll
        for (int qt = 0; qt < 4; qt++)
#pragma unroll
            for (int kt = 0; kt < 4; kt++) {
                unsigned int d0 = ((unsigned int)f2bf(S[kt][qt][1]) << 16) | f2bf(S[kt][qt][0]);
                unsigned int d1 = ((unsigned int)f2bf(S[kt][qt][3]) << 16) | f2bf(S[kt][qt][2]);
                *(uint2*)&Pw[(qt * 16 + l16) * 72 + kt * 16 + quad * 4] = make_uint2(d0, d1);
            }

        bf16x8 vf[2];
#pragma unroll
        for (int ksp = 0; ksp < 2; ksp++)
            vf[ksp] = *(const bf16x8*)&vw[l16 * 72 + ksp * 32 + quad * 8];
#pragma unroll
        for (int qt = 0; qt < 4; qt++) {
            f32x4 O = {0.f, 0.f, 0.f, 0.f};
#pragma unroll
            for (int ksp = 0; ksp < 2; ksp++) {
                bf16x8 pf = *(const bf16x8*)&Pw[(qt * 16 + l16) * 72 + ksp * 32 + quad * 8];
                O = __builtin_amdgcn_mfma_f32_16x16x32_bf16(vf[ksp], pf, O, 0, 0, 0);
            }
            int a = qt * 16 + l16;
            if (a < 49) {
                float ri = rinv[qt];
                unsigned int d0 = ((unsigned int)f2bf(O[1] * ri) << 16) | f2bf(O[0] * ri);
                unsigned int d1 = ((unsigned int)f2bf(O[3] * ri) << 16) | f2bf(O[2] * ri);
                *(uint2*)&ao[(size_t)toks4[qt] * 96 + head * 16 + quad * 4] = make_uint2(d0, d1);
            }
        }
    }
}

// ---------------------------------------------------------------------------
// Final 1x1 conv (96->48) + ReLU via MFMA, pixel-in-reg layout -> dwordx4
// channel-major stores. A = T pixel rows (cast bf16), B = out_w rows.
// ---------------------------------------------------------------------------
__global__ __launch_bounds__(256) void outconv_mfma(const float* __restrict__ T,
        const u16* __restrict__ Woc, const float* __restrict__ ob,
        float* __restrict__ out) {
    __shared__ u16 Xs[128 * 104];
    __shared__ u16 Ws[48 * 104];
    int tid = threadIdx.x;
    int w = tid >> 6, lane = tid & 63, quad = lane >> 4, l16 = lane & 15;
    int t0 = blockIdx.x * 128, b = blockIdx.y;
    size_t m0 = (size_t)b * 12544 + t0;

    for (int i = tid; i < 576; i += 256) {
        int r = i / 12, c = i - r * 12;
        *(u32x4*)&Ws[r * 104 + c * 8] = *(const u32x4*)&Woc[(size_t)r * 96 + c * 8];
    }
    {
        int r = tid >> 1, h = tid & 1;
        const float* rowp = T + (m0 + r) * 96 + h * 48;
#pragma unroll
        for (int j = 0; j < 12; j += 2) {
            float4 a = *(const float4*)&rowp[j * 4];
            float4 c2 = *(const float4*)&rowp[j * 4 + 4];
            u32x4 pk = {((unsigned int)f2bf(a.y) << 16) | f2bf(a.x),
                        ((unsigned int)f2bf(a.w) << 16) | f2bf(a.z),
                        ((unsigned int)f2bf(c2.y) << 16) | f2bf(c2.x),
                        ((unsigned int)f2bf(c2.w) << 16) | f2bf(c2.z)};
            *(u32x4*)&Xs[r * 104 + h * 48 + j * 4] = pk;
        }
    }
    __syncthreads();

    f32x4 acc[2][3];
#pragma unroll
    for (int mi = 0; mi < 2; mi++)
#pragma unroll
        for (int ni = 0; ni < 3; ni++) acc[mi][ni] = f32x4{0.f, 0.f, 0.f, 0.f};
#pragma unroll
    for (int kk = 0; kk < 3; kk++) {
        bf16x8 af[2], bfr[3];
#pragma unroll
        for (int mi = 0; mi < 2; mi++)
            af[mi] = *(const bf16x8*)&Xs[(w * 32 + mi * 16 + l16) * 104 + kk * 32 + quad * 8];
#pragma unroll
        for (int ni = 0; ni < 3; ni++)
            bfr[ni] = *(const bf16x8*)&Ws[(ni * 16 + l16) * 104 + kk * 32 + quad * 8];
#pragma unroll
        for (int mi = 0; mi < 2; mi++)
#pragma unroll
            for (int ni = 0; ni < 3; ni++)
                acc[mi][ni] = __builtin_amdgcn_mfma_f32_16x16x32_bf16(
                    af[mi], bfr[ni], acc[mi][ni], 0, 0, 0);
    }

#pragma unroll
    for (int mi = 0; mi < 2; mi++)
#pragma unroll
        for (int ni = 0; ni < 3; ni++) {
            int co = ni * 16 + l16;
            float bb = ob[co];
            f32x4 o = {fmaxf(acc[mi][ni][0] + bb, 0.f), fmaxf(acc[mi][ni][1] + bb, 0.f),
                       fmaxf(acc[mi][ni][2] + bb, 0.f), fmaxf(acc[mi][ni][3] + bb, 0.f)};
            *(f32x4*)&out[((size_t)b * 48 + co) * 12544 + t0 + w * 32 + mi * 16 + quad * 4] = o;
        }
}

// ---------------------------------------------------------------------------
extern "C" void kernel_launch(void* const* d_in, const int* in_sizes, int n_in,
                              void* d_out, int out_size, void* d_ws, size_t ws_size,
                              hipStream_t stream) {
    const float* x     = (const float*)d_in[0];
    const float* up_w  = (const float*)d_in[1];
    const float* up_b  = (const float*)d_in[2];
    const float* bn_g  = (const float*)d_in[3];
    const float* bn_b  = (const float*)d_in[4];
    const float* bn_m  = (const float*)d_in[5];
    const float* bn_v  = (const float*)d_in[6];
    const float* n1g   = (const float*)d_in[7];
    const float* n1b   = (const float*)d_in[8];
    const float* qkvw  = (const float*)d_in[9];
    const float* qkvb  = (const float*)d_in[10];
    const float* projw = (const float*)d_in[11];
    const float* projb = (const float*)d_in[12];
    const float* rel   = (const float*)d_in[13];
    const float* n2g   = (const float*)d_in[14];
    const float* n2b   = (const float*)d_in[15];
    const float* f1w   = (const float*)d_in[16];
    const float* f1b   = (const float*)d_in[17];
    const float* f2w   = (const float*)d_in[18];
    const float* f2b   = (const float*)d_in[19];
    const float* outw  = (const float*)d_in[20];
    const float* outb  = (const float*)d_in[21];
    float* out = (float*)d_out;

    char* base = (char*)d_ws;
    float* T  = (float*)base;                       base += (size_t)M_TOK * 96 * 4;
    u16* XBh  = (u16*)base;                         base += (size_t)M_TOK * 96 * 2;
    u16* BIGh = (u16*)base;                         base += (size_t)M_TOK * 384 * 2;
    u16* xT   = (u16*)base;                         base += (size_t)8 * 3136 * 192 * 2;
    u16* Wc   = (u16*)base;                         base += (size_t)16 * 96 * 192 * 2;
    u16* Wh   = (u16*)base;                         base += (size_t)225792 * 2;
    float* BT = (float*)base;                       // 2*4*6*4096 f32 = 786 KB
    u16* qkvwh = Wh;
    u16* projwh = Wh + 55296;
    u16* f1wh = Wh + 73728;
    u16* f2wh = Wh + 147456;
    u16* outwh = Wh + 221184;

    cast_w_kernel<<<882, 256, 0, stream>>>(qkvw, projw, f1w, f2w, outw, Wh);
    fold_kernel<<<288, 256, 0, stream>>>(up_w, Wc);
    bias_gen<<<48, 256, 0, stream>>>(rel, BT);
    transpose_kernel<<<dim3(49, 8), 256, 0, stream>>>(x, xT);
    conv_mfma<<<dim3(49, 4, 8), 256, 0, stream>>>(xT, Wc, up_b, bn_g, bn_b, bn_m, bn_v, T);

    for (int blk = 0; blk < 2; blk++) {
        int shift = (blk == 0) ? 0 : 3;
        gemm_ln<0><<<dim3(3, M_TOK / 128), 256, 0, stream>>>(
            T, qkvwh + blk * 27648, n1g + blk * 96, n1b + blk * 96, qkvb + blk * 288, BIGh, 288);
        attn_mfma<<<2048, 192, 0, stream>>>(BIGh, BT + (size_t)blk * 98304, XBh, shift);
        gemm_res<<<M_TOK / 128, 256, 0, stream>>>(
            XBh, projwh + blk * 9216, projb + blk * 96, T, T, 96);
        gemm_ln<1><<<dim3(4, M_TOK / 128), 256, 0, stream>>>(
            T, f1wh + blk * 36864, n2g + blk * 96, n2b + blk * 96, f1b + blk * 384, BIGh, 384);
        gemm_res<<<M_TOK / 128, 256, 0, stream>>>(
            BIGh, f2wh + blk * 36864, f2b + blk * 96, T, T, 384);
    }

    outconv_mfma<<<dim3(98, 8), 256, 0, stream>>>(T, outwh, outb, out);
}

// Round 6
// 611.502 us; speedup vs baseline: 2.6439x; 1.0403x over previous
//
#include <hip/hip_runtime.h>
#include <math.h>

#define M_TOK 100352   // 8*112*112 tokens
#define NHEAD 6

typedef unsigned short u16;
typedef __attribute__((ext_vector_type(8))) short bf16x8;
typedef __attribute__((ext_vector_type(4))) float f32x4;
typedef __attribute__((ext_vector_type(4))) unsigned int u32x4;

__device__ inline u16 f2bf(float f) {
    union { float f; unsigned int i; } v; v.f = f;
    unsigned int r = v.i + 0x7fffu + ((v.i >> 16) & 1u);
    return (u16)(r >> 16);
}

// ---------------------------------------------------------------------------
// Cast all GEMM weights f32 -> bf16 into Wh (incl. out_w 48x96).
// ---------------------------------------------------------------------------
__global__ __launch_bounds__(256) void cast_w_kernel(const float* __restrict__ qkvw,
        const float* __restrict__ projw, const float* __restrict__ f1w,
        const float* __restrict__ f2w, const float* __restrict__ outw,
        u16* __restrict__ Wh) {
    int i = blockIdx.x * 256 + threadIdx.x;
    if (i < 55296) Wh[i] = f2bf(qkvw[i]);
    else if (i < 73728) Wh[i] = f2bf(projw[i - 55296]);
    else if (i < 147456) Wh[i] = f2bf(f1w[i - 73728]);
    else if (i < 221184) Wh[i] = f2bf(f2w[i - 147456]);
    else if (i < 225792) Wh[i] = f2bf(outw[i - 221184]);
}

// ---------------------------------------------------------------------------
// Fold upsample+conv3x3 into 4 parity x 4 tap 2x2 kernels (verified).
// ---------------------------------------------------------------------------
__global__ __launch_bounds__(256) void fold_kernel(const float* __restrict__ up_w,
                                                   u16* __restrict__ Wc) {
    int idx = blockIdx.x * 256 + threadIdx.x;
    if (idx >= 96 * 4 * 192) return;
    int c2 = idx / 768;
    int rem = idx - c2 * 768;
    int p = rem / 192;
    int ci = rem - p * 192;
    int po = p >> 1, pw = p & 1;
    const float* w = up_w + (c2 * 192 + ci) * 9;
    float w9[9];
#pragma unroll
    for (int k = 0; k < 9; k++) w9[k] = w[k];
    float r0[3], r1[3];
#pragma unroll
    for (int kw = 0; kw < 3; kw++) {
        if (po == 0) { r0[kw] = w9[kw];              r1[kw] = w9[3 + kw] + w9[6 + kw]; }
        else         { r0[kw] = w9[kw] + w9[3 + kw]; r1[kw] = w9[6 + kw]; }
    }
    float o00, o01, o10, o11;
    if (pw == 0) { o00 = r0[0];         o01 = r0[1] + r0[2]; o10 = r1[0];         o11 = r1[1] + r1[2]; }
    else         { o00 = r0[0] + r0[1]; o01 = r0[2];         o10 = r1[0] + r1[1]; o11 = r1[2]; }
    size_t base = ((size_t)p * 4 * 96 + c2) * 192 + ci;
    Wc[base + 0 * 96 * 192] = f2bf(o00);
    Wc[base + 1 * 96 * 192] = f2bf(o01);
    Wc[base + 2 * 96 * 192] = f2bf(o10);
    Wc[base + 3 * 96 * 192] = f2bf(o11);
}

// ---------------------------------------------------------------------------
// Precompute attention bias tables: BT[blk][type][head][64][64] f32.
// ---------------------------------------------------------------------------
__global__ __launch_bounds__(256) void bias_gen(const float* __restrict__ rel,
                                                float* __restrict__ BT) {
    int blkid = blockIdx.x;                // blk*24 + type*6 + head
    int blk = blkid / 24;
    int rem = blkid - blk * 24;
    int type = rem / 6, head = rem - (rem / 6) * 6;
    const float* relp = rel + blk * 1014;
    bool shift = (blk == 1);
    for (int i = threadIdx.x; i < 4096; i += 256) {
        int a = i >> 6, k = i & 63;
        float v;
        if (k >= 49) v = -1e30f;
        else if (a >= 49) v = 0.f;
        else {
            int ah = (a * 37) >> 8, aw = a - ah * 7;
            int kh = (k * 37) >> 8, kw = k - kh * 7;
            v = relp[((ah - kh + 6) * 13 + (aw - kw + 6)) * 6 + head];
            if (shift) {
                int lha = (type & 2) ? (ah < 4 ? 1 : 2) : 0;
                int lwa = (type & 1) ? (aw < 4 ? 1 : 2) : 0;
                int lhk = (type & 2) ? (kh < 4 ? 1 : 2) : 0;
                int lwk = (type & 1) ? (kw < 4 ? 1 : 2) : 0;
                if (lha != lhk || lwa != lwk) v -= 100.f;
            }
        }
        BT[(size_t)blkid * 4096 + i] = v;
    }
}

// ---------------------------------------------------------------------------
// x [b][192][56][56] f32 -> xT [b][3136][192] bf16 (XOR-swizzled LDS).
// ---------------------------------------------------------------------------
__global__ __launch_bounds__(256) void transpose_kernel(const float* __restrict__ x,
                                                        u16* __restrict__ xT) {
    __shared__ unsigned int ts[64 * 96];
    int b = blockIdx.y;
    int pix0 = blockIdx.x * 64;
    int tid = threadIdx.x;
    int p = tid & 63, dg = tid >> 6;
    const float* xb = x + (size_t)b * 192 * 3136 + pix0 + p;
    for (int d = dg; d < 96; d += 4) {
        float v0 = xb[(size_t)(2 * d) * 3136];
        float v1 = xb[(size_t)(2 * d + 1) * 3136];
        unsigned int pk = ((unsigned int)f2bf(v1) << 16) | (unsigned int)f2bf(v0);
        ts[p * 96 + ((d & ~31) | ((d & 31) ^ (p & 31)))] = pk;
    }
    __syncthreads();
    for (int i = tid; i < 1536; i += 256) {
        int pp = i / 24, c = i - pp * 24;
        unsigned int r[4];
#pragma unroll
        for (int j = 0; j < 4; j++) {
            int d = c * 4 + j;
            r[j] = ts[pp * 96 + ((d & ~31) | ((d & 31) ^ (pp & 31)))];
        }
        u32x4 v = {r[0], r[1], r[2], r[3]};
        *(u32x4*)&xT[((size_t)b * 3136 + pix0 + pp) * 192 + c * 8] = v;
    }
}

// ---------------------------------------------------------------------------
// Implicit-GEMM conv via MFMA + BN + ReLU -> T f32, AND fused LN1(blk0)
// epilogue -> XBh bf16 (channel-dim LN: shfl over l16 + LDS half-exchange).
// ---------------------------------------------------------------------------
__global__ __launch_bounds__(256) void conv_mfma(const u16* __restrict__ xT,
        const u16* __restrict__ Wc, const float* __restrict__ up_b,
        const float* __restrict__ bn_g, const float* __restrict__ bn_b,
        const float* __restrict__ bn_m, const float* __restrict__ bn_v,
        const float* __restrict__ lg, const float* __restrict__ lb,
        float* __restrict__ T, u16* __restrict__ XBh) {
    __shared__ u16 xs[81 * 200];
    __shared__ __align__(16) u16 ws[96 * 104];
    int tile = blockIdx.x, p = blockIdx.y, b = blockIdx.z;
    int po = p >> 1, pw = p & 1;
    int a0 = (tile / 7) * 8, b0 = (tile % 7) * 8;
    int rro = a0 - 1 + po, cco = b0 - 1 + pw;
    int tid = threadIdx.x;
    int w = tid >> 6, lane = tid & 63, quad = lane >> 4, l16 = lane & 15;
    int mbase = (w & 1) * 32;
    int nt0 = (w >> 1) * 3;
    int half = w >> 1;

    for (int i = tid; i < 1944; i += 256) {
        int pix = i / 24, c = i - pix * 24;
        int rr = pix / 9, cc = pix - rr * 9;
        int gr = rro + rr, gc = cco + cc;
        u32x4 v = {0u, 0u, 0u, 0u};
        if ((unsigned)gr < 56u && (unsigned)gc < 56u)
            v = *(const u32x4*)&xT[((size_t)b * 3136 + gr * 56 + gc) * 192 + c * 8];
        *(u32x4*)&xs[pix * 200 + c * 8] = v;
    }

    f32x4 acc[2][3];
#pragma unroll
    for (int mi = 0; mi < 2; mi++)
#pragma unroll
        for (int ni = 0; ni < 3; ni++) acc[mi][ni] = f32x4{0.f, 0.f, 0.f, 0.f};

    int aoffp[2];
#pragma unroll
    for (int mi = 0; mi < 2; mi++) {
        int pixel = mbase + mi * 16 + l16;
        aoffp[mi] = ((pixel >> 3) * 9 + (pixel & 7)) * 200;
    }

    for (int tap = 0; tap < 4; tap++) {
        int di = tap >> 1, dj = tap & 1;
        int tsh = (di * 9 + dj) * 200;
        for (int kc = 0; kc < 2; kc++) {
            __syncthreads();
            for (int i = tid; i < 1152; i += 256) {
                int r = i / 12, c = i - r * 12;
                *(u32x4*)&ws[r * 104 + c * 8] =
                    *(const u32x4*)&Wc[(((size_t)p * 4 + tap) * 96 + r) * 192 + kc * 96 + c * 8];
            }
            __syncthreads();
#pragma unroll
            for (int kk = 0; kk < 3; kk++) {
                bf16x8 af[2], bfr[3];
#pragma unroll
                for (int mi = 0; mi < 2; mi++)
                    af[mi] = *(const bf16x8*)&xs[aoffp[mi] + tsh + kc * 96 + kk * 32 + quad * 8];
#pragma unroll
                for (int ni = 0; ni < 3; ni++)
                    bfr[ni] = *(const bf16x8*)&ws[((nt0 + ni) * 16 + l16) * 104 + kk * 32 + quad * 8];
#pragma unroll
                for (int mi = 0; mi < 2; mi++)
#pragma unroll
                    for (int ni = 0; ni < 3; ni++)
                        acc[mi][ni] = __builtin_amdgcn_mfma_f32_16x16x32_bf16(
                            af[mi], bfr[ni], acc[mi][ni], 0, 0, 0);
            }
        }
    }

    // BN + ReLU -> T (keep values in acc for LN)
#pragma unroll
    for (int ni = 0; ni < 3; ni++) {
        int c2 = (nt0 + ni) * 16 + l16;
        float sc = bn_g[c2] * rsqrtf(bn_v[c2] + 1e-5f);
        float sh = (up_b[c2] - bn_m[c2]) * sc + bn_b[c2];
#pragma unroll
        for (int mi = 0; mi < 2; mi++) {
#pragma unroll
            for (int reg = 0; reg < 4; reg++) {
                int pixel = mbase + mi * 16 + quad * 4 + reg;
                int pr = pixel >> 3, pc = pixel & 7;
                int oh = 2 * (a0 + pr) + po, ow = 2 * (b0 + pc) + pw;
                size_t tok = (size_t)b * 12544 + oh * 112 + ow;
                float v = fmaxf(acc[mi][ni][reg] * sc + sh, 0.f);
                acc[mi][ni][reg] = v;
                T[tok * 96 + c2] = v;
            }
        }
    }

    // fused LN over channels
    float sA[2][4], qA[2][4];
#pragma unroll
    for (int mi = 0; mi < 2; mi++)
#pragma unroll
        for (int reg = 0; reg < 4; reg++) {
            float s = acc[mi][0][reg] + acc[mi][1][reg] + acc[mi][2][reg];
            float q = acc[mi][0][reg] * acc[mi][0][reg] + acc[mi][1][reg] * acc[mi][1][reg]
                    + acc[mi][2][reg] * acc[mi][2][reg];
#pragma unroll
            for (int d = 1; d < 16; d <<= 1) {
                s += __shfl_xor(s, d, 64);
                q += __shfl_xor(q, d, 64);
            }
            sA[mi][reg] = s; qA[mi][reg] = q;
        }
    __syncthreads();
    float2* parts = (float2*)ws;
    if (l16 == 0) {
#pragma unroll
        for (int mi = 0; mi < 2; mi++)
#pragma unroll
            for (int reg = 0; reg < 4; reg++) {
                int pixel = mbase + mi * 16 + quad * 4 + reg;
                parts[pixel * 2 + half] = make_float2(sA[mi][reg], qA[mi][reg]);
            }
    }
    __syncthreads();
    float gcl[3], bcl[3];
#pragma unroll
    for (int ni = 0; ni < 3; ni++) {
        int c2 = (nt0 + ni) * 16 + l16;
        gcl[ni] = lg[c2]; bcl[ni] = lb[c2];
    }
#pragma unroll
    for (int mi = 0; mi < 2; mi++)
#pragma unroll
        for (int reg = 0; reg < 4; reg++) {
            int pixel = mbase + mi * 16 + quad * 4 + reg;
            float2 oth = parts[pixel * 2 + (half ^ 1)];
            float ts_ = sA[mi][reg] + oth.x, tq = qA[mi][reg] + oth.y;
            float mean = ts_ * (1.f / 96.f);
            float var = tq * (1.f / 96.f) - mean * mean;
            float rstd = rsqrtf(var + 1e-5f);
            int pr = pixel >> 3, pc = pixel & 7;
            int oh = 2 * (a0 + pr) + po, ow = 2 * (b0 + pc) + pw;
            size_t tok = (size_t)b * 12544 + oh * 112 + ow;
#pragma unroll
            for (int ni = 0; ni < 3; ni++) {
                int c2 = (nt0 + ni) * 16 + l16;
                XBh[tok * 96 + c2] = f2bf((acc[mi][ni][reg] - mean) * rstd * gcl[ni] + bcl[ni]);
            }
        }
}

// ---------------------------------------------------------------------------
// Plain bf16 GEMM (K=96, single tile): C = Xh @ W^T + bias [,GELU] -> bf16.
// Transposed-C: A = W rows, B = X rows. BM=128, BN=96.
// ---------------------------------------------------------------------------
template <int EPI>
__global__ __launch_bounds__(256) void gemm_act(const u16* __restrict__ Xh,
        const u16* __restrict__ W, const float* __restrict__ bias,
        u16* __restrict__ Cout, int N) {
    __shared__ u16 Xs[128 * 104];
    __shared__ u16 Ws[96 * 104];
    int tid = threadIdx.x;
    int w = tid >> 6, lane = tid & 63, quad = lane >> 4, l16 = lane & 15;
    int mh = w & 1, nh = w >> 1;
    int n0 = blockIdx.x * 96;
    size_t m0 = (size_t)blockIdx.y * 128;

    for (int i = tid; i < 1536; i += 256) {
        int r = i / 12, c = i - r * 12;
        *(u32x4*)&Xs[r * 104 + c * 8] = *(const u32x4*)&Xh[(m0 + r) * 96 + c * 8];
    }
    for (int i = tid; i < 1152; i += 256) {
        int r = i / 12, c = i - r * 12;
        *(u32x4*)&Ws[r * 104 + c * 8] = *(const u32x4*)&W[(size_t)(n0 + r) * 96 + c * 8];
    }
    __syncthreads();

    f32x4 acc[3][4];
#pragma unroll
    for (int ni = 0; ni < 3; ni++)
#pragma unroll
        for (int mi = 0; mi < 4; mi++) acc[ni][mi] = f32x4{0.f, 0.f, 0.f, 0.f};
#pragma unroll
    for (int kk = 0; kk < 3; kk++) {
        bf16x8 af[3], bf[4];
#pragma unroll
        for (int ni = 0; ni < 3; ni++)
            af[ni] = *(const bf16x8*)&Ws[(nh * 48 + ni * 16 + l16) * 104 + kk * 32 + quad * 8];
#pragma unroll
        for (int mi = 0; mi < 4; mi++)
            bf[mi] = *(const bf16x8*)&Xs[(mh * 64 + mi * 16 + l16) * 104 + kk * 32 + quad * 8];
#pragma unroll
        for (int ni = 0; ni < 3; ni++)
#pragma unroll
            for (int mi = 0; mi < 4; mi++)
                acc[ni][mi] = __builtin_amdgcn_mfma_f32_16x16x32_bf16(
                    af[ni], bf[mi], acc[ni][mi], 0, 0, 0);
    }

#pragma unroll
    for (int ni = 0; ni < 3; ni++) {
        int colb = n0 + nh * 48 + ni * 16 + quad * 4;
        float4 bv = *(const float4*)&bias[colb];
#pragma unroll
        for (int mi = 0; mi < 4; mi++) {
            size_t row = m0 + mh * 64 + mi * 16 + l16;
            float v0 = acc[ni][mi][0] + bv.x, v1 = acc[ni][mi][1] + bv.y;
            float v2 = acc[ni][mi][2] + bv.z, v3 = acc[ni][mi][3] + bv.w;
            if (EPI == 1) {
                v0 = 0.5f * v0 * (1.f + erff(v0 * 0.70710678118654752f));
                v1 = 0.5f * v1 * (1.f + erff(v1 * 0.70710678118654752f));
                v2 = 0.5f * v2 * (1.f + erff(v2 * 0.70710678118654752f));
                v3 = 0.5f * v3 * (1.f + erff(v3 * 0.70710678118654752f));
            }
            unsigned int d0 = ((unsigned int)f2bf(v1) << 16) | f2bf(v0);
            unsigned int d1 = ((unsigned int)f2bf(v3) << 16) | f2bf(v2);
            *(uint2*)&Cout[row * N + colb] = make_uint2(d0, d1);
        }
    }
}

// ---------------------------------------------------------------------------
// GEMM + bias + residual -> T f32, AND fused next-op epilogue -> XBh bf16:
// LNM=1: LayerNorm(g,bt); LNM=0: plain bf16 cast. Transposed-C layout.
// ---------------------------------------------------------------------------
template <int LNM>
__global__ __launch_bounds__(256) void gemm_res(const u16* __restrict__ Xh,
        const u16* __restrict__ W, const float* __restrict__ bias,
        const float* __restrict__ res, float* __restrict__ Tout,
        const float* __restrict__ g, const float* __restrict__ bt,
        u16* __restrict__ Yh, int K) {
    __shared__ __align__(16) u16 Xs[128 * 104];
    __shared__ u16 Ws[96 * 104];
    int tid = threadIdx.x;
    int w = tid >> 6, lane = tid & 63, quad = lane >> 4, l16 = lane & 15;
    int mh = w & 1, nh = w >> 1;
    size_t m0 = (size_t)blockIdx.x * 128;

    f32x4 acc[3][4];
#pragma unroll
    for (int ni = 0; ni < 3; ni++)
#pragma unroll
        for (int mi = 0; mi < 4; mi++) acc[ni][mi] = f32x4{0.f, 0.f, 0.f, 0.f};

    for (int k0 = 0; k0 < K; k0 += 96) {
        __syncthreads();
        for (int i = tid; i < 1536; i += 256) {
            int r = i / 12, c = i - r * 12;
            *(u32x4*)&Xs[r * 104 + c * 8] = *(const u32x4*)&Xh[(m0 + r) * K + k0 + c * 8];
        }
        for (int i = tid; i < 1152; i += 256) {
            int r = i / 12, c = i - r * 12;
            *(u32x4*)&Ws[r * 104 + c * 8] = *(const u32x4*)&W[(size_t)r * K + k0 + c * 8];
        }
        __syncthreads();
#pragma unroll
        for (int kk = 0; kk < 3; kk++) {
            bf16x8 af[3], bf[4];
#pragma unroll
            for (int ni = 0; ni < 3; ni++)
                af[ni] = *(const bf16x8*)&Ws[(nh * 48 + ni * 16 + l16) * 104 + kk * 32 + quad * 8];
#pragma unroll
            for (int mi = 0; mi < 4; mi++)
                bf[mi] = *(const bf16x8*)&Xs[(mh * 64 + mi * 16 + l16) * 104 + kk * 32 + quad * 8];
#pragma unroll
            for (int ni = 0; ni < 3; ni++)
#pragma unroll
                for (int mi = 0; mi < 4; mi++)
                    acc[ni][mi] = __builtin_amdgcn_mfma_f32_16x16x32_bf16(
                        af[ni], bf[mi], acc[ni][mi], 0, 0, 0);
        }
    }

    // bias + residual -> T (keep in acc)
#pragma unroll
    for (int ni = 0; ni < 3; ni++) {
        int colb = nh * 48 + ni * 16 + quad * 4;
        float4 bv = *(const float4*)&bias[colb];
#pragma unroll
        for (int mi = 0; mi < 4; mi++) {
            size_t row = m0 + mh * 64 + mi * 16 + l16;
            float4 rv = *(const float4*)&res[row * 96 + colb];
            acc[ni][mi][0] += bv.x + rv.x;
            acc[ni][mi][1] += bv.y + rv.y;
            acc[ni][mi][2] += bv.z + rv.z;
            acc[ni][mi][3] += bv.w + rv.w;
            *(f32x4*)&Tout[row * 96 + colb] = acc[ni][mi];
        }
    }

    if (LNM == 1) {
        // per-row partials: sum over own 12 cols, reduce over quad
        float sm4[4], qm4[4];
#pragma unroll
        for (int mi = 0; mi < 4; mi++) {
            float s = 0.f, q = 0.f;
#pragma unroll
            for (int ni = 0; ni < 3; ni++)
#pragma unroll
                for (int r = 0; r < 4; r++) {
                    float v = acc[ni][mi][r];
                    s += v; q += v * v;
                }
            s += __shfl_xor(s, 16, 64); s += __shfl_xor(s, 32, 64);
            q += __shfl_xor(q, 16, 64); q += __shfl_xor(q, 32, 64);
            sm4[mi] = s; qm4[mi] = q;
        }
        __syncthreads();
        float2* parts = (float2*)Xs;
        if (quad == 0) {
#pragma unroll
            for (int mi = 0; mi < 4; mi++)
                parts[(mh * 64 + mi * 16 + l16) * 2 + nh] = make_float2(sm4[mi], qm4[mi]);
        }
        __syncthreads();
        float mean4[4], rstd4[4];
#pragma unroll
        for (int mi = 0; mi < 4; mi++) {
            float2 oth = parts[(mh * 64 + mi * 16 + l16) * 2 + (nh ^ 1)];
            float ts_ = sm4[mi] + oth.x, tq = qm4[mi] + oth.y;
            float mean = ts_ * (1.f / 96.f);
            float var = tq * (1.f / 96.f) - mean * mean;
            mean4[mi] = mean;
            rstd4[mi] = rsqrtf(var + 1e-5f);
        }
#pragma unroll
        for (int ni = 0; ni < 3; ni++) {
            int colb = nh * 48 + ni * 16 + quad * 4;
            float4 g4 = *(const float4*)&g[colb];
            float4 b4 = *(const float4*)&bt[colb];
#pragma unroll
            for (int mi = 0; mi < 4; mi++) {
                size_t row = m0 + mh * 64 + mi * 16 + l16;
                float y0 = (acc[ni][mi][0] - mean4[mi]) * rstd4[mi] * g4.x + b4.x;
                float y1 = (acc[ni][mi][1] - mean4[mi]) * rstd4[mi] * g4.y + b4.y;
                float y2 = (acc[ni][mi][2] - mean4[mi]) * rstd4[mi] * g4.z + b4.z;
                float y3 = (acc[ni][mi][3] - mean4[mi]) * rstd4[mi] * g4.w + b4.w;
                unsigned int d0 = ((unsigned int)f2bf(y1) << 16) | f2bf(y0);
                unsigned int d1 = ((unsigned int)f2bf(y3) << 16) | f2bf(y2);
                *(uint2*)&Yh[row * 96 + colb] = make_uint2(d0, d1);
            }
        }
    } else {
        // plain bf16 cast
#pragma unroll
        for (int ni = 0; ni < 3; ni++) {
            int colb = nh * 48 + ni * 16 + quad * 4;
#pragma unroll
            for (int mi = 0; mi < 4; mi++) {
                size_t row = m0 + mh * 64 + mi * 16 + l16;
                unsigned int d0 = ((unsigned int)f2bf(acc[ni][mi][1]) << 16) | f2bf(acc[ni][mi][0]);
                unsigned int d1 = ((unsigned int)f2bf(acc[ni][mi][3]) << 16) | f2bf(acc[ni][mi][2]);
                *(uint2*)&Yh[row * 96 + colb] = make_uint2(d0, d1);
            }
        }
    }
}

// ---------------------------------------------------------------------------
// MFMA window attention v2 (unchanged from passing R4/R5).
// ---------------------------------------------------------------------------
__global__ __launch_bounds__(192, 3) void attn_mfma(const u16* __restrict__ qkv,
        const float* __restrict__ BT, u16* __restrict__ ao, int shift) {
    __shared__ u16 Pl[3][64 * 72];
    __shared__ u16 vts[3][16 * 72];

    int tid = threadIdx.x;
    int w = tid >> 6, lane = tid & 63, quad = lane >> 4, l16 = lane & 15;
    int Wd = blockIdx.x;
    int bb = Wd >> 8, wl = Wd & 255, wh = wl >> 4, ww = wl & 15;
    int type = ((wh == 15) ? 2 : 0) + ((ww == 15) ? 1 : 0);

    int toks4[4], tokV;
#pragma unroll
    for (int t = 0; t < 4; t++) {
        int a = t * 16 + l16; if (a > 48) a = 48;
        int r = (a * 37) >> 8, c = a - r * 7;
        int h = wh * 7 + r, wq = ww * 7 + c;
        if (shift) { h += 3; if (h >= 112) h -= 112; wq += 3; if (wq >= 112) wq -= 112; }
        toks4[t] = bb * 12544 + h * 112 + wq;
    }
    {
        int a = lane > 48 ? 48 : lane;
        int r = (a * 37) >> 8, c = a - r * 7;
        int h = wh * 7 + r, wq = ww * 7 + c;
        if (shift) { h += 3; if (h >= 112) h -= 112; wq += 3; if (wq >= 112) wq -= 112; }
        tokV = bb * 12544 + h * 112 + wq;
    }

    u16* Pw = Pl[w];
    u16* vw = vts[w];

    for (int i = lane; i < 240; i += 64) {
        int rrow = i / 15, key = 49 + (i - rrow * 15);
        vw[rrow * 72 + key] = 0;
    }

    for (int hh = 0; hh < 2; hh++) {
        int head = w * 2 + hh;

        union { u32x4 u; bf16x8 h; } qf[4], kf[4];
#pragma unroll
        for (int t = 0; t < 4; t++) {
            u32x4 zq = {0u, 0u, 0u, 0u}, zk = {0u, 0u, 0u, 0u};
            if (quad < 2) {
                const u16* rb = qkv + (size_t)toks4[t] * 288 + head * 16 + quad * 8;
                zq = *(const u32x4*)(rb);
                zk = *(const u32x4*)(rb + 96);
            }
            qf[t].u = zq; kf[t].u = zk;
        }

        if (lane < 49) {
            const u16* vb = qkv + (size_t)tokV * 288 + head * 16 + 192;
            union { u32x4 v; unsigned int u[4]; } v0, v1;
            v0.v = *(const u32x4*)(vb);
            v1.v = *(const u32x4*)(vb + 8);
#pragma unroll
            for (int j = 0; j < 4; j++) {
                vw[(2 * j) * 72 + lane]         = (u16)(v0.u[j] & 0xffffu);
                vw[(2 * j + 1) * 72 + lane]     = (u16)(v0.u[j] >> 16);
                vw[(8 + 2 * j) * 72 + lane]     = (u16)(v1.u[j] & 0xffffu);
                vw[(8 + 2 * j + 1) * 72 + lane] = (u16)(v1.u[j] >> 16);
            }
        }

        f32x4 S[4][4];
#pragma unroll
        for (int kt = 0; kt < 4; kt++)
#pragma unroll
            for (int qt = 0; qt < 4; qt++)
                S[kt][qt] = __builtin_amdgcn_mfma_f32_16x16x32_bf16(
                    kf[kt].h, qf[qt].h, f32x4{0.f, 0.f, 0.f, 0.f}, 0, 0, 0);

        const float* bbase = BT + (size_t)(type * 6 + head) * 4096;
        float rinv[4];
#pragma unroll
        for (int qt = 0; qt < 4; qt++) {
            f32x4 bv[4];
#pragma unroll
            for (int kt = 0; kt < 4; kt++)
                bv[kt] = *(const f32x4*)&bbase[(size_t)(qt * 16 + l16) * 64 + kt * 16 + quad * 4];
            float mx = -3e38f;
#pragma unroll
            for (int kt = 0; kt < 4; kt++)
#pragma unroll
                for (int r = 0; r < 4; r++) {
                    float v = fmaf(S[kt][qt][r], 0.25f, bv[kt][r]);
                    S[kt][qt][r] = v;
                    mx = fmaxf(mx, v);
                }
            mx = fmaxf(mx, __shfl_xor(mx, 16, 64));
            mx = fmaxf(mx, __shfl_xor(mx, 32, 64));
            float sm = 0.f;
#pragma unroll
            for (int kt = 0; kt < 4; kt++)
#pragma unroll
                for (int r = 0; r < 4; r++) {
                    float e = __expf(S[kt][qt][r] - mx);
                    S[kt][qt][r] = e;
                    sm += e;
                }
            sm += __shfl_xor(sm, 16, 64);
            sm += __shfl_xor(sm, 32, 64);
            rinv[qt] = 1.0f / sm;
        }

#pragma unroll
        for (int qt = 0; qt < 4; qt++)
#pragma unroll
            for (int kt = 0; kt < 4; kt++) {
                unsigned int d0 = ((unsigned int)f2bf(S[kt][qt][1]) << 16) | f2bf(S[kt][qt][0]);
                unsigned int d1 = ((unsigned int)f2bf(S[kt][qt][3]) << 16) | f2bf(S[kt][qt][2]);
                *(uint2*)&Pw[(qt * 16 + l16) * 72 + kt * 16 + quad * 4] = make_uint2(d0, d1);
            }

        bf16x8 vf[2];
#pragma unroll
        for (int ksp = 0; ksp < 2; ksp++)
            vf[ksp] = *(const bf16x8*)&vw[l16 * 72 + ksp * 32 + quad * 8];
#pragma unroll
        for (int qt = 0; qt < 4; qt++) {
            f32x4 O = {0.f, 0.f, 0.f, 0.f};
#pragma unroll
            for (int ksp = 0; ksp < 2; ksp++) {
                bf16x8 pf = *(const bf16x8*)&Pw[(qt * 16 + l16) * 72 + ksp * 32 + quad * 8];
                O = __builtin_amdgcn_mfma_f32_16x16x32_bf16(vf[ksp], pf, O, 0, 0, 0);
            }
            int a = qt * 16 + l16;
            if (a < 49) {
                float ri = rinv[qt];
                unsigned int d0 = ((unsigned int)f2bf(O[1] * ri) << 16) | f2bf(O[0] * ri);
                unsigned int d1 = ((unsigned int)f2bf(O[3] * ri) << 16) | f2bf(O[2] * ri);
                *(uint2*)&ao[(size_t)toks4[qt] * 96 + head * 16 + quad * 4] = make_uint2(d0, d1);
            }
        }
    }
}

// ---------------------------------------------------------------------------
// Final 1x1 conv (96->48) + ReLU via MFMA, reads bf16 tokens (XBh).
// ---------------------------------------------------------------------------
__global__ __launch_bounds__(256) void outconv_mfma(const u16* __restrict__ Th,
        const u16* __restrict__ Woc, const float* __restrict__ ob,
        float* __restrict__ out) {
    __shared__ u16 Xs[128 * 104];
    __shared__ u16 Ws[48 * 104];
    int tid = threadIdx.x;
    int w = tid >> 6, lane = tid & 63, quad = lane >> 4, l16 = lane & 15;
    int t0 = blockIdx.x * 128, b = blockIdx.y;
    size_t m0 = (size_t)b * 12544 + t0;

    for (int i = tid; i < 576; i += 256) {
        int r = i / 12, c = i - r * 12;
        *(u32x4*)&Ws[r * 104 + c * 8] = *(const u32x4*)&Woc[(size_t)r * 96 + c * 8];
    }
    for (int i = tid; i < 1536; i += 256) {
        int r = i / 12, c = i - r * 12;
        *(u32x4*)&Xs[r * 104 + c * 8] = *(const u32x4*)&Th[(m0 + r) * 96 + c * 8];
    }
    __syncthreads();

    f32x4 acc[2][3];
#pragma unroll
    for (int mi = 0; mi < 2; mi++)
#pragma unroll
        for (int ni = 0; ni < 3; ni++) acc[mi][ni] = f32x4{0.f, 0.f, 0.f, 0.f};
#pragma unroll
    for (int kk = 0; kk < 3; kk++) {
        bf16x8 af[2], bfr[3];
#pragma unroll
        for (int mi = 0; mi < 2; mi++)
            af[mi] = *(const bf16x8*)&Xs[(w * 32 + mi * 16 + l16) * 104 + kk * 32 + quad * 8];
#pragma unroll
        for (int ni = 0; ni < 3; ni++)
            bfr[ni] = *(const bf16x8*)&Ws[(ni * 16 + l16) * 104 + kk * 32 + quad * 8];
#pragma unroll
        for (int mi = 0; mi < 2; mi++)
#pragma unroll
            for (int ni = 0; ni < 3; ni++)
                acc[mi][ni] = __builtin_amdgcn_mfma_f32_16x16x32_bf16(
                    af[mi], bfr[ni], acc[mi][ni], 0, 0, 0);
    }

#pragma unroll
    for (int mi = 0; mi < 2; mi++)
#pragma unroll
        for (int ni = 0; ni < 3; ni++) {
            int co = ni * 16 + l16;
            float bb = ob[co];
            f32x4 o = {fmaxf(acc[mi][ni][0] + bb, 0.f), fmaxf(acc[mi][ni][1] + bb, 0.f),
                       fmaxf(acc[mi][ni][2] + bb, 0.f), fmaxf(acc[mi][ni][3] + bb, 0.f)};
            *(f32x4*)&out[((size_t)b * 48 + co) * 12544 + t0 + w * 32 + mi * 16 + quad * 4] = o;
        }
}

// ---------------------------------------------------------------------------
extern "C" void kernel_launch(void* const* d_in, const int* in_sizes, int n_in,
                              void* d_out, int out_size, void* d_ws, size_t ws_size,
                              hipStream_t stream) {
    const float* x     = (const float*)d_in[0];
    const float* up_w  = (const float*)d_in[1];
    const float* up_b  = (const float*)d_in[2];
    const float* bn_g  = (const float*)d_in[3];
    const float* bn_b  = (const float*)d_in[4];
    const float* bn_m  = (const float*)d_in[5];
    const float* bn_v  = (const float*)d_in[6];
    const float* n1g   = (const float*)d_in[7];
    const float* n1b   = (const float*)d_in[8];
    const float* qkvw  = (const float*)d_in[9];
    const float* qkvb  = (const float*)d_in[10];
    const float* projw = (const float*)d_in[11];
    const float* projb = (const float*)d_in[12];
    const float* rel   = (const float*)d_in[13];
    const float* n2g   = (const float*)d_in[14];
    const float* n2b   = (const float*)d_in[15];
    const float* f1w   = (const float*)d_in[16];
    const float* f1b   = (const float*)d_in[17];
    const float* f2w   = (const float*)d_in[18];
    const float* f2b   = (const float*)d_in[19];
    const float* outw  = (const float*)d_in[20];
    const float* outb  = (const float*)d_in[21];
    float* out = (float*)d_out;

    char* base = (char*)d_ws;
    float* T  = (float*)base;                       base += (size_t)M_TOK * 96 * 4;
    u16* XBh  = (u16*)base;                         base += (size_t)M_TOK * 96 * 2;
    u16* BIGh = (u16*)base;                         base += (size_t)M_TOK * 384 * 2;
    u16* xT   = (u16*)base;                         base += (size_t)8 * 3136 * 192 * 2;
    u16* Wc   = (u16*)base;                         base += (size_t)16 * 96 * 192 * 2;
    u16* Wh   = (u16*)base;                         base += (size_t)225792 * 2;
    float* BT = (float*)base;
    u16* qkvwh = Wh;
    u16* projwh = Wh + 55296;
    u16* f1wh = Wh + 73728;
    u16* f2wh = Wh + 147456;
    u16* outwh = Wh + 221184;

    cast_w_kernel<<<882, 256, 0, stream>>>(qkvw, projw, f1w, f2w, outw, Wh);
    fold_kernel<<<288, 256, 0, stream>>>(up_w, Wc);
    bias_gen<<<48, 256, 0, stream>>>(rel, BT);
    transpose_kernel<<<dim3(49, 8), 256, 0, stream>>>(x, xT);
    conv_mfma<<<dim3(49, 4, 8), 256, 0, stream>>>(xT, Wc, up_b, bn_g, bn_b, bn_m, bn_v,
                                                  n1g, n1b, T, XBh);

    for (int blk = 0; blk < 2; blk++) {
        int shift = (blk == 0) ? 0 : 3;
        gemm_act<0><<<dim3(3, M_TOK / 128), 256, 0, stream>>>(
            XBh, qkvwh + blk * 27648, qkvb + blk * 288, BIGh, 288);
        attn_mfma<<<2048, 192, 0, stream>>>(BIGh, BT + (size_t)blk * 98304, XBh, shift);
        gemm_res<1><<<M_TOK / 128, 256, 0, stream>>>(
            XBh, projwh + blk * 9216, projb + blk * 96, T, T,
            n2g + blk * 96, n2b + blk * 96, XBh, 96);
        gemm_act<1><<<dim3(4, M_TOK / 128), 256, 0, stream>>>(
            XBh, f1wh + blk * 36864, f1b + blk * 384, BIGh, 384);
        if (blk == 0) {
            gemm_res<1><<<M_TOK / 128, 256, 0, stream>>>(
                BIGh, f2wh + blk * 36864, f2b + blk * 96, T, T,
                n1g + 96, n1b + 96, XBh, 384);
        } else {
            gemm_res<0><<<M_TOK / 128, 256, 0, stream>>>(
                BIGh, f2wh + blk * 36864, f2b + blk * 96, T, T,
                nullptr, nullptr, XBh, 384);
        }
    }

    outconv_mfma<<<dim3(98, 8), 256, 0, stream>>>(XBh, outwh, outb, out);
}

// Round 7
// 597.661 us; speedup vs baseline: 2.7051x; 1.0232x over previous
//
#include <hip/hip_runtime.h>
#include <math.h>

#define M_TOK 100352   // 8*112*112 tokens
#define NHEAD 6

typedef unsigned short u16;
typedef __attribute__((ext_vector_type(8))) short bf16x8;
typedef __attribute__((ext_vector_type(4))) float f32x4;
typedef __attribute__((ext_vector_type(4))) unsigned int u32x4;

__device__ inline u16 f2bf(float f) {
    union { float f; unsigned int i; } v; v.f = f;
    unsigned int r = v.i + 0x7fffu + ((v.i >> 16) & 1u);
    return (u16)(r >> 16);
}

// ---------------------------------------------------------------------------
// Merged prep: [0,882) cast weights; [882,1170) fold conv w; [1170,1218) bias.
// ---------------------------------------------------------------------------
__global__ __launch_bounds__(256) void prep_kernel(const float* __restrict__ qkvw,
        const float* __restrict__ projw, const float* __restrict__ f1w,
        const float* __restrict__ f2w, const float* __restrict__ outw,
        const float* __restrict__ up_w, const float* __restrict__ rel,
        u16* __restrict__ Wh, u16* __restrict__ Wc, float* __restrict__ BT) {
    int bid = blockIdx.x;
    if (bid < 882) {
        int i = bid * 256 + threadIdx.x;
        if (i < 55296) Wh[i] = f2bf(qkvw[i]);
        else if (i < 73728) Wh[i] = f2bf(projw[i - 55296]);
        else if (i < 147456) Wh[i] = f2bf(f1w[i - 73728]);
        else if (i < 221184) Wh[i] = f2bf(f2w[i - 147456]);
        else if (i < 225792) Wh[i] = f2bf(outw[i - 221184]);
        return;
    }
    if (bid < 1170) {
        int idx = (bid - 882) * 256 + threadIdx.x;
        if (idx >= 96 * 4 * 192) return;
        int c2 = idx / 768;
        int rem = idx - c2 * 768;
        int p = rem / 192;
        int ci = rem - p * 192;
        int po = p >> 1, pw = p & 1;
        const float* w = up_w + (c2 * 192 + ci) * 9;
        float w9[9];
#pragma unroll
        for (int k = 0; k < 9; k++) w9[k] = w[k];
        float r0[3], r1[3];
#pragma unroll
        for (int kw = 0; kw < 3; kw++) {
            if (po == 0) { r0[kw] = w9[kw];              r1[kw] = w9[3 + kw] + w9[6 + kw]; }
            else         { r0[kw] = w9[kw] + w9[3 + kw]; r1[kw] = w9[6 + kw]; }
        }
        float o00, o01, o10, o11;
        if (pw == 0) { o00 = r0[0];         o01 = r0[1] + r0[2]; o10 = r1[0];         o11 = r1[1] + r1[2]; }
        else         { o00 = r0[0] + r0[1]; o01 = r0[2];         o10 = r1[0] + r1[1]; o11 = r1[2]; }
        size_t base = ((size_t)p * 4 * 96 + c2) * 192 + ci;
        Wc[base + 0 * 96 * 192] = f2bf(o00);
        Wc[base + 1 * 96 * 192] = f2bf(o01);
        Wc[base + 2 * 96 * 192] = f2bf(o10);
        Wc[base + 3 * 96 * 192] = f2bf(o11);
        return;
    }
    {
        int blkid = bid - 1170;                // blk*24 + type*6 + head
        int blk = blkid / 24;
        int rem = blkid - blk * 24;
        int type = rem / 6, head = rem - (rem / 6) * 6;
        const float* relp = rel + blk * 1014;
        bool shift = (blk == 1);
        for (int i = threadIdx.x; i < 4096; i += 256) {
            int a = i >> 6, k = i & 63;
            float v;
            if (k >= 49) v = -1e30f;
            else if (a >= 49) v = 0.f;
            else {
                int ah = (a * 37) >> 8, aw = a - ah * 7;
                int kh = (k * 37) >> 8, kw = k - kh * 7;
                v = relp[((ah - kh + 6) * 13 + (aw - kw + 6)) * 6 + head];
                if (shift) {
                    int lha = (type & 2) ? (ah < 4 ? 1 : 2) : 0;
                    int lwa = (type & 1) ? (aw < 4 ? 1 : 2) : 0;
                    int lhk = (type & 2) ? (kh < 4 ? 1 : 2) : 0;
                    int lwk = (type & 1) ? (kw < 4 ? 1 : 2) : 0;
                    if (lha != lhk || lwa != lwk) v -= 100.f;
                }
            }
            BT[(size_t)blkid * 4096 + i] = v;
        }
    }
}

// ---------------------------------------------------------------------------
// x [b][192][56][56] f32 -> xT [b][3136][192] bf16 (XOR-swizzled LDS).
// ---------------------------------------------------------------------------
__global__ __launch_bounds__(256) void transpose_kernel(const float* __restrict__ x,
                                                        u16* __restrict__ xT) {
    __shared__ unsigned int ts[64 * 96];
    int b = blockIdx.y;
    int pix0 = blockIdx.x * 64;
    int tid = threadIdx.x;
    int p = tid & 63, dg = tid >> 6;
    const float* xb = x + (size_t)b * 192 * 3136 + pix0 + p;
    for (int d = dg; d < 96; d += 4) {
        float v0 = xb[(size_t)(2 * d) * 3136];
        float v1 = xb[(size_t)(2 * d + 1) * 3136];
        unsigned int pk = ((unsigned int)f2bf(v1) << 16) | (unsigned int)f2bf(v0);
        ts[p * 96 + ((d & ~31) | ((d & 31) ^ (p & 31)))] = pk;
    }
    __syncthreads();
    for (int i = tid; i < 1536; i += 256) {
        int pp = i / 24, c = i - pp * 24;
        unsigned int r[4];
#pragma unroll
        for (int j = 0; j < 4; j++) {
            int d = c * 4 + j;
            r[j] = ts[pp * 96 + ((d & ~31) | ((d & 31) ^ (pp & 31)))];
        }
        u32x4 v = {r[0], r[1], r[2], r[3]};
        *(u32x4*)&xT[((size_t)b * 3136 + pix0 + pp) * 192 + c * 8] = v;
    }
}

// ---------------------------------------------------------------------------
// Implicit-GEMM conv via MFMA + BN + ReLU -> T f32 + fused LN1 -> XBh bf16
// (unchanged from passing R6).
// ---------------------------------------------------------------------------
__global__ __launch_bounds__(256) void conv_mfma(const u16* __restrict__ xT,
        const u16* __restrict__ Wc, const float* __restrict__ up_b,
        const float* __restrict__ bn_g, const float* __restrict__ bn_b,
        const float* __restrict__ bn_m, const float* __restrict__ bn_v,
        const float* __restrict__ lg, const float* __restrict__ lb,
        float* __restrict__ T, u16* __restrict__ XBh) {
    __shared__ u16 xs[81 * 200];
    __shared__ __align__(16) u16 ws[96 * 104];
    int tile = blockIdx.x, p = blockIdx.y, b = blockIdx.z;
    int po = p >> 1, pw = p & 1;
    int a0 = (tile / 7) * 8, b0 = (tile % 7) * 8;
    int rro = a0 - 1 + po, cco = b0 - 1 + pw;
    int tid = threadIdx.x;
    int w = tid >> 6, lane = tid & 63, quad = lane >> 4, l16 = lane & 15;
    int mbase = (w & 1) * 32;
    int nt0 = (w >> 1) * 3;
    int half = w >> 1;

    for (int i = tid; i < 1944; i += 256) {
        int pix = i / 24, c = i - pix * 24;
        int rr = pix / 9, cc = pix - rr * 9;
        int gr = rro + rr, gc = cco + cc;
        u32x4 v = {0u, 0u, 0u, 0u};
        if ((unsigned)gr < 56u && (unsigned)gc < 56u)
            v = *(const u32x4*)&xT[((size_t)b * 3136 + gr * 56 + gc) * 192 + c * 8];
        *(u32x4*)&xs[pix * 200 + c * 8] = v;
    }

    f32x4 acc[2][3];
#pragma unroll
    for (int mi = 0; mi < 2; mi++)
#pragma unroll
        for (int ni = 0; ni < 3; ni++) acc[mi][ni] = f32x4{0.f, 0.f, 0.f, 0.f};

    int aoffp[2];
#pragma unroll
    for (int mi = 0; mi < 2; mi++) {
        int pixel = mbase + mi * 16 + l16;
        aoffp[mi] = ((pixel >> 3) * 9 + (pixel & 7)) * 200;
    }

    for (int tap = 0; tap < 4; tap++) {
        int di = tap >> 1, dj = tap & 1;
        int tsh = (di * 9 + dj) * 200;
        for (int kc = 0; kc < 2; kc++) {
            __syncthreads();
            for (int i = tid; i < 1152; i += 256) {
                int r = i / 12, c = i - r * 12;
                *(u32x4*)&ws[r * 104 + c * 8] =
                    *(const u32x4*)&Wc[(((size_t)p * 4 + tap) * 96 + r) * 192 + kc * 96 + c * 8];
            }
            __syncthreads();
#pragma unroll
            for (int kk = 0; kk < 3; kk++) {
                bf16x8 af[2], bfr[3];
#pragma unroll
                for (int mi = 0; mi < 2; mi++)
                    af[mi] = *(const bf16x8*)&xs[aoffp[mi] + tsh + kc * 96 + kk * 32 + quad * 8];
#pragma unroll
                for (int ni = 0; ni < 3; ni++)
                    bfr[ni] = *(const bf16x8*)&ws[((nt0 + ni) * 16 + l16) * 104 + kk * 32 + quad * 8];
#pragma unroll
                for (int mi = 0; mi < 2; mi++)
#pragma unroll
                    for (int ni = 0; ni < 3; ni++)
                        acc[mi][ni] = __builtin_amdgcn_mfma_f32_16x16x32_bf16(
                            af[mi], bfr[ni], acc[mi][ni], 0, 0, 0);
            }
        }
    }

#pragma unroll
    for (int ni = 0; ni < 3; ni++) {
        int c2 = (nt0 + ni) * 16 + l16;
        float sc = bn_g[c2] * rsqrtf(bn_v[c2] + 1e-5f);
        float sh = (up_b[c2] - bn_m[c2]) * sc + bn_b[c2];
#pragma unroll
        for (int mi = 0; mi < 2; mi++) {
#pragma unroll
            for (int reg = 0; reg < 4; reg++) {
                int pixel = mbase + mi * 16 + quad * 4 + reg;
                int pr = pixel >> 3, pc = pixel & 7;
                int oh = 2 * (a0 + pr) + po, ow = 2 * (b0 + pc) + pw;
                size_t tok = (size_t)b * 12544 + oh * 112 + ow;
                float v = fmaxf(acc[mi][ni][reg] * sc + sh, 0.f);
                acc[mi][ni][reg] = v;
                T[tok * 96 + c2] = v;
            }
        }
    }

    float sA[2][4], qA[2][4];
#pragma unroll
    for (int mi = 0; mi < 2; mi++)
#pragma unroll
        for (int reg = 0; reg < 4; reg++) {
            float s = acc[mi][0][reg] + acc[mi][1][reg] + acc[mi][2][reg];
            float q = acc[mi][0][reg] * acc[mi][0][reg] + acc[mi][1][reg] * acc[mi][1][reg]
                    + acc[mi][2][reg] * acc[mi][2][reg];
#pragma unroll
            for (int d = 1; d < 16; d <<= 1) {
                s += __shfl_xor(s, d, 64);
                q += __shfl_xor(q, d, 64);
            }
            sA[mi][reg] = s; qA[mi][reg] = q;
        }
    __syncthreads();
    float2* parts = (float2*)ws;
    if (l16 == 0) {
#pragma unroll
        for (int mi = 0; mi < 2; mi++)
#pragma unroll
            for (int reg = 0; reg < 4; reg++) {
                int pixel = mbase + mi * 16 + quad * 4 + reg;
                parts[pixel * 2 + half] = make_float2(sA[mi][reg], qA[mi][reg]);
            }
    }
    __syncthreads();
    float gcl[3], bcl[3];
#pragma unroll
    for (int ni = 0; ni < 3; ni++) {
        int c2 = (nt0 + ni) * 16 + l16;
        gcl[ni] = lg[c2]; bcl[ni] = lb[c2];
    }
#pragma unroll
    for (int mi = 0; mi < 2; mi++)
#pragma unroll
        for (int reg = 0; reg < 4; reg++) {
            int pixel = mbase + mi * 16 + quad * 4 + reg;
            float2 oth = parts[pixel * 2 + (half ^ 1)];
            float ts_ = sA[mi][reg] + oth.x, tq = qA[mi][reg] + oth.y;
            float mean = ts_ * (1.f / 96.f);
            float var = tq * (1.f / 96.f) - mean * mean;
            float rstd = rsqrtf(var + 1e-5f);
            int pr = pixel >> 3, pc = pixel & 7;
            int oh = 2 * (a0 + pr) + po, ow = 2 * (b0 + pc) + pw;
            size_t tok = (size_t)b * 12544 + oh * 112 + ow;
#pragma unroll
            for (int ni = 0; ni < 3; ni++) {
                int c2 = (nt0 + ni) * 16 + l16;
                XBh[tok * 96 + c2] = f2bf((acc[mi][ni][reg] - mean) * rstd * gcl[ni] + bcl[ni]);
            }
        }
}

// ---------------------------------------------------------------------------
// LDS-free bf16 GEMM (K=96): C = Xh @ W^T + bias [,GELU] -> bf16.
// All MFMA fragments loaded directly from global (attn-style); no barriers.
// ---------------------------------------------------------------------------
template <int EPI>
__global__ __launch_bounds__(256) void gemm_act(const u16* __restrict__ Xh,
        const u16* __restrict__ W, const float* __restrict__ bias,
        u16* __restrict__ Cout, int N) {
    int tid = threadIdx.x;
    int w = tid >> 6, lane = tid & 63, quad = lane >> 4, l16 = lane & 15;
    int mh = w & 1, nh = w >> 1;
    int n0 = blockIdx.x * 96;
    size_t m0 = (size_t)blockIdx.y * 128;

    bf16x8 af[3][3], bf[4][3];
#pragma unroll
    for (int ni = 0; ni < 3; ni++)
#pragma unroll
        for (int kk = 0; kk < 3; kk++)
            af[ni][kk] = *(const bf16x8*)&W[(size_t)(n0 + nh * 48 + ni * 16 + l16) * 96 + kk * 32 + quad * 8];
#pragma unroll
    for (int mi = 0; mi < 4; mi++)
#pragma unroll
        for (int kk = 0; kk < 3; kk++)
            bf[mi][kk] = *(const bf16x8*)&Xh[(m0 + mh * 64 + mi * 16 + l16) * 96 + kk * 32 + quad * 8];

    f32x4 acc[3][4];
#pragma unroll
    for (int ni = 0; ni < 3; ni++)
#pragma unroll
        for (int mi = 0; mi < 4; mi++) acc[ni][mi] = f32x4{0.f, 0.f, 0.f, 0.f};
#pragma unroll
    for (int kk = 0; kk < 3; kk++)
#pragma unroll
        for (int ni = 0; ni < 3; ni++)
#pragma unroll
            for (int mi = 0; mi < 4; mi++)
                acc[ni][mi] = __builtin_amdgcn_mfma_f32_16x16x32_bf16(
                    af[ni][kk], bf[mi][kk], acc[ni][mi], 0, 0, 0);

#pragma unroll
    for (int ni = 0; ni < 3; ni++) {
        int colb = n0 + nh * 48 + ni * 16 + quad * 4;
        float4 bv = *(const float4*)&bias[colb];
#pragma unroll
        for (int mi = 0; mi < 4; mi++) {
            size_t row = m0 + mh * 64 + mi * 16 + l16;
            float v0 = acc[ni][mi][0] + bv.x, v1 = acc[ni][mi][1] + bv.y;
            float v2 = acc[ni][mi][2] + bv.z, v3 = acc[ni][mi][3] + bv.w;
            if (EPI == 1) {
                v0 = 0.5f * v0 * (1.f + erff(v0 * 0.70710678118654752f));
                v1 = 0.5f * v1 * (1.f + erff(v1 * 0.70710678118654752f));
                v2 = 0.5f * v2 * (1.f + erff(v2 * 0.70710678118654752f));
                v3 = 0.5f * v3 * (1.f + erff(v3 * 0.70710678118654752f));
            }
            unsigned int d0 = ((unsigned int)f2bf(v1) << 16) | f2bf(v0);
            unsigned int d1 = ((unsigned int)f2bf(v3) << 16) | f2bf(v2);
            *(uint2*)&Cout[row * N + colb] = make_uint2(d0, d1);
        }
    }
}

// ---------------------------------------------------------------------------
// LDS-free GEMM + bias + residual -> T f32 + fused epilogue -> Yh bf16:
// LNM=1: LayerNorm(g,bt); LNM=0: plain cast. K in {96,384}. Only LDS: 2 KB
// LN half-exchange.
// ---------------------------------------------------------------------------
template <int LNM>
__global__ __launch_bounds__(256) void gemm_res(const u16* __restrict__ Xh,
        const u16* __restrict__ W, const float* __restrict__ bias,
        const float* __restrict__ res, float* __restrict__ Tout,
        const float* __restrict__ g, const float* __restrict__ bt,
        u16* __restrict__ Yh, int K) {
    __shared__ float2 parts[256];
    int tid = threadIdx.x;
    int w = tid >> 6, lane = tid & 63, quad = lane >> 4, l16 = lane & 15;
    int mh = w & 1, nh = w >> 1;
    size_t m0 = (size_t)blockIdx.x * 128;

    f32x4 acc[3][4];
#pragma unroll
    for (int ni = 0; ni < 3; ni++)
#pragma unroll
        for (int mi = 0; mi < 4; mi++) acc[ni][mi] = f32x4{0.f, 0.f, 0.f, 0.f};

    for (int k0 = 0; k0 < K; k0 += 96) {
        bf16x8 af[3][3], bf[4][3];
#pragma unroll
        for (int ni = 0; ni < 3; ni++)
#pragma unroll
            for (int kk = 0; kk < 3; kk++)
                af[ni][kk] = *(const bf16x8*)&W[(size_t)(nh * 48 + ni * 16 + l16) * K + k0 + kk * 32 + quad * 8];
#pragma unroll
        for (int mi = 0; mi < 4; mi++)
#pragma unroll
            for (int kk = 0; kk < 3; kk++)
                bf[mi][kk] = *(const bf16x8*)&Xh[(m0 + mh * 64 + mi * 16 + l16) * K + k0 + kk * 32 + quad * 8];
#pragma unroll
        for (int kk = 0; kk < 3; kk++)
#pragma unroll
            for (int ni = 0; ni < 3; ni++)
#pragma unroll
                for (int mi = 0; mi < 4; mi++)
                    acc[ni][mi] = __builtin_amdgcn_mfma_f32_16x16x32_bf16(
                        af[ni][kk], bf[mi][kk], acc[ni][mi], 0, 0, 0);
    }

#pragma unroll
    for (int ni = 0; ni < 3; ni++) {
        int colb = nh * 48 + ni * 16 + quad * 4;
        float4 bv = *(const float4*)&bias[colb];
#pragma unroll
        for (int mi = 0; mi < 4; mi++) {
            size_t row = m0 + mh * 64 + mi * 16 + l16;
            float4 rv = *(const float4*)&res[row * 96 + colb];
            acc[ni][mi][0] += bv.x + rv.x;
            acc[ni][mi][1] += bv.y + rv.y;
            acc[ni][mi][2] += bv.z + rv.z;
            acc[ni][mi][3] += bv.w + rv.w;
            *(f32x4*)&Tout[row * 96 + colb] = acc[ni][mi];
        }
    }

    if (LNM == 1) {
        float sm4[4], qm4[4];
#pragma unroll
        for (int mi = 0; mi < 4; mi++) {
            float s = 0.f, q = 0.f;
#pragma unroll
            for (int ni = 0; ni < 3; ni++)
#pragma unroll
                for (int r = 0; r < 4; r++) {
                    float v = acc[ni][mi][r];
                    s += v; q += v * v;
                }
            s += __shfl_xor(s, 16, 64); s += __shfl_xor(s, 32, 64);
            q += __shfl_xor(q, 16, 64); q += __shfl_xor(q, 32, 64);
            sm4[mi] = s; qm4[mi] = q;
        }
        __syncthreads();
        if (quad == 0) {
#pragma unroll
            for (int mi = 0; mi < 4; mi++)
                parts[(mh * 64 + mi * 16 + l16) * 2 + nh] = make_float2(sm4[mi], qm4[mi]);
        }
        __syncthreads();
        float mean4[4], rstd4[4];
#pragma unroll
        for (int mi = 0; mi < 4; mi++) {
            float2 oth = parts[(mh * 64 + mi * 16 + l16) * 2 + (nh ^ 1)];
            float ts_ = sm4[mi] + oth.x, tq = qm4[mi] + oth.y;
            float mean = ts_ * (1.f / 96.f);
            float var = tq * (1.f / 96.f) - mean * mean;
            mean4[mi] = mean;
            rstd4[mi] = rsqrtf(var + 1e-5f);
        }
#pragma unroll
        for (int ni = 0; ni < 3; ni++) {
            int colb = nh * 48 + ni * 16 + quad * 4;
            float4 g4 = *(const float4*)&g[colb];
            float4 b4 = *(const float4*)&bt[colb];
#pragma unroll
            for (int mi = 0; mi < 4; mi++) {
                size_t row = m0 + mh * 64 + mi * 16 + l16;
                float y0 = (acc[ni][mi][0] - mean4[mi]) * rstd4[mi] * g4.x + b4.x;
                float y1 = (acc[ni][mi][1] - mean4[mi]) * rstd4[mi] * g4.y + b4.y;
                float y2 = (acc[ni][mi][2] - mean4[mi]) * rstd4[mi] * g4.z + b4.z;
                float y3 = (acc[ni][mi][3] - mean4[mi]) * rstd4[mi] * g4.w + b4.w;
                unsigned int d0 = ((unsigned int)f2bf(y1) << 16) | f2bf(y0);
                unsigned int d1 = ((unsigned int)f2bf(y3) << 16) | f2bf(y2);
                *(uint2*)&Yh[row * 96 + colb] = make_uint2(d0, d1);
            }
        }
    } else {
#pragma unroll
        for (int ni = 0; ni < 3; ni++) {
            int colb = nh * 48 + ni * 16 + quad * 4;
#pragma unroll
            for (int mi = 0; mi < 4; mi++) {
                size_t row = m0 + mh * 64 + mi * 16 + l16;
                unsigned int d0 = ((unsigned int)f2bf(acc[ni][mi][1]) << 16) | f2bf(acc[ni][mi][0]);
                unsigned int d1 = ((unsigned int)f2bf(acc[ni][mi][3]) << 16) | f2bf(acc[ni][mi][2]);
                *(uint2*)&Yh[row * 96 + colb] = make_uint2(d0, d1);
            }
        }
    }
}

// ---------------------------------------------------------------------------
// MFMA window attention v2 (unchanged from passing R4-R6).
// ---------------------------------------------------------------------------
__global__ __launch_bounds__(192, 3) void attn_mfma(const u16* __restrict__ qkv,
        const float* __restrict__ BT, u16* __restrict__ ao, int shift) {
    __shared__ u16 Pl[3][64 * 72];
    __shared__ u16 vts[3][16 * 72];

    int tid = threadIdx.x;
    int w = tid >> 6, lane = tid & 63, quad = lane >> 4, l16 = lane & 15;
    int Wd = blockIdx.x;
    int bb = Wd >> 8, wl = Wd & 255, wh = wl >> 4, ww = wl & 15;
    int type = ((wh == 15) ? 2 : 0) + ((ww == 15) ? 1 : 0);

    int toks4[4], tokV;
#pragma unroll
    for (int t = 0; t < 4; t++) {
        int a = t * 16 + l16; if (a > 48) a = 48;
        int r = (a * 37) >> 8, c = a - r * 7;
        int h = wh * 7 + r, wq = ww * 7 + c;
        if (shift) { h += 3; if (h >= 112) h -= 112; wq += 3; if (wq >= 112) wq -= 112; }
        toks4[t] = bb * 12544 + h * 112 + wq;
    }
    {
        int a = lane > 48 ? 48 : lane;
        int r = (a * 37) >> 8, c = a - r * 7;
        int h = wh * 7 + r, wq = ww * 7 + c;
        if (shift) { h += 3; if (h >= 112) h -= 112; wq += 3; if (wq >= 112) wq -= 112; }
        tokV = bb * 12544 + h * 112 + wq;
    }

    u16* Pw = Pl[w];
    u16* vw = vts[w];

    for (int i = lane; i < 240; i += 64) {
        int rrow = i / 15, key = 49 + (i - rrow * 15);
        vw[rrow * 72 + key] = 0;
    }

    for (int hh = 0; hh < 2; hh++) {
        int head = w * 2 + hh;

        union { u32x4 u; bf16x8 h; } qf[4], kf[4];
#pragma unroll
        for (int t = 0; t < 4; t++) {
            u32x4 zq = {0u, 0u, 0u, 0u}, zk = {0u, 0u, 0u, 0u};
            if (quad < 2) {
                const u16* rb = qkv + (size_t)toks4[t] * 288 + head * 16 + quad * 8;
                zq = *(const u32x4*)(rb);
                zk = *(const u32x4*)(rb + 96);
            }
            qf[t].u = zq; kf[t].u = zk;
        }

        if (lane < 49) {
            const u16* vb = qkv + (size_t)tokV * 288 + head * 16 + 192;
            union { u32x4 v; unsigned int u[4]; } v0, v1;
            v0.v = *(const u32x4*)(vb);
            v1.v = *(const u32x4*)(vb + 8);
#pragma unroll
            for (int j = 0; j < 4; j++) {
                vw[(2 * j) * 72 + lane]         = (u16)(v0.u[j] & 0xffffu);
                vw[(2 * j + 1) * 72 + lane]     = (u16)(v0.u[j] >> 16);
                vw[(8 + 2 * j) * 72 + lane]     = (u16)(v1.u[j] & 0xffffu);
                vw[(8 + 2 * j + 1) * 72 + lane] = (u16)(v1.u[j] >> 16);
            }
        }

        f32x4 S[4][4];
#pragma unroll
        for (int kt = 0; kt < 4; kt++)
#pragma unroll
            for (int qt = 0; qt < 4; qt++)
                S[kt][qt] = __builtin_amdgcn_mfma_f32_16x16x32_bf16(
                    kf[kt].h, qf[qt].h, f32x4{0.f, 0.f, 0.f, 0.f}, 0, 0, 0);

        const float* bbase = BT + (size_t)(type * 6 + head) * 4096;
        float rinv[4];
#pragma unroll
        for (int qt = 0; qt < 4; qt++) {
            f32x4 bv[4];
#pragma unroll
            for (int kt = 0; kt < 4; kt++)
                bv[kt] = *(const f32x4*)&bbase[(size_t)(qt * 16 + l16) * 64 + kt * 16 + quad * 4];
            float mx = -3e38f;
#pragma unroll
            for (int kt = 0; kt < 4; kt++)
#pragma unroll
                for (int r = 0; r < 4; r++) {
                    float v = fmaf(S[kt][qt][r], 0.25f, bv[kt][r]);
                    S[kt][qt][r] = v;
                    mx = fmaxf(mx, v);
                }
            mx = fmaxf(mx, __shfl_xor(mx, 16, 64));
            mx = fmaxf(mx, __shfl_xor(mx, 32, 64));
            float sm = 0.f;
#pragma unroll
            for (int kt = 0; kt < 4; kt++)
#pragma unroll
                for (int r = 0; r < 4; r++) {
                    float e = __expf(S[kt][qt][r] - mx);
                    S[kt][qt][r] = e;
                    sm += e;
                }
            sm += __shfl_xor(sm, 16, 64);
            sm += __shfl_xor(sm, 32, 64);
            rinv[qt] = 1.0f / sm;
        }

#pragma unroll
        for (int qt = 0; qt < 4; qt++)
#pragma unroll
            for (int kt = 0; kt < 4; kt++) {
                unsigned int d0 = ((unsigned int)f2bf(S[kt][qt][1]) << 16) | f2bf(S[kt][qt][0]);
                unsigned int d1 = ((unsigned int)f2bf(S[kt][qt][3]) << 16) | f2bf(S[kt][qt][2]);
                *(uint2*)&Pw[(qt * 16 + l16) * 72 + kt * 16 + quad * 4] = make_uint2(d0, d1);
            }

        bf16x8 vf[2];
#pragma unroll
        for (int ksp = 0; ksp < 2; ksp++)
            vf[ksp] = *(const bf16x8*)&vw[l16 * 72 + ksp * 32 + quad * 8];
#pragma unroll
        for (int qt = 0; qt < 4; qt++) {
            f32x4 O = {0.f, 0.f, 0.f, 0.f};
#pragma unroll
            for (int ksp = 0; ksp < 2; ksp++) {
                bf16x8 pf = *(const bf16x8*)&Pw[(qt * 16 + l16) * 72 + ksp * 32 + quad * 8];
                O = __builtin_amdgcn_mfma_f32_16x16x32_bf16(vf[ksp], pf, O, 0, 0, 0);
            }
            int a = qt * 16 + l16;
            if (a < 49) {
                float ri = rinv[qt];
                unsigned int d0 = ((unsigned int)f2bf(O[1] * ri) << 16) | f2bf(O[0] * ri);
                unsigned int d1 = ((unsigned int)f2bf(O[3] * ri) << 16) | f2bf(O[2] * ri);
                *(uint2*)&ao[(size_t)toks4[qt] * 96 + head * 16 + quad * 4] = make_uint2(d0, d1);
            }
        }
    }
}

// ---------------------------------------------------------------------------
// Final 1x1 conv (96->48) + ReLU via MFMA, LDS-free direct fragments.
// ---------------------------------------------------------------------------
__global__ __launch_bounds__(256) void outconv_mfma(const u16* __restrict__ Th,
        const u16* __restrict__ Woc, const float* __restrict__ ob,
        float* __restrict__ out) {
    int tid = threadIdx.x;
    int w = tid >> 6, lane = tid & 63, quad = lane >> 4, l16 = lane & 15;
    int t0 = blockIdx.x * 128, b = blockIdx.y;
    size_t m0 = (size_t)b * 12544 + t0;

    bf16x8 af[2][3], bfr[3][3];
#pragma unroll
    for (int mi = 0; mi < 2; mi++)
#pragma unroll
        for (int kk = 0; kk < 3; kk++)
            af[mi][kk] = *(const bf16x8*)&Th[(m0 + w * 32 + mi * 16 + l16) * 96 + kk * 32 + quad * 8];
#pragma unroll
    for (int ni = 0; ni < 3; ni++)
#pragma unroll
        for (int kk = 0; kk < 3; kk++)
            bfr[ni][kk] = *(const bf16x8*)&Woc[(size_t)(ni * 16 + l16) * 96 + kk * 32 + quad * 8];

    f32x4 acc[2][3];
#pragma unroll
    for (int mi = 0; mi < 2; mi++)
#pragma unroll
        for (int ni = 0; ni < 3; ni++) acc[mi][ni] = f32x4{0.f, 0.f, 0.f, 0.f};
#pragma unroll
    for (int kk = 0; kk < 3; kk++)
#pragma unroll
        for (int mi = 0; mi < 2; mi++)
#pragma unroll
            for (int ni = 0; ni < 3; ni++)
                acc[mi][ni] = __builtin_amdgcn_mfma_f32_16x16x32_bf16(
                    af[mi][kk], bfr[ni][kk], acc[mi][ni], 0, 0, 0);

#pragma unroll
    for (int mi = 0; mi < 2; mi++)
#pragma unroll
        for (int ni = 0; ni < 3; ni++) {
            int co = ni * 16 + l16;
            float bb = ob[co];
            f32x4 o = {fmaxf(acc[mi][ni][0] + bb, 0.f), fmaxf(acc[mi][ni][1] + bb, 0.f),
                       fmaxf(acc[mi][ni][2] + bb, 0.f), fmaxf(acc[mi][ni][3] + bb, 0.f)};
            *(f32x4*)&out[((size_t)b * 48 + co) * 12544 + t0 + w * 32 + mi * 16 + quad * 4] = o;
        }
}

// ---------------------------------------------------------------------------
extern "C" void kernel_launch(void* const* d_in, const int* in_sizes, int n_in,
                              void* d_out, int out_size, void* d_ws, size_t ws_size,
                              hipStream_t stream) {
    const float* x     = (const float*)d_in[0];
    const float* up_w  = (const float*)d_in[1];
    const float* up_b  = (const float*)d_in[2];
    const float* bn_g  = (const float*)d_in[3];
    const float* bn_b  = (const float*)d_in[4];
    const float* bn_m  = (const float*)d_in[5];
    const float* bn_v  = (const float*)d_in[6];
    const float* n1g   = (const float*)d_in[7];
    const float* n1b   = (const float*)d_in[8];
    const float* qkvw  = (const float*)d_in[9];
    const float* qkvb  = (const float*)d_in[10];
    const float* projw = (const float*)d_in[11];
    const float* projb = (const float*)d_in[12];
    const float* rel   = (const float*)d_in[13];
    const float* n2g   = (const float*)d_in[14];
    const float* n2b   = (const float*)d_in[15];
    const float* f1w   = (const float*)d_in[16];
    const float* f1b   = (const float*)d_in[17];
    const float* f2w   = (const float*)d_in[18];
    const float* f2b   = (const float*)d_in[19];
    const float* outw  = (const float*)d_in[20];
    const float* outb  = (const float*)d_in[21];
    float* out = (float*)d_out;

    char* base = (char*)d_ws;
    float* T  = (float*)base;                       base += (size_t)M_TOK * 96 * 4;
    u16* XBh  = (u16*)base;                         base += (size_t)M_TOK * 96 * 2;
    u16* BIGh = (u16*)base;                         base += (size_t)M_TOK * 384 * 2;
    u16* xT   = (u16*)base;                         base += (size_t)8 * 3136 * 192 * 2;
    u16* Wc   = (u16*)base;                         base += (size_t)16 * 96 * 192 * 2;
    u16* Wh   = (u16*)base;                         base += (size_t)225792 * 2;
    float* BT = (float*)base;
    u16* qkvwh = Wh;
    u16* projwh = Wh + 55296;
    u16* f1wh = Wh + 73728;
    u16* f2wh = Wh + 147456;
    u16* outwh = Wh + 221184;

    prep_kernel<<<1218, 256, 0, stream>>>(qkvw, projw, f1w, f2w, outw, up_w, rel, Wh, Wc, BT);
    transpose_kernel<<<dim3(49, 8), 256, 0, stream>>>(x, xT);
    conv_mfma<<<dim3(49, 4, 8), 256, 0, stream>>>(xT, Wc, up_b, bn_g, bn_b, bn_m, bn_v,
                                                  n1g, n1b, T, XBh);

    for (int blk = 0; blk < 2; blk++) {
        int shift = (blk == 0) ? 0 : 3;
        gemm_act<0><<<dim3(3, M_TOK / 128), 256, 0, stream>>>(
            XBh, qkvwh + blk * 27648, qkvb + blk * 288, BIGh, 288);
        attn_mfma<<<2048, 192, 0, stream>>>(BIGh, BT + (size_t)blk * 98304, XBh, shift);
        gemm_res<1><<<M_TOK / 128, 256, 0, stream>>>(
            XBh, projwh + blk * 9216, projb + blk * 96, T, T,
            n2g + blk * 96, n2b + blk * 96, XBh, 96);
        gemm_act<1><<<dim3(4, M_TOK / 128), 256, 0, stream>>>(
            XBh, f1wh + blk * 36864, f1b + blk * 384, BIGh, 384);
        if (blk == 0) {
            gemm_res<1><<<M_TOK / 128, 256, 0, stream>>>(
                BIGh, f2wh + blk * 36864, f2b + blk * 96, T, T,
                n1g + 96, n1b + 96, XBh, 384);
        } else {
            gemm_res<0><<<M_TOK / 128, 256, 0, stream>>>(
                BIGh, f2wh + blk * 36864, f2b + blk * 96, T, T,
                nullptr, nullptr, XBh, 384);
        }
    }

    outconv_mfma<<<dim3(98, 8), 256, 0, stream>>>(XBh, outwh, outb, out);
}